// Round 1
// baseline (5270.795 us; speedup 1.0000x reference)
//
#include <hip/hip_runtime.h>
#include <math.h>

#define NFEAT 512
#define NHEADS 8
#define HDIM 64
#define NB 4
#define NG 1024
#define NC 1024
#define NQ 256
#define NEGV -9e15f

__device__ __forceinline__ float lrelu(float x){ return x >= 0.f ? x : 0.2f*x; }

// ---------------- repack W [H,F,D] -> Wflat [F, H*D] ----------------
__global__ __launch_bounds__(256) void repack_W_k(const float* __restrict__ W, float* __restrict__ Wf){
    int idx = blockIdx.x*256 + threadIdx.x;          // idx over F*H*D = 262144
    int f = idx >> 9, c = idx & 511;
    int h = c >> 6, d = c & 63;
    Wf[idx] = W[((size_t)((h<<9) + f))*64 + d];
}

// ---------------- wa[h,f] = sum_d W[h,f,d]*a[h,d] (both a1,a2) ----------------
__global__ __launch_bounds__(256) void wa_k(const float* __restrict__ W, const float* __restrict__ a1,
                                            const float* __restrict__ a2,
                                            float* __restrict__ wa1, float* __restrict__ wa2){
    int idx = blockIdx.x*256 + threadIdx.x;          // idx = h*512 + f, total 4096
    int h = idx >> 9;
    const float* Wp = W + (size_t)idx*64;            // (h*F + f)*D
    float s1 = 0.f, s2 = 0.f;
    #pragma unroll
    for (int d = 0; d < 64; ++d){ float w = Wp[d]; s1 += w*a1[(h<<6)+d]; s2 += w*a2[(h<<6)+d]; }
    wa1[idx] = s1; wa2[idx] = s2;
}

// ---------------- scores: sc[row,h] = X[row,:] . wa[h,:]  (row = b*N+n flat) ----------------
__global__ __launch_bounds__(256) void scores_k(const float* __restrict__ X, const float* __restrict__ wa,
                                                float* __restrict__ sc){
    int lane = threadIdx.x & 63;
    int row  = blockIdx.x*4 + (threadIdx.x >> 6);
    const float* Xr = X + (size_t)row*NFEAT;
    float p[NHEADS];
    #pragma unroll
    for (int h = 0; h < NHEADS; ++h) p[h] = 0.f;
    #pragma unroll
    for (int c = 0; c < 8; ++c){
        float x = Xr[(c<<6) + lane];
        #pragma unroll
        for (int h = 0; h < NHEADS; ++h) p[h] += x * wa[(h<<9) + (c<<6) + lane];
    }
    #pragma unroll
    for (int h = 0; h < NHEADS; ++h){
        float v = p[h];
        #pragma unroll
        for (int off = 32; off > 0; off >>= 1) v += __shfl_xor(v, off);
        if (lane == 0) sc[(size_t)row*NHEADS + h] = v;
    }
}

// ---------------- per-column (over n) online max/sum of exp ----------------
// e[n,m] = adj? lrelu(qs[n]+ks[m]) : NEG ; out colmax[b,m,h], invsum[b,m,h]
__global__ __launch_bounds__(256) void colstats_k(const int* __restrict__ adj, int bstride, int ns, int ms,
    const float* __restrict__ qs, const float* __restrict__ ks,
    float* __restrict__ cmax, float* __restrict__ isum, int N, int M){
    int b  = blockIdx.y;
    int ml = threadIdx.x & 63;
    int m  = blockIdx.x*64 + ml;
    int g  = threadIdx.x >> 6;                 // 4 n-chunks
    int chunk = N >> 2;
    const int* adjb = adj + (size_t)b*bstride;
    float ksv[8], mx[8], s[8];
    #pragma unroll
    for (int h = 0; h < 8; ++h){ ksv[h] = ks[((size_t)b*M + m)*8 + h]; mx[h] = -INFINITY; s[h] = 0.f; }
    int n0 = g*chunk, n1 = n0 + chunk;
    for (int n = n0; n < n1; ++n){
        int a = adjb[(size_t)n*ns + (size_t)m*ms];
        const float* qr = qs + ((size_t)b*N + n)*8;
        #pragma unroll
        for (int h = 0; h < 8; ++h){
            float t = qr[h] + ksv[h];
            float e = (a > 0) ? lrelu(t) : NEGV;
            float mn = fmaxf(mx[h], e);
            s[h] = s[h]*expf(mx[h]-mn) + expf(e-mn);
            mx[h] = mn;
        }
    }
    __shared__ float smx[4][64][8];
    __shared__ float ssm[4][64][8];
    #pragma unroll
    for (int h = 0; h < 8; ++h){ smx[g][ml][h] = mx[h]; ssm[g][ml][h] = s[h]; }
    __syncthreads();
    if (g == 0){
        #pragma unroll
        for (int h = 0; h < 8; ++h){
            float m0 = fmaxf(fmaxf(smx[0][ml][h], smx[1][ml][h]), fmaxf(smx[2][ml][h], smx[3][ml][h]));
            float S  = ssm[0][ml][h]*expf(smx[0][ml][h]-m0) + ssm[1][ml][h]*expf(smx[1][ml][h]-m0)
                     + ssm[2][ml][h]*expf(smx[2][ml][h]-m0) + ssm[3][ml][h]*expf(smx[3][ml][h]-m0);
            size_t o = ((size_t)b*M + m)*8 + h;
            cmax[o] = m0; isum[o] = 1.f/S;
        }
    }
}

// ---------------- generic fp32 GEMM, C[b,r,c] = A1@B1 (+A2@B2), cols = 512 ----------------
// epi=0: store. epi=1: fusion gate: f=sigmoid(acc); C = f*P + (1-f)*Aorig
__global__ __launch_bounds__(256) void gemm2_k(const float* __restrict__ A1, const float* __restrict__ B1,
    const float* __restrict__ A2, const float* __restrict__ B2,
    float* __restrict__ C, const float* __restrict__ P, const float* __restrict__ Aorig,
    int rowsPB, int epi){
    int b = blockIdx.z;
    int r0 = blockIdx.y << 6, c0 = blockIdx.x << 6;
    int tid = threadIdx.x;
    int tx = tid & 15, ty = tid >> 4;
    __shared__ float As[32][68];   // [k][r], padded: rows 16B-aligned for b128 reads
    __shared__ float Bs[32][64];   // [k][c]
    float acc[4][4];
    #pragma unroll
    for (int i = 0; i < 4; ++i)
        #pragma unroll
        for (int j = 0; j < 4; ++j) acc[i][j] = 0.f;
    for (int pair = 0; pair < 2; ++pair){
        const float* Ab; const float* Bb;
        if (pair == 0){ Ab = A1 + (size_t)b*rowsPB*NFEAT; Bb = B1; }
        else { if (A2 == nullptr) break; Ab = A2 + (size_t)b*rowsPB*NFEAT; Bb = B2; }
        for (int kt = 0; kt < NFEAT; kt += 32){
            __syncthreads();
            #pragma unroll
            for (int q = tid; q < 2048; q += 256){
                int r = q >> 5, k = q & 31;
                As[k][r] = Ab[(size_t)(r0+r)*NFEAT + kt + k];
            }
            #pragma unroll
            for (int q = tid; q < 2048; q += 256){
                int k = q >> 6, c = q & 63;
                Bs[k][c] = Bb[(size_t)(kt+k)*NFEAT + c0 + c];
            }
            __syncthreads();
            #pragma unroll
            for (int k = 0; k < 32; ++k){
                float av[4], bv[4];
                #pragma unroll
                for (int i = 0; i < 4; ++i) av[i] = As[k][(ty<<2)+i];
                #pragma unroll
                for (int j = 0; j < 4; ++j) bv[j] = Bs[k][(tx<<2)+j];
                #pragma unroll
                for (int i = 0; i < 4; ++i)
                    #pragma unroll
                    for (int j = 0; j < 4; ++j) acc[i][j] += av[i]*bv[j];
            }
        }
    }
    #pragma unroll
    for (int i = 0; i < 4; ++i){
        int r = r0 + (ty<<2) + i;
        size_t base = ((size_t)b*rowsPB + r)*NFEAT + c0 + (tx<<2);
        #pragma unroll
        for (int j = 0; j < 4; ++j){
            float v = acc[i][j];
            size_t o = base + j;
            if (epi == 0) C[o] = v;
            else { float f = 1.f/(1.f + expf(-v)); C[o] = f*P[o] + (1.f - f)*Aorig[o]; }
        }
    }
}

// ---------------- gloss_same: C[b,m,f] = sum_n adj[b,n,m] * X[b,n,f] ----------------
__global__ __launch_bounds__(256) void gemm_adjT_k(const int* __restrict__ adj, const float* __restrict__ X,
    float* __restrict__ C, int Kn, int Mrows){
    int b = blockIdx.z;
    int m0 = blockIdx.y << 6, c0 = blockIdx.x << 6;
    int tid = threadIdx.x;
    int tx = tid & 15, ty = tid >> 4;
    const int*   adjb = adj + (size_t)b*Kn*Mrows;
    const float* Xb   = X   + (size_t)b*Kn*NFEAT;
    __shared__ float As[32][68];   // [k][m]
    __shared__ float Bs[32][64];
    float acc[4][4];
    #pragma unroll
    for (int i = 0; i < 4; ++i)
        #pragma unroll
        for (int j = 0; j < 4; ++j) acc[i][j] = 0.f;
    for (int kt = 0; kt < Kn; kt += 32){
        __syncthreads();
        #pragma unroll
        for (int q = tid; q < 2048; q += 256){
            int k = q >> 6, r = q & 63;
            As[k][r] = (float)adjb[(size_t)(kt+k)*Mrows + m0 + r];
        }
        #pragma unroll
        for (int q = tid; q < 2048; q += 256){
            int k = q >> 6, c = q & 63;
            Bs[k][c] = Xb[(size_t)(kt+k)*NFEAT + c0 + c];
        }
        __syncthreads();
        #pragma unroll
        for (int k = 0; k < 32; ++k){
            float av[4], bv[4];
            #pragma unroll
            for (int i = 0; i < 4; ++i) av[i] = As[k][(ty<<2)+i];
            #pragma unroll
            for (int j = 0; j < 4; ++j) bv[j] = Bs[k][(tx<<2)+j];
            #pragma unroll
            for (int i = 0; i < 4; ++i)
                #pragma unroll
                for (int j = 0; j < 4; ++j) acc[i][j] += av[i]*bv[j];
        }
    }
    #pragma unroll
    for (int i = 0; i < 4; ++i){
        int r = m0 + (ty<<2) + i;
        size_t base = ((size_t)b*Mrows + r)*NFEAT + c0 + (tx<<2);
        #pragma unroll
        for (int j = 0; j < 4; ++j) C[base + j] = acc[i][j];
    }
}

// ---------------- attention output: out[b,n,h*64+d] = elu( sum_m p[n,m]*Wk[b,m,h*64+d] ) ----------------
// p generated on the fly from qs/ks/adj/colmax/invsum. grid: (N/64, B*H)
__global__ __launch_bounds__(256) void attn_out_k(const int* __restrict__ adj, int bstride, int ns, int ms,
    const float* __restrict__ qs, const float* __restrict__ ks,
    const float* __restrict__ cmax, const float* __restrict__ isum,
    const float* __restrict__ Wk, float* __restrict__ outp, int N, int M){
    int bh = blockIdx.y; int b = bh >> 3, h = bh & 7;
    int n0 = blockIdx.x << 6;
    int tid = threadIdx.x;
    int tx = tid & 15, ty = tid >> 4;
    __shared__ float pS[32][68];   // [m_local][n_local]
    __shared__ float wS[32][64];   // [m_local][d]
    __shared__ float qsS[64];
    if (tid < 64) qsS[tid] = qs[((size_t)b*N + n0 + tid)*8 + h];
    const int* adjb = adj + (size_t)b*bstride;
    int mlp = tid & 31;            // this thread's fixed m within each tile
    float acc[4][4];
    #pragma unroll
    for (int i = 0; i < 4; ++i)
        #pragma unroll
        for (int j = 0; j < 4; ++j) acc[i][j] = 0.f;
    for (int mt = 0; mt < M; mt += 32){
        int m = mt + mlp;
        size_t mo = ((size_t)b*M + m)*8 + h;
        float ksv = ks[mo], cmv = cmax[mo], isv = isum[mo];
        __syncthreads();
        #pragma unroll
        for (int j = 0; j < 8; ++j){
            int nl = (tid >> 5) + (j << 3);
            int a = adjb[(size_t)(n0+nl)*ns + (size_t)m*ms];
            float e = (a > 0) ? lrelu(qsS[nl] + ksv) : NEGV;
            pS[mlp][nl] = expf(e - cmv) * isv;
        }
        #pragma unroll
        for (int q = tid; q < 2048; q += 256){
            int k = q >> 6, d = q & 63;
            wS[k][d] = Wk[((size_t)b*M + mt + k)*NFEAT + (h<<6) + d];
        }
        __syncthreads();
        #pragma unroll
        for (int k = 0; k < 32; ++k){
            float av[4], bv[4];
            #pragma unroll
            for (int i = 0; i < 4; ++i) av[i] = pS[k][(ty<<2)+i];
            #pragma unroll
            for (int j = 0; j < 4; ++j) bv[j] = wS[k][(tx<<2)+j];
            #pragma unroll
            for (int i = 0; i < 4; ++i)
                #pragma unroll
                for (int j = 0; j < 4; ++j) acc[i][j] += av[i]*bv[j];
        }
    }
    #pragma unroll
    for (int i = 0; i < 4; ++i){
        int r = n0 + (ty<<2) + i;
        size_t base = ((size_t)b*N + r)*NFEAT + (h<<6) + (tx<<2);
        #pragma unroll
        for (int j = 0; j < 4; ++j){
            float v = acc[i][j];
            outp[base + j] = (v > 0.f) ? v : expm1f(v);
        }
    }
}

extern "C" void kernel_launch(void* const* d_in, const int* in_sizes, int n_in,
                              void* d_out, int out_size, void* d_ws, size_t ws_size,
                              hipStream_t stream){
    const float* in_gloss = (const float*)d_in[0];
    const float* in_clip  = (const float*)d_in[1];
    const float* in_q     = (const float*)d_in[2];
    const int*   adj_gc   = (const int*)d_in[3];   // [B,Ng,Nc]
    const int*   adj_gq   = (const int*)d_in[4];   // [B,Ng,Nq]
    const float* c2gW = (const float*)d_in[5];
    const float* c2ga1 = (const float*)d_in[6];
    const float* c2ga2 = (const float*)d_in[7];
    const float* g2qW = (const float*)d_in[8];
    const float* g2qa1 = (const float*)d_in[9];
    const float* g2qa2 = (const float*)d_in[10];
    const float* q2gW = (const float*)d_in[11];
    const float* q2ga1 = (const float*)d_in[12];
    const float* q2ga2 = (const float*)d_in[13];
    const float* fusW  = (const float*)d_in[14];
    const float* fusU  = (const float*)d_in[15];
    const float* fusWf = (const float*)d_in[16];
    const float* fusUf = (const float*)d_in[17];
    float* out = (float*)d_out;
    float* out_gloss = out;
    float* out_clip  = out + (size_t)NB*NG*NFEAT;
    float* out_q     = out + (size_t)NB*NG*NFEAT*2;

    float* ws = (float*)d_ws;
    size_t off = 0;
    auto alloc = [&](size_t n){ float* p = ws + off; off += n; return p; };
    float* glossA    = alloc((size_t)NB*NG*NFEAT);
    float* glossB    = alloc((size_t)NB*NG*NFEAT);
    float* clipA     = alloc((size_t)NB*NC*NFEAT);
    float* questionA = alloc((size_t)NB*NQ*NFEAT);
    float* agg       = alloc((size_t)NB*NG*NFEAT);   // reused per stage
    float* Pbuf      = alloc((size_t)NB*NG*NFEAT);
    float* Wkbuf     = alloc((size_t)NB*NG*NFEAT);
    float* Wflat     = alloc((size_t)NFEAT*NHEADS*HDIM);
    float* wa1       = alloc((size_t)NHEADS*NFEAT);
    float* wa2       = alloc((size_t)NHEADS*NFEAT);
    float* qsb       = alloc((size_t)NB*NG*NHEADS);
    float* ksb       = alloc((size_t)NB*NG*NHEADS);
    float* cmaxb     = alloc((size_t)NB*NG*NHEADS);
    float* isumb     = alloc((size_t)NB*NG*NHEADS);
    (void)ws_size; (void)in_sizes; (void)n_in; (void)out_size;

    const size_t FF = (size_t)NFEAT*NFEAT;           // 262144
    const size_t HFD = (size_t)NHEADS*NFEAT*HDIM;    // 262144
    const size_t HD = (size_t)NHEADS*HDIM;           // 512

    auto run_attn = [&](const float* q, int N, const float* kv, int M,
                        const int* adjp, int bstride, int ns, int ms,
                        const float* W, const float* a1, const float* a2, float* dst){
        repack_W_k<<<1024, 256, 0, stream>>>(W, Wflat);
        wa_k<<<16, 256, 0, stream>>>(W, a1, a2, wa1, wa2);
        scores_k<<<(NB*N)/4, 256, 0, stream>>>(q, wa1, qsb);
        scores_k<<<(NB*M)/4, 256, 0, stream>>>(kv, wa2, ksb);
        gemm2_k<<<dim3(8, M/64, NB), 256, 0, stream>>>(kv, Wflat, nullptr, nullptr,
                                                       Wkbuf, nullptr, nullptr, M, 0);
        colstats_k<<<dim3(M/64, NB), 256, 0, stream>>>(adjp, bstride, ns, ms, qsb, ksb,
                                                       cmaxb, isumb, N, M);
        attn_out_k<<<dim3(N/64, NB*NHEADS), 256, 0, stream>>>(adjp, bstride, ns, ms,
                                                              qsb, ksb, cmaxb, isumb,
                                                              Wkbuf, dst, N, M);
    };
    auto run_fusion = [&](const float* a, const float* bb, int N,
                          const float* W, const float* U, const float* Wf, const float* Uf,
                          float* dst){
        gemm2_k<<<dim3(8, N/64, NB), 256, 0, stream>>>(a, W, bb, U, Pbuf, nullptr, nullptr, N, 0);
        gemm2_k<<<dim3(8, N/64, NB), 256, 0, stream>>>(a, Wf, bb, Uf, dst, Pbuf, a, N, 1);
    };

    for (int l = 0; l < 2; ++l){
        const float* gloss_old = (l == 0) ? in_gloss : glossB;
        const float* clip_old  = (l == 0) ? in_clip  : clipA;
        const float* q_old     = (l == 0) ? in_q     : questionA;
        float* gloss2_dst = (l == 0) ? glossB    : out_gloss;
        float* clip1_dst  = (l == 0) ? clipA     : out_clip;
        float* q1_dst     = (l == 0) ? questionA : out_q;
        const float* fW  = fusW  + (size_t)l*4*FF;
        const float* fU  = fusU  + (size_t)l*4*FF;
        const float* fWf = fusWf + (size_t)l*4*FF;
        const float* fUf = fusUf + (size_t)l*4*FF;

        // gloss_same = adj_gc^T @ gloss_old  -> agg [B, Nc, F]
        gemm_adjT_k<<<dim3(8, NC/64, NB), 256, 0, stream>>>(adj_gc, gloss_old, agg, NG, NC);
        // clip_1
        run_fusion(clip_old, agg, NC, fW+0*FF, fU+0*FF, fWf+0*FF, fUf+0*FF, clip1_dst);
        // clip_agg = attn(q=gloss, kv=clip, adj_gc)  (ns=Nc, ms=1)
        run_attn(gloss_old, NG, clip_old, NC, adj_gc, NG*NC, NC, 1,
                 c2gW + l*HFD, c2ga1 + l*HD, c2ga2 + l*HD, agg);
        // gloss_1
        run_fusion(gloss_old, agg, NG, fW+1*FF, fU+1*FF, fWf+1*FF, fUf+1*FF, glossA);
        // gloss_agg = attn(q=question, kv=gloss, adj_gq^T)  (ns=1, ms=Nq)
        run_attn(q_old, NQ, gloss_old, NG, adj_gq, NG*NQ, 1, NQ,
                 g2qW + l*HFD, g2qa1 + l*HD, g2qa2 + l*HD, agg);
        // question_1
        run_fusion(q_old, agg, NQ, fW+2*FF, fU+2*FF, fWf+2*FF, fUf+2*FF, q1_dst);
        // question_agg = attn(q=gloss, kv=question, adj_gq)  (ns=Nq, ms=1)
        run_attn(gloss_old, NG, q_old, NQ, adj_gq, NG*NQ, NQ, 1,
                 q2gW + l*HFD, q2ga1 + l*HD, q2ga2 + l*HD, agg);
        // gloss_2
        run_fusion(glossA, agg, NG, fW+3*FF, fU+3*FF, fWf+3*FF, fUf+3*FF, gloss2_dst);
    }
}

// Round 2
// 3880.559 us; speedup vs baseline: 1.3583x; 1.3583x over previous
//
#include <hip/hip_runtime.h>
#include <math.h>

#define NFEAT 512
#define NHEADS 8
#define HDIM 64
#define NB 4
#define NG 1024
#define NC 1024
#define NQ 256
#define NEGV -9e15f
#define CHUNKS 16

__device__ __forceinline__ float lrelu(float x){ return x >= 0.f ? x : 0.2f*x; }

// ---------------- repack W [H,F,D] -> Wflat [F, H*D] ----------------
__global__ __launch_bounds__(256) void repack_W_k(const float* __restrict__ W, float* __restrict__ Wf){
    int idx = blockIdx.x*256 + threadIdx.x;          // idx over F*H*D = 262144
    int f = idx >> 9, c = idx & 511;
    int h = c >> 6, d = c & 63;
    Wf[idx] = W[((size_t)((h<<9) + f))*64 + d];
}

// ---------------- wa[h,f] = sum_d W[h,f,d]*a[h,d] (both a1,a2) ----------------
__global__ __launch_bounds__(256) void wa_k(const float* __restrict__ W, const float* __restrict__ a1,
                                            const float* __restrict__ a2,
                                            float* __restrict__ wa1, float* __restrict__ wa2){
    int idx = blockIdx.x*256 + threadIdx.x;          // idx = h*512 + f, total 4096
    int h = idx >> 9;
    const float* Wp = W + (size_t)idx*64;            // (h*F + f)*D
    float s1 = 0.f, s2 = 0.f;
    #pragma unroll
    for (int d = 0; d < 64; ++d){ float w = Wp[d]; s1 += w*a1[(h<<6)+d]; s2 += w*a2[(h<<6)+d]; }
    wa1[idx] = s1; wa2[idx] = s2;
}

// ---------------- scores: sc[row,h] = X[row,:] . wa[h,:]  (row = b*N+n flat) ----------------
__global__ __launch_bounds__(256) void scores_k(const float* __restrict__ X, const float* __restrict__ wa,
                                                float* __restrict__ sc){
    int lane = threadIdx.x & 63;
    int row  = blockIdx.x*4 + (threadIdx.x >> 6);
    const float* Xr = X + (size_t)row*NFEAT;
    float p[NHEADS];
    #pragma unroll
    for (int h = 0; h < NHEADS; ++h) p[h] = 0.f;
    #pragma unroll
    for (int c = 0; c < 8; ++c){
        float x = Xr[(c<<6) + lane];
        #pragma unroll
        for (int h = 0; h < NHEADS; ++h) p[h] += x * wa[(h<<9) + (c<<6) + lane];
    }
    #pragma unroll
    for (int h = 0; h < NHEADS; ++h){
        float v = p[h];
        #pragma unroll
        for (int off = 32; off > 0; off >>= 1) v += __shfl_xor(v, off);
        if (lane == 0) sc[(size_t)row*NHEADS + h] = v;
    }
}

// ---------------- pass A: partial masked max of qs over an n-chunk ----------------
// pmax[b,ch,m,h] = max_{n in chunk, adj[n,m]>0} qs[b,n,h]  (else -inf)
__global__ __launch_bounds__(256) void colmax_part_k(const int* __restrict__ adj, int bstride, int ns, int ms,
    const float* __restrict__ qs, float* __restrict__ pmax, int N, int M){
    int b = blockIdx.z, ch = blockIdx.y;
    int ml = threadIdx.x & 63; int m = blockIdx.x*64 + ml;
    int g = threadIdx.x >> 6;
    int chunk = N / CHUNKS, subl = chunk >> 2;
    int n0 = ch*chunk + g*subl, n1 = n0 + subl;
    const int* adjb = adj + (size_t)b*bstride;
    float mx[8];
    #pragma unroll
    for (int h = 0; h < 8; ++h) mx[h] = -INFINITY;
    for (int n = n0; n < n1; ++n){
        int a = adjb[(size_t)n*ns + (size_t)m*ms];
        const float* qr = qs + ((size_t)b*N + n)*8;
        #pragma unroll
        for (int h = 0; h < 8; ++h){ float qv = qr[h]; if (a > 0) mx[h] = fmaxf(mx[h], qv); }
    }
    __shared__ float smx[4][64][8];
    #pragma unroll
    for (int h = 0; h < 8; ++h) smx[g][ml][h] = mx[h];
    __syncthreads();
    if (g == 0){
        #pragma unroll
        for (int h = 0; h < 8; ++h){
            float v = fmaxf(fmaxf(smx[0][ml][h], smx[1][ml][h]), fmaxf(smx[2][ml][h], smx[3][ml][h]));
            pmax[(((size_t)b*CHUNKS + ch)*M + m)*8 + h] = v;
        }
    }
}

// ---------------- finalize colmax: cmax = (Mq==-inf)? NEG : lrelu(Mq + ks) ----------------
__global__ __launch_bounds__(256) void colmax_fin_k(const float* __restrict__ pmax, const float* __restrict__ ks,
    float* __restrict__ cmax, int M){
    int idx = blockIdx.x*256 + threadIdx.x;          // idx = (b*M+m)*8+h
    float mx = -INFINITY;
    int m8 = M*8;
    int bm = idx / 8 / M;                            // b
    int rem = idx - bm*m8*CHUNKS/CHUNKS;             // keep simple below
    (void)rem;
    size_t base = (size_t)bm*CHUNKS*m8 + (idx - (size_t)bm*m8);
    #pragma unroll
    for (int ch = 0; ch < CHUNKS; ++ch) mx = fmaxf(mx, pmax[base + (size_t)ch*m8]);
    cmax[idx] = (mx == -INFINITY) ? NEGV : lrelu(mx + ks[idx]);
}

// ---------------- pass B: partial sum of exp(e - cmax) over an n-chunk ----------------
__global__ __launch_bounds__(256) void colsum_part_k(const int* __restrict__ adj, int bstride, int ns, int ms,
    const float* __restrict__ qs, const float* __restrict__ ks, const float* __restrict__ cmax,
    float* __restrict__ psum, int N, int M){
    int b = blockIdx.z, ch = blockIdx.y;
    int ml = threadIdx.x & 63; int m = blockIdx.x*64 + ml;
    int g = threadIdx.x >> 6;
    int chunk = N / CHUNKS, subl = chunk >> 2;
    int n0 = ch*chunk + g*subl, n1 = n0 + subl;
    const int* adjb = adj + (size_t)b*bstride;
    float ksv[8], cmv[8], s[8];
    size_t mo = ((size_t)b*M + m)*8;
    #pragma unroll
    for (int h = 0; h < 8; ++h){ ksv[h] = ks[mo+h]; cmv[h] = cmax[mo+h]; s[h] = 0.f; }
    for (int n = n0; n < n1; ++n){
        int a = adjb[(size_t)n*ns + (size_t)m*ms];
        const float* qr = qs + ((size_t)b*N + n)*8;
        #pragma unroll
        for (int h = 0; h < 8; ++h){
            float e = (a > 0) ? lrelu(qr[h] + ksv[h]) : NEGV;
            s[h] += expf(e - cmv[h]);
        }
    }
    __shared__ float ssm[4][64][8];
    #pragma unroll
    for (int h = 0; h < 8; ++h) ssm[g][ml][h] = s[h];
    __syncthreads();
    if (g == 0){
        #pragma unroll
        for (int h = 0; h < 8; ++h){
            float v = ssm[0][ml][h] + ssm[1][ml][h] + ssm[2][ml][h] + ssm[3][ml][h];
            psum[(((size_t)b*CHUNKS + ch)*M + m)*8 + h] = v;
        }
    }
}

// ---------------- finalize invsum ----------------
__global__ __launch_bounds__(256) void colsum_fin_k(const float* __restrict__ psum, float* __restrict__ isum, int M){
    int idx = blockIdx.x*256 + threadIdx.x;          // idx = (b*M+m)*8+h
    int m8 = M*8;
    int b = idx / m8;
    size_t base = (size_t)b*CHUNKS*m8 + (idx - (size_t)b*m8);
    float S = 0.f;
    #pragma unroll
    for (int ch = 0; ch < CHUNKS; ++ch) S += psum[base + (size_t)ch*m8];
    isum[idx] = 1.f/S;
}

// ---------------- generic fp32 GEMM, C[b,r,c] = A1@B1 (+A2@B2), cols = 512 ----------------
// epi=0: store. epi=1: fusion gate: f=sigmoid(acc); C = f*P + (1-f)*Aorig
__global__ __launch_bounds__(256) void gemm2_k(const float* __restrict__ A1, const float* __restrict__ B1,
    const float* __restrict__ A2, const float* __restrict__ B2,
    float* __restrict__ C, const float* __restrict__ P, const float* __restrict__ Aorig,
    int rowsPB, int epi){
    int b = blockIdx.z;
    int r0 = blockIdx.y << 6, c0 = blockIdx.x << 6;
    int tid = threadIdx.x;
    int tx = tid & 15, ty = tid >> 4;
    __shared__ float As[32][68];
    __shared__ float Bs[32][64];
    float acc[4][4];
    #pragma unroll
    for (int i = 0; i < 4; ++i)
        #pragma unroll
        for (int j = 0; j < 4; ++j) acc[i][j] = 0.f;
    for (int pair = 0; pair < 2; ++pair){
        const float* Ab; const float* Bb;
        if (pair == 0){ Ab = A1 + (size_t)b*rowsPB*NFEAT; Bb = B1; }
        else { if (A2 == nullptr) break; Ab = A2 + (size_t)b*rowsPB*NFEAT; Bb = B2; }
        for (int kt = 0; kt < NFEAT; kt += 32){
            __syncthreads();
            #pragma unroll
            for (int q = tid; q < 2048; q += 256){
                int r = q >> 5, k = q & 31;
                As[k][r] = Ab[(size_t)(r0+r)*NFEAT + kt + k];
            }
            #pragma unroll
            for (int q = tid; q < 2048; q += 256){
                int k = q >> 6, c = q & 63;
                Bs[k][c] = Bb[(size_t)(kt+k)*NFEAT + c0 + c];
            }
            __syncthreads();
            #pragma unroll
            for (int k = 0; k < 32; ++k){
                float av[4], bv[4];
                #pragma unroll
                for (int i = 0; i < 4; ++i) av[i] = As[k][(ty<<2)+i];
                #pragma unroll
                for (int j = 0; j < 4; ++j) bv[j] = Bs[k][(tx<<2)+j];
                #pragma unroll
                for (int i = 0; i < 4; ++i)
                    #pragma unroll
                    for (int j = 0; j < 4; ++j) acc[i][j] += av[i]*bv[j];
            }
        }
    }
    #pragma unroll
    for (int i = 0; i < 4; ++i){
        int r = r0 + (ty<<2) + i;
        size_t base = ((size_t)b*rowsPB + r)*NFEAT + c0 + (tx<<2);
        #pragma unroll
        for (int j = 0; j < 4; ++j){
            float v = acc[i][j];
            size_t o = base + j;
            if (epi == 0) C[o] = v;
            else { float f = 1.f/(1.f + expf(-v)); C[o] = f*P[o] + (1.f - f)*Aorig[o]; }
        }
    }
}

// ---------------- gloss_same: C[b,m,f] = sum_n adj[b,n,m] * X[b,n,f] ----------------
__global__ __launch_bounds__(256) void gemm_adjT_k(const int* __restrict__ adj, const float* __restrict__ X,
    float* __restrict__ C, int Kn, int Mrows){
    int b = blockIdx.z;
    int m0 = blockIdx.y << 6, c0 = blockIdx.x << 6;
    int tid = threadIdx.x;
    int tx = tid & 15, ty = tid >> 4;
    const int*   adjb = adj + (size_t)b*Kn*Mrows;
    const float* Xb   = X   + (size_t)b*Kn*NFEAT;
    __shared__ float As[32][68];
    __shared__ float Bs[32][64];
    float acc[4][4];
    #pragma unroll
    for (int i = 0; i < 4; ++i)
        #pragma unroll
        for (int j = 0; j < 4; ++j) acc[i][j] = 0.f;
    for (int kt = 0; kt < Kn; kt += 32){
        __syncthreads();
        #pragma unroll
        for (int q = tid; q < 2048; q += 256){
            int k = q >> 6, r = q & 63;
            As[k][r] = (float)adjb[(size_t)(kt+k)*Mrows + m0 + r];
        }
        #pragma unroll
        for (int q = tid; q < 2048; q += 256){
            int k = q >> 6, c = q & 63;
            Bs[k][c] = Xb[(size_t)(kt+k)*NFEAT + c0 + c];
        }
        __syncthreads();
        #pragma unroll
        for (int k = 0; k < 32; ++k){
            float av[4], bv[4];
            #pragma unroll
            for (int i = 0; i < 4; ++i) av[i] = As[k][(ty<<2)+i];
            #pragma unroll
            for (int j = 0; j < 4; ++j) bv[j] = Bs[k][(tx<<2)+j];
            #pragma unroll
            for (int i = 0; i < 4; ++i)
                #pragma unroll
                for (int j = 0; j < 4; ++j) acc[i][j] += av[i]*bv[j];
        }
    }
    #pragma unroll
    for (int i = 0; i < 4; ++i){
        int r = m0 + (ty<<2) + i;
        size_t base = ((size_t)b*Mrows + r)*NFEAT + c0 + (tx<<2);
        #pragma unroll
        for (int j = 0; j < 4; ++j) C[base + j] = acc[i][j];
    }
}

// ---------------- attention output: out[b,n,h*64+d] = elu( sum_m p[n,m]*Wk[b,m,h*64+d] ) ----------------
__global__ __launch_bounds__(256) void attn_out_k(const int* __restrict__ adj, int bstride, int ns, int ms,
    const float* __restrict__ qs, const float* __restrict__ ks,
    const float* __restrict__ cmax, const float* __restrict__ isum,
    const float* __restrict__ Wk, float* __restrict__ outp, int N, int M){
    int bh = blockIdx.y; int b = bh >> 3, h = bh & 7;
    int n0 = blockIdx.x << 6;
    int tid = threadIdx.x;
    int tx = tid & 15, ty = tid >> 4;
    __shared__ float pS[32][68];
    __shared__ float wS[32][64];
    __shared__ float qsS[64];
    if (tid < 64) qsS[tid] = qs[((size_t)b*N + n0 + tid)*8 + h];
    const int* adjb = adj + (size_t)b*bstride;
    int mlp = tid & 31;
    float acc[4][4];
    #pragma unroll
    for (int i = 0; i < 4; ++i)
        #pragma unroll
        for (int j = 0; j < 4; ++j) acc[i][j] = 0.f;
    for (int mt = 0; mt < M; mt += 32){
        int m = mt + mlp;
        size_t mo = ((size_t)b*M + m)*8 + h;
        float ksv = ks[mo], cmv = cmax[mo], isv = isum[mo];
        __syncthreads();
        #pragma unroll
        for (int j = 0; j < 8; ++j){
            int nl = (tid >> 5) + (j << 3);
            int a = adjb[(size_t)(n0+nl)*ns + (size_t)m*ms];
            float e = (a > 0) ? lrelu(qsS[nl] + ksv) : NEGV;
            pS[mlp][nl] = expf(e - cmv) * isv;
        }
        #pragma unroll
        for (int q = tid; q < 2048; q += 256){
            int k = q >> 6, d = q & 63;
            wS[k][d] = Wk[((size_t)b*M + mt + k)*NFEAT + (h<<6) + d];
        }
        __syncthreads();
        #pragma unroll
        for (int k = 0; k < 32; ++k){
            float av[4], bv[4];
            #pragma unroll
            for (int i = 0; i < 4; ++i) av[i] = pS[k][(ty<<2)+i];
            #pragma unroll
            for (int j = 0; j < 4; ++j) bv[j] = wS[k][(tx<<2)+j];
            #pragma unroll
            for (int i = 0; i < 4; ++i)
                #pragma unroll
                for (int j = 0; j < 4; ++j) acc[i][j] += av[i]*bv[j];
        }
    }
    #pragma unroll
    for (int i = 0; i < 4; ++i){
        int r = n0 + (ty<<2) + i;
        size_t base = ((size_t)b*N + r)*NFEAT + (h<<6) + (tx<<2);
        #pragma unroll
        for (int j = 0; j < 4; ++j){
            float v = acc[i][j];
            outp[base + j] = (v > 0.f) ? v : expm1f(v);
        }
    }
}

extern "C" void kernel_launch(void* const* d_in, const int* in_sizes, int n_in,
                              void* d_out, int out_size, void* d_ws, size_t ws_size,
                              hipStream_t stream){
    const float* in_gloss = (const float*)d_in[0];
    const float* in_clip  = (const float*)d_in[1];
    const float* in_q     = (const float*)d_in[2];
    const int*   adj_gc   = (const int*)d_in[3];   // [B,Ng,Nc]
    const int*   adj_gq   = (const int*)d_in[4];   // [B,Ng,Nq]
    const float* c2gW = (const float*)d_in[5];
    const float* c2ga1 = (const float*)d_in[6];
    const float* c2ga2 = (const float*)d_in[7];
    const float* g2qW = (const float*)d_in[8];
    const float* g2qa1 = (const float*)d_in[9];
    const float* g2qa2 = (const float*)d_in[10];
    const float* q2gW = (const float*)d_in[11];
    const float* q2ga1 = (const float*)d_in[12];
    const float* q2ga2 = (const float*)d_in[13];
    const float* fusW  = (const float*)d_in[14];
    const float* fusU  = (const float*)d_in[15];
    const float* fusWf = (const float*)d_in[16];
    const float* fusUf = (const float*)d_in[17];
    float* out = (float*)d_out;
    float* out_gloss = out;
    float* out_clip  = out + (size_t)NB*NG*NFEAT;
    float* out_q     = out + (size_t)NB*NG*NFEAT*2;

    float* ws = (float*)d_ws;
    size_t off = 0;
    auto alloc = [&](size_t n){ float* p = ws + off; off += n; return p; };
    float* glossA    = alloc((size_t)NB*NG*NFEAT);
    float* glossB    = alloc((size_t)NB*NG*NFEAT);
    float* clipA     = alloc((size_t)NB*NC*NFEAT);
    float* questionA = alloc((size_t)NB*NQ*NFEAT);
    float* agg       = alloc((size_t)NB*NG*NFEAT);
    float* Pbuf      = alloc((size_t)NB*NG*NFEAT);
    float* Wkbuf     = alloc((size_t)NB*NG*NFEAT);
    float* Wflat     = alloc((size_t)NFEAT*NHEADS*HDIM);
    float* wa1       = alloc((size_t)NHEADS*NFEAT);
    float* wa2       = alloc((size_t)NHEADS*NFEAT);
    float* qsb       = alloc((size_t)NB*NG*NHEADS);
    float* ksb       = alloc((size_t)NB*NG*NHEADS);
    float* cmaxb     = alloc((size_t)NB*NG*NHEADS);
    float* isumb     = alloc((size_t)NB*NG*NHEADS);
    // softmax-stat partials alias Pbuf (only live between fusion stages)
    float* pmaxb     = Pbuf;
    float* psumb     = Pbuf + (size_t)NB*CHUNKS*NG*NHEADS;
    (void)ws_size; (void)in_sizes; (void)n_in; (void)out_size;

    const size_t FF = (size_t)NFEAT*NFEAT;
    const size_t HFD = (size_t)NHEADS*NFEAT*HDIM;
    const size_t HD = (size_t)NHEADS*HDIM;

    auto run_attn = [&](const float* q, int N, const float* kv, int M,
                        const int* adjp, int bstride, int ns, int ms,
                        const float* W, const float* a1, const float* a2, float* dst){
        repack_W_k<<<1024, 256, 0, stream>>>(W, Wflat);
        wa_k<<<16, 256, 0, stream>>>(W, a1, a2, wa1, wa2);
        scores_k<<<(NB*N)/4, 256, 0, stream>>>(q, wa1, qsb);
        scores_k<<<(NB*M)/4, 256, 0, stream>>>(kv, wa2, ksb);
        gemm2_k<<<dim3(8, M/64, NB), 256, 0, stream>>>(kv, Wflat, nullptr, nullptr,
                                                       Wkbuf, nullptr, nullptr, M, 0);
        colmax_part_k<<<dim3(M/64, CHUNKS, NB), 256, 0, stream>>>(adjp, bstride, ns, ms, qsb, pmaxb, N, M);
        colmax_fin_k<<<(NB*M*NHEADS)/256, 256, 0, stream>>>(pmaxb, ksb, cmaxb, M);
        colsum_part_k<<<dim3(M/64, CHUNKS, NB), 256, 0, stream>>>(adjp, bstride, ns, ms, qsb, ksb, cmaxb, psumb, N, M);
        colsum_fin_k<<<(NB*M*NHEADS)/256, 256, 0, stream>>>(psumb, isumb, M);
        attn_out_k<<<dim3(N/64, NB*NHEADS), 256, 0, stream>>>(adjp, bstride, ns, ms,
                                                              qsb, ksb, cmaxb, isumb,
                                                              Wkbuf, dst, N, M);
    };
    auto run_fusion = [&](const float* a, const float* bb, int N,
                          const float* W, const float* U, const float* Wf, const float* Uf,
                          float* dst){
        gemm2_k<<<dim3(8, N/64, NB), 256, 0, stream>>>(a, W, bb, U, Pbuf, nullptr, nullptr, N, 0);
        gemm2_k<<<dim3(8, N/64, NB), 256, 0, stream>>>(a, Wf, bb, Uf, dst, Pbuf, a, N, 1);
    };

    for (int l = 0; l < 2; ++l){
        const float* gloss_old = (l == 0) ? in_gloss : glossB;
        const float* clip_old  = (l == 0) ? in_clip  : clipA;
        const float* q_old     = (l == 0) ? in_q     : questionA;
        float* gloss2_dst = (l == 0) ? glossB    : out_gloss;
        float* clip1_dst  = (l == 0) ? clipA     : out_clip;
        float* q1_dst     = (l == 0) ? questionA : out_q;
        const float* fW  = fusW  + (size_t)l*4*FF;
        const float* fU  = fusU  + (size_t)l*4*FF;
        const float* fWf = fusWf + (size_t)l*4*FF;
        const float* fUf = fusUf + (size_t)l*4*FF;

        gemm_adjT_k<<<dim3(8, NC/64, NB), 256, 0, stream>>>(adj_gc, gloss_old, agg, NG, NC);
        run_fusion(clip_old, agg, NC, fW+0*FF, fU+0*FF, fWf+0*FF, fUf+0*FF, clip1_dst);
        run_attn(gloss_old, NG, clip_old, NC, adj_gc, NG*NC, NC, 1,
                 c2gW + l*HFD, c2ga1 + l*HD, c2ga2 + l*HD, agg);
        run_fusion(gloss_old, agg, NG, fW+1*FF, fU+1*FF, fWf+1*FF, fUf+1*FF, glossA);
        run_attn(q_old, NQ, gloss_old, NG, adj_gq, NG*NQ, 1, NQ,
                 g2qW + l*HFD, g2qa1 + l*HD, g2qa2 + l*HD, agg);
        run_fusion(q_old, agg, NQ, fW+2*FF, fU+2*FF, fWf+2*FF, fUf+2*FF, q1_dst);
        run_attn(gloss_old, NG, q_old, NQ, adj_gq, NG*NQ, NQ, 1,
                 q2gW + l*HFD, q2ga1 + l*HD, q2ga2 + l*HD, agg);
        run_fusion(glossA, agg, NG, fW+3*FF, fU+3*FF, fWf+3*FF, fUf+3*FF, gloss2_dst);
    }
}

// Round 6
// 1432.918 us; speedup vs baseline: 3.6784x; 2.7082x over previous
//
#include <hip/hip_runtime.h>
#include <math.h>

#define NFEAT 512
#define NHEADS 8
#define HDIM 64
#define NB 4
#define NG 1024
#define NC 1024
#define NQ 256
#define NEGV -9e15f
#define CHUNKS 16
#define FF ((size_t)NFEAT*NFEAT)

typedef _Float16 v8h __attribute__((ext_vector_type(8)));
typedef float v4f __attribute__((ext_vector_type(4)));
#define MFMA16(a,b,c) __builtin_amdgcn_mfma_f32_16x16x32_f16((a),(b),(c),0,0,0)

__device__ __forceinline__ float lrelu(float x){ return fmaxf(x, 0.2f*x); }
__device__ __forceinline__ unsigned short f2h(float x){ union{_Float16 h; unsigned short u;} v; v.h = (_Float16)x; return v.u; }
__device__ __forceinline__ float h2f(unsigned short u){ union{_Float16 h; unsigned short u;} v; v.u = u; return (float)v.h; }

// ============ prep: fp32 -> fp16 flat ============
__global__ __launch_bounds__(256) void cvt_h_k(const float* __restrict__ src, unsigned short* __restrict__ dst){
    int idx = blockIdx.x*256 + threadIdx.x;
    const float4* s = (const float4*)(src + (size_t)idx*8);
    float4 a = s[0], b = s[1];
    ushort4 p0{f2h(a.x),f2h(a.y),f2h(a.z),f2h(a.w)};
    ushort4 p1{f2h(b.x),f2h(b.y),f2h(b.z),f2h(b.w)};
    *(ushort4*)(dst + (size_t)idx*8) = p0;
    *(ushort4*)(dst + (size_t)idx*8 + 4) = p1;
}

// ============ prep: fp32 -> fp16 hi/lo flat ============
__global__ __launch_bounds__(256) void cvt_hl_k(const float* __restrict__ src,
    unsigned short* __restrict__ dstHi, unsigned short* __restrict__ dstLo){
    int idx = blockIdx.x*256 + threadIdx.x;
    const float4* s = (const float4*)(src + (size_t)idx*8);
    float4 a = s[0], b = s[1];
    float x[8] = {a.x,a.y,a.z,a.w,b.x,b.y,b.z,b.w};
    unsigned short hi[8], lo[8];
    #pragma unroll
    for (int j = 0; j < 8; ++j){ hi[j] = f2h(x[j]); lo[j] = f2h(x[j] - h2f(hi[j])); }
    *(ushort4*)(dstHi + (size_t)idx*8)     = ushort4{hi[0],hi[1],hi[2],hi[3]};
    *(ushort4*)(dstHi + (size_t)idx*8 + 4) = ushort4{hi[4],hi[5],hi[6],hi[7]};
    *(ushort4*)(dstLo + (size_t)idx*8)     = ushort4{lo[0],lo[1],lo[2],lo[3]};
    *(ushort4*)(dstLo + (size_t)idx*8 + 4) = ushort4{lo[4],lo[5],lo[6],lo[7]};
}

// ============ prep: fusion weights -> transposed fp16 hi/lo, all 32 matrices ============
__global__ __launch_bounds__(256) void wtT_k(const float* __restrict__ w0, const float* __restrict__ w1,
    const float* __restrict__ w2, const float* __restrict__ w3,
    unsigned short* __restrict__ dstHi, unsigned short* __restrict__ dstLo){
    int bx = blockIdx.x;
    int mat = bx >> 6, t = bx & 63;
    int a = mat & 3, li = mat >> 2;
    const float* src = (a==0?w0:a==1?w1:a==2?w2:w3) + (size_t)li*FF;
    int fo0 = (t>>3)*64, fi0 = (t&7)*64;
    __shared__ float sT[64][65];
    int tid = threadIdx.x;
    #pragma unroll
    for (int it = 0; it < 4; ++it){
        int idx = it*256 + tid;
        int r = idx >> 4, c4 = idx & 15;
        float4 v = *(const float4*)(src + (size_t)(fi0+r)*512 + fo0 + c4*4);
        sT[r][c4*4+0]=v.x; sT[r][c4*4+1]=v.y; sT[r][c4*4+2]=v.z; sT[r][c4*4+3]=v.w;
    }
    __syncthreads();
    #pragma unroll
    for (int it = 0; it < 2; ++it){
        int idx = it*256 + tid;
        int dd = idx >> 3, c8 = idx & 7;
        unsigned short hi[8], lo[8];
        #pragma unroll
        for (int j = 0; j < 8; ++j){
            float x = sT[c8*8+j][dd];
            hi[j] = f2h(x);
            lo[j] = f2h(x - h2f(hi[j]));
        }
        size_t oo = (size_t)mat*FF + (size_t)(fo0+dd)*512 + fi0 + c8*8;
        *(ushort4*)(dstHi+oo)   = ushort4{hi[0],hi[1],hi[2],hi[3]};
        *(ushort4*)(dstHi+oo+4) = ushort4{hi[4],hi[5],hi[6],hi[7]};
        *(ushort4*)(dstLo+oo)   = ushort4{lo[0],lo[1],lo[2],lo[3]};
        *(ushort4*)(dstLo+oo+4) = ushort4{lo[4],lo[5],lo[6],lo[7]};
    }
}

// ============ prep: attention W [H,F,D] -> WflatT [h*64+d][f] fp16 ============
__global__ __launch_bounds__(256) void repackT_W_k(const float* __restrict__ W, unsigned short* __restrict__ WT){
    int bx = blockIdx.x;
    int h = bx >> 3, f0 = (bx & 7)*64;
    __shared__ float sT[64][65];
    int tid = threadIdx.x;
    #pragma unroll
    for (int it = 0; it < 4; ++it){
        int idx = it*256 + tid;
        int r = idx >> 4, c4 = idx & 15;
        float4 v = *(const float4*)(W + ((size_t)h*512 + f0 + r)*64 + c4*4);
        sT[r][c4*4+0]=v.x; sT[r][c4*4+1]=v.y; sT[r][c4*4+2]=v.z; sT[r][c4*4+3]=v.w;
    }
    __syncthreads();
    #pragma unroll
    for (int it = 0; it < 2; ++it){
        int idx = it*256 + tid;
        int dd = idx >> 3, c8 = idx & 7;
        ushort4 p0{f2h(sT[c8*8+0][dd]),f2h(sT[c8*8+1][dd]),f2h(sT[c8*8+2][dd]),f2h(sT[c8*8+3][dd])};
        ushort4 p1{f2h(sT[c8*8+4][dd]),f2h(sT[c8*8+5][dd]),f2h(sT[c8*8+6][dd]),f2h(sT[c8*8+7][dd])};
        unsigned short* o = WT + ((size_t)h*64 + dd)*512 + f0 + c8*8;
        *(ushort4*)o = p0; *(ushort4*)(o+4) = p1;
    }
}

// ============ prep: adj_gc [b][g][c] int -> adjT fp16 [b][c][g] ============
__global__ __launch_bounds__(256) void adjT_h_k(const int* __restrict__ adj, unsigned short* __restrict__ dst){
    int b = blockIdx.z;
    int c0 = blockIdx.x*64, g0 = blockIdx.y*64;
    __shared__ int sI[64][65];
    int tid = threadIdx.x;
    #pragma unroll
    for (int it = 0; it < 4; ++it){
        int idx = it*256 + tid;
        int r = idx >> 4, c4 = idx & 15;
        int4 v = *(const int4*)(adj + ((size_t)b*NG + g0 + r)*NC + c0 + c4*4);
        sI[r][c4*4+0]=v.x; sI[r][c4*4+1]=v.y; sI[r][c4*4+2]=v.z; sI[r][c4*4+3]=v.w;
    }
    __syncthreads();
    #pragma unroll
    for (int it = 0; it < 2; ++it){
        int idx = it*256 + tid;
        int dd = idx >> 3, c8 = idx & 7;
        ushort4 p0, p1;
        #pragma unroll
        for (int j = 0; j < 4; ++j) (&p0.x)[j] = sI[c8*8+j][dd] > 0 ? (unsigned short)0x3C00 : (unsigned short)0;
        #pragma unroll
        for (int j = 0; j < 4; ++j) (&p1.x)[j] = sI[c8*8+4+j][dd] > 0 ? (unsigned short)0x3C00 : (unsigned short)0;
        unsigned short* o = dst + ((size_t)b*NC + c0 + dd)*NG + g0 + c8*8;
        *(ushort4*)o = p0; *(ushort4*)(o+4) = p1;
    }
}

// ============ prep: adj_gq [b][g][q] int -> adjT int [b][q][g] ============
__global__ __launch_bounds__(256) void adjT_int_k(const int* __restrict__ adj, int* __restrict__ dst){
    int b = blockIdx.z;
    int q0 = blockIdx.x*64, g0 = blockIdx.y*64;
    __shared__ int sI[64][65];
    int tid = threadIdx.x;
    #pragma unroll
    for (int it = 0; it < 4; ++it){
        int idx = it*256 + tid;
        int r = idx >> 4, c4 = idx & 15;
        int4 v = *(const int4*)(adj + ((size_t)b*NG + g0 + r)*NQ + q0 + c4*4);
        sI[r][c4*4+0]=v.x; sI[r][c4*4+1]=v.y; sI[r][c4*4+2]=v.z; sI[r][c4*4+3]=v.w;
    }
    __syncthreads();
    #pragma unroll
    for (int it = 0; it < 4; ++it){
        int idx = it*256 + tid;
        int dd = idx >> 4, c4 = idx & 15;
        int4 v{sI[c4*4+0][dd], sI[c4*4+1][dd], sI[c4*4+2][dd], sI[c4*4+3][dd]};
        *(int4*)(dst + ((size_t)b*NQ + q0 + dd)*NG + g0 + c4*4) = v;
    }
}

// ============ prep: fp32 act [b][rows][512] -> transposed hi/lo fp16 [b][512][rows] ============
__global__ __launch_bounds__(256) void actT_hl_k(const float* __restrict__ src,
    unsigned short* __restrict__ dstHi, unsigned short* __restrict__ dstLo, int Nrows){
    int b = blockIdx.z;
    int f0 = blockIdx.x*64, g0 = blockIdx.y*64;
    __shared__ float sF[64][65];
    int tid = threadIdx.x;
    #pragma unroll
    for (int it = 0; it < 4; ++it){
        int idx = it*256 + tid;
        int r = idx >> 4, c4 = idx & 15;
        float4 v = *(const float4*)(src + ((size_t)b*Nrows + g0 + r)*512 + f0 + c4*4);
        sF[r][c4*4+0]=v.x; sF[r][c4*4+1]=v.y; sF[r][c4*4+2]=v.z; sF[r][c4*4+3]=v.w;
    }
    __syncthreads();
    #pragma unroll
    for (int it = 0; it < 2; ++it){
        int idx = it*256 + tid;
        int dd = idx >> 3, c8 = idx & 7;
        unsigned short hi[8], lo[8];
        #pragma unroll
        for (int j = 0; j < 8; ++j){
            float x = sF[c8*8+j][dd];
            hi[j] = f2h(x);
            lo[j] = f2h(x - h2f(hi[j]));
        }
        size_t oo = ((size_t)b*512 + f0 + dd)*Nrows + g0 + c8*8;
        *(ushort4*)(dstHi+oo)   = ushort4{hi[0],hi[1],hi[2],hi[3]};
        *(ushort4*)(dstHi+oo+4) = ushort4{hi[4],hi[5],hi[6],hi[7]};
        *(ushort4*)(dstLo+oo)   = ushort4{lo[0],lo[1],lo[2],lo[3]};
        *(ushort4*)(dstLo+oo+4) = ushort4{lo[4],lo[5],lo[6],lo[7]};
    }
}

// ============ wa[h,f] = sum_d W[h,f,d]*a[h,d] ============
__global__ __launch_bounds__(256) void wa_k(const float* __restrict__ W, const float* __restrict__ a1,
                                            const float* __restrict__ a2,
                                            float* __restrict__ wa1, float* __restrict__ wa2){
    int idx = blockIdx.x*256 + threadIdx.x;
    int h = idx >> 9;
    const float* Wp = W + (size_t)idx*64;
    float s1 = 0.f, s2 = 0.f;
    #pragma unroll
    for (int d = 0; d < 64; ++d){ float w = Wp[d]; s1 += w*a1[(h<<6)+d]; s2 += w*a2[(h<<6)+d]; }
    wa1[idx] = s1; wa2[idx] = s2;
}

// ============ scores from fp16 X ============
__global__ __launch_bounds__(256) void scores_h_k(const unsigned short* __restrict__ X, const float* __restrict__ wa,
                                                  float* __restrict__ sc){
    int lane = threadIdx.x & 63;
    int row  = blockIdx.x*4 + (threadIdx.x >> 6);
    const unsigned short* Xr = X + (size_t)row*NFEAT;
    float p[NHEADS];
    #pragma unroll
    for (int h = 0; h < NHEADS; ++h) p[h] = 0.f;
    #pragma unroll
    for (int c = 0; c < 8; ++c){
        float x = h2f(Xr[(c<<6) + lane]);
        #pragma unroll
        for (int h = 0; h < NHEADS; ++h) p[h] += x * wa[(h<<9) + (c<<6) + lane];
    }
    #pragma unroll
    for (int h = 0; h < NHEADS; ++h){
        float v = p[h];
        #pragma unroll
        for (int off = 32; off > 0; off >>= 1) v += __shfl_xor(v, off);
        if (lane == 0) sc[(size_t)row*NHEADS + h] = v;
    }
}

// ============ colmax partial / final ============
__global__ __launch_bounds__(256) void colmax_part_k(const int* __restrict__ adj, long bstride, int ns,
    const float* __restrict__ qs, float* __restrict__ pmax, int N, int M){
    int b = blockIdx.z, ch = blockIdx.y;
    int ml = threadIdx.x & 63; int m = blockIdx.x*64 + ml;
    int g = threadIdx.x >> 6;
    int chunk = N / CHUNKS, subl = chunk >> 2;
    int n0 = ch*chunk + g*subl, n1 = n0 + subl;
    const int* adjb = adj + (size_t)b*bstride;
    float mx[8];
    #pragma unroll
    for (int h = 0; h < 8; ++h) mx[h] = -INFINITY;
    for (int n = n0; n < n1; ++n){
        int a = adjb[(size_t)n*ns + m];
        const float* qr = qs + ((size_t)b*N + n)*8;
        #pragma unroll
        for (int h = 0; h < 8; ++h){ float qv = qr[h]; if (a > 0) mx[h] = fmaxf(mx[h], qv); }
    }
    __shared__ float smx[4][64][8];
    #pragma unroll
    for (int h = 0; h < 8; ++h) smx[g][ml][h] = mx[h];
    __syncthreads();
    if (g == 0){
        #pragma unroll
        for (int h = 0; h < 8; ++h){
            float v = fmaxf(fmaxf(smx[0][ml][h], smx[1][ml][h]), fmaxf(smx[2][ml][h], smx[3][ml][h]));
            pmax[(((size_t)b*CHUNKS + ch)*M + m)*8 + h] = v;
        }
    }
}

__global__ __launch_bounds__(256) void colmax_fin_k(const float* __restrict__ pmax, const float* __restrict__ ks,
    float* __restrict__ cmax, int M){
    int idx = blockIdx.x*256 + threadIdx.x;
    int m8 = M*8;
    int b = idx / m8;
    size_t base = (size_t)b*CHUNKS*m8 + (idx - (size_t)b*m8);
    float mx = -INFINITY;
    #pragma unroll
    for (int ch = 0; ch < CHUNKS; ++ch) mx = fmaxf(mx, pmax[base + (size_t)ch*m8]);
    cmax[idx] = (mx == -INFINITY) ? NEGV : lrelu(mx + ks[idx]);
}

__global__ __launch_bounds__(256) void colsum_part_k(const int* __restrict__ adj, long bstride, int ns,
    const float* __restrict__ qs, const float* __restrict__ ks, const float* __restrict__ cmax,
    float* __restrict__ psum, int N, int M){
    int b = blockIdx.z, ch = blockIdx.y;
    int ml = threadIdx.x & 63; int m = blockIdx.x*64 + ml;
    int g = threadIdx.x >> 6;
    int chunk = N / CHUNKS, subl = chunk >> 2;
    int n0 = ch*chunk + g*subl, n1 = n0 + subl;
    const int* adjb = adj + (size_t)b*bstride;
    float ksv[8], cmv[8], s[8];
    size_t mo = ((size_t)b*M + m)*8;
    #pragma unroll
    for (int h = 0; h < 8; ++h){ ksv[h] = ks[mo+h]; cmv[h] = cmax[mo+h]; s[h] = 0.f; }
    for (int n = n0; n < n1; ++n){
        int a = adjb[(size_t)n*ns + m];
        const float* qr = qs + ((size_t)b*N + n)*8;
        #pragma unroll
        for (int h = 0; h < 8; ++h){
            float e = (a > 0) ? lrelu(qr[h] + ksv[h]) : NEGV;
            s[h] += expf(e - cmv[h]);
        }
    }
    __shared__ float ssm[4][64][8];
    #pragma unroll
    for (int h = 0; h < 8; ++h) ssm[g][ml][h] = s[h];
    __syncthreads();
    if (g == 0){
        #pragma unroll
        for (int h = 0; h < 8; ++h){
            float v = ssm[0][ml][h] + ssm[1][ml][h] + ssm[2][ml][h] + ssm[3][ml][h];
            psum[(((size_t)b*CHUNKS + ch)*M + m)*8 + h] = v;
        }
    }
}

__global__ __launch_bounds__(256) void colsum_fin_k(const float* __restrict__ psum, float* __restrict__ isum, int M){
    int idx = blockIdx.x*256 + threadIdx.x;
    int m8 = M*8;
    int b = idx / m8;
    size_t base = (size_t)b*CHUNKS*m8 + (idx - (size_t)b*m8);
    float S = 0.f;
    #pragma unroll
    for (int ch = 0; ch < CHUNKS; ++ch) S += psum[base + (size_t)ch*m8];
    isum[idx] = 1.f/S;
}

// ============ [b][m][8] -> [b][8][M] repack of softmax stats ============
__global__ __launch_bounds__(256) void stat_repack_k(const float* __restrict__ ks, const float* __restrict__ cm,
    const float* __restrict__ is, float* __restrict__ ksh, float* __restrict__ cmh, float* __restrict__ ish, int M){
    int idx = blockIdx.x*256 + threadIdx.x;
    int m8 = M*8;
    int b = idx / m8, rem = idx - b*m8;
    int m = rem >> 3, h = rem & 7;
    size_t o = ((size_t)b*8 + h)*M + m;
    ksh[o] = ks[idx]; cmh[o] = cm[idx]; ish[o] = is[idx];
}

// ============ fused fusion MFMA with optional hi/lo passes ============
// pass0: (a,b,Whi); pass1 (if aLo||bLo): (aLo,bLo,Whi); pass2 (if WT4lo): (a,b,Wlo)
__global__ __launch_bounds__(256) void fusion_mfma_k(
    const unsigned short* __restrict__ aB, const unsigned short* __restrict__ aLo,
    const unsigned short* __restrict__ bB, const unsigned short* __restrict__ bLo,
    const unsigned short* __restrict__ WT4, const unsigned short* __restrict__ WT4lo,
    unsigned short* __restrict__ dst, unsigned short* __restrict__ dstLo,
    unsigned short* __restrict__ dstT, unsigned short* __restrict__ dstTLo,
    float* __restrict__ dstF, int rowsPB){
    int b = blockIdx.z;
    int r0 = blockIdx.y*128, c0 = blockIdx.x*64;
    int tid = threadIdx.x;
    __shared__ unsigned short aS[128*56];
    __shared__ unsigned short bS[128*56];
    __shared__ unsigned short wS[4*64*56];
    size_t actOff = (size_t)b*rowsPB*512;
    const unsigned short* aG = aB + actOff;
    int w = tid >> 6, lane = tid & 63;
    int lrow = lane & 15, quad = lane >> 4;
    v4f accN[2][4], accF[2][4];
    #pragma unroll
    for (int r = 0; r < 2; ++r)
        #pragma unroll
        for (int cf = 0; cf < 4; ++cf){ accN[r][cf] = (v4f)0.f; accF[r][cf] = (v4f)0.f; }
    bool hasLo = (aLo != nullptr) || (bLo != nullptr);
    for (int p = 0; p < 3; ++p){
        const unsigned short *Ap, *Bp, *Wp;
        if (p == 0){ Ap = aB; Bp = bB; Wp = WT4; }
        else if (p == 1){ if (!hasLo) continue; Ap = aLo; Bp = bLo; Wp = WT4; }
        else { if (!WT4lo) continue; Ap = aB; Bp = bB; Wp = WT4lo; }
        const unsigned short* ApG = Ap ? Ap + actOff : nullptr;
        const unsigned short* BpG = Bp ? Bp + actOff : nullptr;
        for (int kt = 0; kt < 512; kt += 32){
            __syncthreads();
            uint4 za; za.x = za.y = za.z = za.w = 0u;
            #pragma unroll
            for (int it = 0; it < 2; ++it){
                int idx = it*256 + tid;
                int row = idx >> 2, c4 = idx & 3;
                *(uint4*)&aS[row*56 + c4*8] = ApG ? *(const uint4*)(ApG + (size_t)(r0+row)*512 + kt + c4*8) : za;
                *(uint4*)&bS[row*56 + c4*8] = BpG ? *(const uint4*)(BpG + (size_t)(r0+row)*512 + kt + c4*8) : za;
            }
            #pragma unroll
            for (int it = 0; it < 4; ++it){
                int idx = it*256 + tid;
                int mat = idx >> 8, row = (idx >> 2) & 63, c4 = idx & 3;
                *(uint4*)&wS[(mat*64+row)*56 + c4*8] =
                    *(const uint4*)(Wp + ((size_t)mat*512 + c0 + row)*512 + kt + c4*8);
            }
            __syncthreads();
            v8h af[2], bf[2];
            #pragma unroll
            for (int r = 0; r < 2; ++r){
                af[r] = *(const v8h*)&aS[(w*32 + r*16 + lrow)*56 + quad*8];
                bf[r] = *(const v8h*)&bS[(w*32 + r*16 + lrow)*56 + quad*8];
            }
            v8h wf[4][4];
            #pragma unroll
            for (int mat = 0; mat < 4; ++mat)
                #pragma unroll
                for (int cf = 0; cf < 4; ++cf)
                    wf[mat][cf] = *(const v8h*)&wS[(mat*64 + cf*16 + lrow)*56 + quad*8];
            #pragma unroll
            for (int r = 0; r < 2; ++r)
                #pragma unroll
                for (int cf = 0; cf < 4; ++cf){
                    accN[r][cf] = MFMA16(af[r], wf[0][cf], accN[r][cf]);
                    accN[r][cf] = MFMA16(bf[r], wf[1][cf], accN[r][cf]);
                    accF[r][cf] = MFMA16(af[r], wf[2][cf], accF[r][cf]);
                    accF[r][cf] = MFMA16(bf[r], wf[3][cf], accF[r][cf]);
                }
        }
    }
    #pragma unroll
    for (int r = 0; r < 2; ++r)
        #pragma unroll
        for (int cf = 0; cf < 4; ++cf){
            int colg = c0 + cf*16 + lrow;
            int rbase = r0 + w*32 + r*16 + quad*4;
            float o4[4];
            #pragma unroll
            for (int reg = 0; reg < 4; ++reg){
                float f = 1.f/(1.f + expf(-accF[r][cf][reg]));
                size_t ai = (size_t)(rbase+reg)*512 + colg;
                float ao = h2f(aG[ai]);
                if (aLo) ao += h2f(aLo[actOff + ai]);
                o4[reg] = f*accN[r][cf][reg] + (1.f - f)*ao;
                size_t oo = ((size_t)b*rowsPB + rbase + reg)*512 + colg;
                unsigned short hv = f2h(o4[reg]);
                dst[oo] = hv;
                if (dstLo) dstLo[oo] = f2h(o4[reg] - h2f(hv));
                if (dstF) dstF[oo] = o4[reg];
            }
            if (dstT){
                unsigned short h0 = f2h(o4[0]), h1 = f2h(o4[1]), h2 = f2h(o4[2]), h3 = f2h(o4[3]);
                ushort4 pk{h0,h1,h2,h3};
                size_t to = ((size_t)b*512 + colg)*rowsPB + rbase;
                *(ushort4*)&dstT[to] = pk;
                if (dstTLo){
                    ushort4 pl{f2h(o4[0]-h2f(h0)), f2h(o4[1]-h2f(h1)),
                               f2h(o4[2]-h2f(h2)), f2h(o4[3]-h2f(h3))};
                    *(ushort4*)&dstTLo[to] = pl;
                }
            }
        }
}

// ============ generic MFMA GEMM: C[b] = A[b]@BT^T (+ A[b]@BT2^T) ============
__global__ __launch_bounds__(256) void gemmT_mfma_k(
    const unsigned short* __restrict__ A, size_t aStride,
    const unsigned short* __restrict__ BT, const unsigned short* __restrict__ BT2, size_t bStride,
    int K, int rowsPB,
    unsigned short* __restrict__ outRM, unsigned short* __restrict__ outLo,
    unsigned short* __restrict__ outT){
    int b = blockIdx.z;
    int r0 = blockIdx.y*128, c0 = blockIdx.x*64;
    int tid = threadIdx.x;
    __shared__ unsigned short aS[128*56];
    __shared__ unsigned short bS[64*56];
    const unsigned short* aG = A + (size_t)b*aStride;
    int w = tid >> 6, lane = tid & 63;
    int lrow = lane & 15, quad = lane >> 4;
    v4f acc[2][4];
    #pragma unroll
    for (int r = 0; r < 2; ++r)
        #pragma unroll
        for (int cf = 0; cf < 4; ++cf) acc[r][cf] = (v4f)0.f;
    for (int p = 0; p < 2; ++p){
        if (p == 1 && BT2 == nullptr) break;
        const unsigned short* bG = (p ? BT2 : BT) + (size_t)b*bStride;
        for (int kt = 0; kt < K; kt += 32){
            __syncthreads();
            #pragma unroll
            for (int it = 0; it < 2; ++it){
                int idx = it*256 + tid;
                int row = idx >> 2, c4 = idx & 3;
                *(uint4*)&aS[row*56 + c4*8] = *(const uint4*)(aG + (size_t)(r0+row)*K + kt + c4*8);
            }
            {
                int row = tid >> 2, c4 = tid & 3;
                *(uint4*)&bS[row*56 + c4*8] = *(const uint4*)(bG + (size_t)(c0+row)*K + kt + c4*8);
            }
            __syncthreads();
            v8h af[2], bf[4];
            #pragma unroll
            for (int r = 0; r < 2; ++r) af[r] = *(const v8h*)&aS[(w*32 + r*16 + lrow)*56 + quad*8];
            #pragma unroll
            for (int cf = 0; cf < 4; ++cf) bf[cf] = *(const v8h*)&bS[(cf*16 + lrow)*56 + quad*8];
            #pragma unroll
            for (int r = 0; r < 2; ++r)
                #pragma unroll
                for (int cf = 0; cf < 4; ++cf)
                    acc[r][cf] = MFMA16(af[r], bf[cf], acc[r][cf]);
        }
    }
    #pragma unroll
    for (int r = 0; r < 2; ++r)
        #pragma unroll
        for (int cf = 0; cf < 4; ++cf){
            int colg = c0 + cf*16 + lrow;
            int rbase = r0 + w*32 + r*16 + quad*4;
            if (outRM){
                #pragma unroll
                for (int reg = 0; reg < 4; ++reg){
                    float v = acc[r][cf][reg];
                    unsigned short hv = f2h(v);
                    size_t oo = ((size_t)b*rowsPB + rbase + reg)*512 + colg;
                    outRM[oo] = hv;
                    if (outLo) outLo[oo] = f2h(v - h2f(hv));
                }
            }
            if (outT){
                ushort4 pk{f2h(acc[r][cf][0]), f2h(acc[r][cf][1]), f2h(acc[r][cf][2]), f2h(acc[r][cf][3])};
                *(ushort4*)&outT[((size_t)b*512 + colg)*rowsPB + rbase] = pk;
            }
        }
}

// ============ attention output MFMA ============
__global__ __launch_bounds__(256) void attn_mfma_k(const int* __restrict__ adj, long bstride, int ns,
    const float* __restrict__ qs, const float* __restrict__ ksh, const float* __restrict__ cmh,
    const float* __restrict__ ish, const unsigned short* __restrict__ WkT,
    unsigned short* __restrict__ outp, int N, int M){
    int bh = blockIdx.y; int b = bh >> 3, h = bh & 7;
    int n0 = blockIdx.x*64;
    int tid = threadIdx.x;
    __shared__ unsigned short pS[64*56];
    __shared__ unsigned short wS[64*56];
    __shared__ float qsS[64];
    if (tid < 64) qsS[tid] = qs[((size_t)b*N + n0 + tid)*8 + h];
    const int* adjb = adj + (size_t)b*bstride;
    const float* ksb = ksh + ((size_t)b*8 + h)*M;
    const float* cmb = cmh + ((size_t)b*8 + h)*M;
    const float* isb = ish + ((size_t)b*8 + h)*M;
    const unsigned short* wkb = WkT + ((size_t)b*512 + h*64)*M;
    int w = tid >> 6, lane = tid & 63;
    int lrow = lane & 15, quad = lane >> 4;
    int pn = tid >> 2, pm = (tid & 3)*8;
    v4f acc[4];
    #pragma unroll
    for (int cf = 0; cf < 4; ++cf) acc[cf] = (v4f)0.f;
    for (int mt = 0; mt < M; mt += 32){
        __syncthreads();
        *(uint4*)&wS[(tid>>2)*56 + (tid&3)*8] = *(const uint4*)(wkb + (size_t)(tid>>2)*M + mt + (tid&3)*8);
        const int* arow = adjb + (size_t)(n0+pn)*ns + mt + pm;
        int4 a0 = *(const int4*)arow;
        int4 a1 = *(const int4*)(arow + 4);
        float4 k0 = *(const float4*)(ksb + mt + pm), k1 = *(const float4*)(ksb + mt + pm + 4);
        float4 c0v = *(const float4*)(cmb + mt + pm), c1v = *(const float4*)(cmb + mt + pm + 4);
        float4 i0 = *(const float4*)(isb + mt + pm), i1 = *(const float4*)(isb + mt + pm + 4);
        float qv = qsS[pn];
        float p[8];
        const int* aa0 = &a0.x; const int* aa1 = &a1.x;
        const float* kk0 = &k0.x; const float* kk1 = &k1.x;
        const float* cc0 = &c0v.x; const float* cc1 = &c1v.x;
        const float* ii0 = &i0.x; const float* ii1 = &i1.x;
        #pragma unroll
        for (int j = 0; j < 4; ++j){
            float e = (aa0[j] > 0) ? lrelu(qv + kk0[j]) : NEGV;
            p[j] = expf(e - cc0[j]) * ii0[j];
        }
        #pragma unroll
        for (int j = 0; j < 4; ++j){
            float e = (aa1[j] > 0) ? lrelu(qv + kk1[j]) : NEGV;
            p[4+j] = expf(e - cc1[j]) * ii1[j];
        }
        ushort4 pk0{f2h(p[0]), f2h(p[1]), f2h(p[2]), f2h(p[3])};
        ushort4 pk1{f2h(p[4]), f2h(p[5]), f2h(p[6]), f2h(p[7])};
        *(ushort4*)&pS[pn*56 + pm] = pk0;
        *(ushort4*)&pS[pn*56 + pm + 4] = pk1;
        __syncthreads();
        v8h af = *(const v8h*)&pS[(w*16 + lrow)*56 + quad*8];
        #pragma unroll
        for (int cf = 0; cf < 4; ++cf){
            v8h bf = *(const v8h*)&wS[(cf*16 + lrow)*56 + quad*8];
            acc[cf] = MFMA16(af, bf, acc[cf]);
        }
    }
    #pragma unroll
    for (int cf = 0; cf < 4; ++cf){
        int colg = h*64 + cf*16 + lrow;
        int rbase = n0 + w*16 + quad*4;
        #pragma unroll
        for (int reg = 0; reg < 4; ++reg){
            float v = acc[cf][reg];
            v = (v > 0.f) ? v : expm1f(v);
            outp[((size_t)b*N + rbase + reg)*512 + colg] = f2h(v);
        }
    }
}

extern "C" void kernel_launch(void* const* d_in, const int* in_sizes, int n_in,
                              void* d_out, int out_size, void* d_ws, size_t ws_size,
                              hipStream_t stream){
    const float* in_gloss = (const float*)d_in[0];
    const float* in_clip  = (const float*)d_in[1];
    const float* in_q     = (const float*)d_in[2];
    const int*   adj_gc   = (const int*)d_in[3];
    const int*   adj_gq   = (const int*)d_in[4];
    const float* c2gW  = (const float*)d_in[5];
    const float* c2ga1 = (const float*)d_in[6];
    const float* c2ga2 = (const float*)d_in[7];
    const float* g2qW  = (const float*)d_in[8];
    const float* g2qa1 = (const float*)d_in[9];
    const float* g2qa2 = (const float*)d_in[10];
    const float* q2gW  = (const float*)d_in[11];
    const float* q2ga1 = (const float*)d_in[12];
    const float* q2ga2 = (const float*)d_in[13];
    const float* fusW  = (const float*)d_in[14];
    const float* fusU  = (const float*)d_in[15];
    const float* fusWf = (const float*)d_in[16];
    const float* fusUf = (const float*)d_in[17];
    float* out = (float*)d_out;
    float* out_gloss = out;
    float* out_clip  = out + (size_t)NB*NG*NFEAT;
    float* out_q     = out + (size_t)NB*NG*NFEAT*2;

    char* wsB = (char*)d_ws;
    size_t off = 0;
    auto alloc = [&](size_t bytes){ void* p = wsB + off; off += (bytes + 255) & ~(size_t)255; return p; };
    float* wa1   = (float*)alloc(4096*4);
    float* wa2   = (float*)alloc(4096*4);
    float* qsb   = (float*)alloc((size_t)NB*NG*8*4);
    float* ksb   = (float*)alloc((size_t)NB*NG*8*4);
    float* cmaxb = (float*)alloc((size_t)NB*NG*8*4);
    float* isumb = (float*)alloc((size_t)NB*NG*8*4);
    float* ksh   = (float*)alloc((size_t)NB*NG*8*4);
    float* cmh   = (float*)alloc((size_t)NB*NG*8*4);
    float* ish   = (float*)alloc((size_t)NB*NG*8*4);
    float* pmaxb = (float*)alloc((size_t)NB*CHUNKS*NG*8*4);
    float* psumb = (float*)alloc((size_t)NB*CHUNKS*NG*8*4);
    unsigned short* WflatT  = (unsigned short*)alloc((size_t)NFEAT*NFEAT*2);
    unsigned short* wtAll   = (unsigned short*)alloc((size_t)32*FF*2);
    unsigned short* wtAllLo = (unsigned short*)alloc((size_t)32*FF*2);
    unsigned short* adjTgc  = (unsigned short*)alloc((size_t)NB*NC*NG*2);
    unsigned short* g_bf0   = (unsigned short*)alloc((size_t)NB*NG*NFEAT*2);
    unsigned short* gLo0    = (unsigned short*)alloc((size_t)NB*NG*NFEAT*2);
    unsigned short* g_bf1   = (unsigned short*)alloc((size_t)NB*NG*NFEAT*2);
    unsigned short* gLo1    = (unsigned short*)alloc((size_t)NB*NG*NFEAT*2);
    unsigned short* gT      = (unsigned short*)alloc((size_t)NB*NFEAT*NG*2);
    unsigned short* gTlo    = (unsigned short*)alloc((size_t)NB*NFEAT*NG*2);
    unsigned short* gA_bf   = (unsigned short*)alloc((size_t)NB*NG*NFEAT*2);
    unsigned short* gALo    = (unsigned short*)alloc((size_t)NB*NG*NFEAT*2);
    unsigned short* c_bf0   = (unsigned short*)alloc((size_t)NB*NC*NFEAT*2);
    unsigned short* cLo0    = (unsigned short*)alloc((size_t)NB*NC*NFEAT*2);
    unsigned short* c_bf1   = (unsigned short*)alloc((size_t)NB*NC*NFEAT*2);
    unsigned short* cLo1    = (unsigned short*)alloc((size_t)NB*NC*NFEAT*2);
    unsigned short* q_bf0   = (unsigned short*)alloc((size_t)NB*NQ*NFEAT*2);
    unsigned short* q_bf1   = (unsigned short*)alloc((size_t)NB*NQ*NFEAT*2);
    unsigned short* agg_bf  = (unsigned short*)alloc((size_t)NB*NG*NFEAT*2);
    unsigned short* aggLo   = (unsigned short*)alloc((size_t)NB*NG*NFEAT*2);
    unsigned short* WkT     = (unsigned short*)alloc((size_t)NB*NFEAT*NG*2);
    int* adjTgq = (int*)alloc((size_t)NB*NQ*NG*4);
    (void)ws_size; (void)in_sizes; (void)n_in; (void)out_size;

    const size_t HFD = (size_t)NHEADS*NFEAT*HDIM;
    const size_t HD  = (size_t)NHEADS*HDIM;

    // ---- prep ----
    wtT_k<<<2048, 256, 0, stream>>>(fusW, fusU, fusWf, fusUf, wtAll, wtAllLo);
    adjT_h_k<<<dim3(NC/64, NG/64, NB), 256, 0, stream>>>(adj_gc, adjTgc);
    adjT_int_k<<<dim3(NQ/64, NG/64, NB), 256, 0, stream>>>(adj_gq, adjTgq);
    cvt_hl_k<<<(NB*NG*NFEAT)/2048, 256, 0, stream>>>(in_gloss, g_bf0, gLo0);
    cvt_hl_k<<<(NB*NC*NFEAT)/2048, 256, 0, stream>>>(in_clip,  c_bf0, cLo0);
    cvt_h_k<<<(NB*NQ*NFEAT)/2048, 256, 0, stream>>>(in_q,     q_bf0);
    actT_hl_k<<<dim3(8, NG/64, NB), 256, 0, stream>>>(in_gloss, gT, gTlo, NG);

    auto run_attn = [&](const unsigned short* qX, int N, const unsigned short* kvX, int M,
                        const int* adjp, long bstride, int ns,
                        const float* W, const float* a1, const float* a2, unsigned short* dst){
        repackT_W_k<<<64, 256, 0, stream>>>(W, WflatT);
        wa_k<<<16, 256, 0, stream>>>(W, a1, a2, wa1, wa2);
        scores_h_k<<<(NB*N)/4, 256, 0, stream>>>(qX, wa1, qsb);
        scores_h_k<<<(NB*M)/4, 256, 0, stream>>>(kvX, wa2, ksb);
        gemmT_mfma_k<<<dim3(8, M/128, NB), 256, 0, stream>>>(kvX, (size_t)M*512, WflatT, nullptr, 0,
                                                             512, M, nullptr, nullptr, WkT);
        colmax_part_k<<<dim3(M/64, CHUNKS, NB), 256, 0, stream>>>(adjp, bstride, ns, qsb, pmaxb, N, M);
        colmax_fin_k<<<(NB*M*8)/256, 256, 0, stream>>>(pmaxb, ksb, cmaxb, M);
        colsum_part_k<<<dim3(M/64, CHUNKS, NB), 256, 0, stream>>>(adjp, bstride, ns, qsb, ksb, cmaxb, psumb, N, M);
        colsum_fin_k<<<(NB*M*8)/256, 256, 0, stream>>>(psumb, isumb, M);
        stat_repack_k<<<(NB*M*8)/256, 256, 0, stream>>>(ksb, cmaxb, isumb, ksh, cmh, ish, M);
        attn_mfma_k<<<dim3(N/64, NB*8), 256, 0, stream>>>(adjp, bstride, ns, qsb, ksh, cmh, ish,
                                                          WkT, dst, N, M);
    };
    auto run_fusion = [&](const unsigned short* a, const unsigned short* aLo,
                          const unsigned short* bb, const unsigned short* bLo, int rows,
                          int l, int i, bool wlo,
                          unsigned short* dst, unsigned short* dstLo,
                          unsigned short* dstT, unsigned short* dstTLo, float* dstF){
        fusion_mfma_k<<<dim3(8, rows/128, NB), 256, 0, stream>>>(
            a, aLo, bb, bLo, wtAll + (size_t)((l*4 + i)*4)*FF,
            wlo ? wtAllLo + (size_t)((l*4 + i)*4)*FF : nullptr,
            dst, dstLo, dstT, dstTLo, dstF, rows);
    };

    for (int l = 0; l < 2; ++l){
        const unsigned short* g_cur = (l == 0) ? g_bf0 : g_bf1;
        const unsigned short* gLoC  = (l == 0) ? gLo0  : gLo1;
        const unsigned short* c_cur = (l == 0) ? c_bf0 : c_bf1;
        const unsigned short* cLoC  = (l == 0) ? cLo0  : cLo1;
        const unsigned short* q_cur = (l == 0) ? q_bf0 : q_bf1;
        unsigned short* g_nxt = (l == 0) ? g_bf1 : g_bf0;
        unsigned short* gLoN  = (l == 0) ? gLo1  : nullptr;
        unsigned short* c_nxt = (l == 0) ? c_bf1 : c_bf0;
        unsigned short* cLoN  = (l == 0) ? cLo1  : nullptr;
        unsigned short* q_nxt = (l == 0) ? q_bf1 : q_bf0;
        float* gF = (l == 1) ? out_gloss : nullptr;
        float* cF = (l == 1) ? out_clip  : nullptr;
        float* qF = (l == 1) ? out_q     : nullptr;

        // gloss_same = adj_gc^T @ gloss  (hi/lo B, hi/lo out)
        gemmT_mfma_k<<<dim3(8, NC/128, NB), 256, 0, stream>>>(adjTgc, (size_t)NC*NG, gT, gTlo,
                                                              (size_t)512*NG, NG, NC,
                                                              agg_bf, aggLo, nullptr);
        // clip_1 (3-pass hi/lo)
        run_fusion(c_cur, cLoC, agg_bf, aggLo, NC, l, 0, true,
                   c_nxt, cLoN, nullptr, nullptr, cF);
        // clip_agg = attn(q=gloss, kv=clip, adj_gc)
        run_attn(g_cur, NG, c_cur, NC, adj_gc, (long)NG*NC, NC,
                 c2gW + l*HFD, c2ga1 + l*HD, c2ga2 + l*HD, agg_bf);
        // gloss_1 (3-pass hi/lo: a-lo + weight-lo; b-lo absent)
        run_fusion(g_cur, gLoC, agg_bf, nullptr, NG, l, 1, true,
                   gA_bf, gALo, nullptr, nullptr, nullptr);
        // gloss_agg = attn(q=question, kv=gloss, adjT_gq)
        run_attn(q_cur, NQ, g_cur, NG, adjTgq, (long)NQ*NG, NG,
                 g2qW + l*HFD, g2qa1 + l*HD, g2qa2 + l*HD, agg_bf);
        // question_1 (single pass)
        run_fusion(q_cur, nullptr, agg_bf, nullptr, NQ, l, 2, false,
                   q_nxt, nullptr, nullptr, nullptr, qF);
        // question_agg = attn(q=gloss, kv=question, adj_gq)
        run_attn(g_cur, NG, q_cur, NQ, adj_gq, (long)NG*NQ, NQ,
                 q2gW + l*HFD, q2ga1 + l*HD, q2ga2 + l*HD, agg_bf);
        // gloss_2 (3-pass; emit hi/lo + transposed hi/lo for next layer's gloss_same)
        run_fusion(gA_bf, gALo, agg_bf, nullptr, NG, l, 3, true,
                   g_nxt, gLoN, (l == 0) ? gT : nullptr, (l == 0) ? gTlo : nullptr, gF);
    }
}

// Round 7
// 1412.352 us; speedup vs baseline: 3.7319x; 1.0146x over previous
//
#include <hip/hip_runtime.h>
#include <math.h>

#define NFEAT 512
#define NHEADS 8
#define HDIM 64
#define NB 4
#define NG 1024
#define NC 1024
#define NQ 256
#define NEGV -9e15f
#define CHUNKS 16
#define FF ((size_t)NFEAT*NFEAT)
#define LSTR 36   // LDS row stride (ushorts): 32 payload + 4 pad -> 18-bank step, conflict-free

typedef _Float16 v8h __attribute__((ext_vector_type(8)));
typedef float v4f __attribute__((ext_vector_type(4)));
#define MFMA16(a,b,c) __builtin_amdgcn_mfma_f32_16x16x32_f16((a),(b),(c),0,0,0)

__device__ __forceinline__ float lrelu(float x){ return fmaxf(x, 0.2f*x); }
__device__ __forceinline__ unsigned short f2h(float x){ union{_Float16 h; unsigned short u;} v; v.h = (_Float16)x; return v.u; }
__device__ __forceinline__ float h2f(unsigned short u){ union{_Float16 h; unsigned short u;} v; v.u = u; return (float)v.h; }

// ============ prep: fp32 -> fp16 flat ============
__global__ __launch_bounds__(256) void cvt_h_k(const float* __restrict__ src, unsigned short* __restrict__ dst){
    int idx = blockIdx.x*256 + threadIdx.x;
    const float4* s = (const float4*)(src + (size_t)idx*8);
    float4 a = s[0], b = s[1];
    ushort4 p0{f2h(a.x),f2h(a.y),f2h(a.z),f2h(a.w)};
    ushort4 p1{f2h(b.x),f2h(b.y),f2h(b.z),f2h(b.w)};
    *(ushort4*)(dst + (size_t)idx*8) = p0;
    *(ushort4*)(dst + (size_t)idx*8 + 4) = p1;
}

// ============ prep: fp32 -> fp16 hi/lo flat ============
__global__ __launch_bounds__(256) void cvt_hl_k(const float* __restrict__ src,
    unsigned short* __restrict__ dstHi, unsigned short* __restrict__ dstLo){
    int idx = blockIdx.x*256 + threadIdx.x;
    const float4* s = (const float4*)(src + (size_t)idx*8);
    float4 a = s[0], b = s[1];
    float x[8] = {a.x,a.y,a.z,a.w,b.x,b.y,b.z,b.w};
    unsigned short hi[8], lo[8];
    #pragma unroll
    for (int j = 0; j < 8; ++j){ hi[j] = f2h(x[j]); lo[j] = f2h(x[j] - h2f(hi[j])); }
    *(ushort4*)(dstHi + (size_t)idx*8)     = ushort4{hi[0],hi[1],hi[2],hi[3]};
    *(ushort4*)(dstHi + (size_t)idx*8 + 4) = ushort4{hi[4],hi[5],hi[6],hi[7]};
    *(ushort4*)(dstLo + (size_t)idx*8)     = ushort4{lo[0],lo[1],lo[2],lo[3]};
    *(ushort4*)(dstLo + (size_t)idx*8 + 4) = ushort4{lo[4],lo[5],lo[6],lo[7]};
}

// ============ prep: fusion weights -> transposed fp16 hi/lo, all 32 matrices ============
__global__ __launch_bounds__(256) void wtT_k(const float* __restrict__ w0, const float* __restrict__ w1,
    const float* __restrict__ w2, const float* __restrict__ w3,
    unsigned short* __restrict__ dstHi, unsigned short* __restrict__ dstLo){
    int bx = blockIdx.x;
    int mat = bx >> 6, t = bx & 63;
    int a = mat & 3, li = mat >> 2;
    const float* src = (a==0?w0:a==1?w1:a==2?w2:w3) + (size_t)li*FF;
    int fo0 = (t>>3)*64, fi0 = (t&7)*64;
    __shared__ float sT[64][65];
    int tid = threadIdx.x;
    #pragma unroll
    for (int it = 0; it < 4; ++it){
        int idx = it*256 + tid;
        int r = idx >> 4, c4 = idx & 15;
        float4 v = *(const float4*)(src + (size_t)(fi0+r)*512 + fo0 + c4*4);
        sT[r][c4*4+0]=v.x; sT[r][c4*4+1]=v.y; sT[r][c4*4+2]=v.z; sT[r][c4*4+3]=v.w;
    }
    __syncthreads();
    #pragma unroll
    for (int it = 0; it < 2; ++it){
        int idx = it*256 + tid;
        int dd = idx >> 3, c8 = idx & 7;
        unsigned short hi[8], lo[8];
        #pragma unroll
        for (int j = 0; j < 8; ++j){
            float x = sT[c8*8+j][dd];
            hi[j] = f2h(x);
            lo[j] = f2h(x - h2f(hi[j]));
        }
        size_t oo = (size_t)mat*FF + (size_t)(fo0+dd)*512 + fi0 + c8*8;
        *(ushort4*)(dstHi+oo)   = ushort4{hi[0],hi[1],hi[2],hi[3]};
        *(ushort4*)(dstHi+oo+4) = ushort4{hi[4],hi[5],hi[6],hi[7]};
        *(ushort4*)(dstLo+oo)   = ushort4{lo[0],lo[1],lo[2],lo[3]};
        *(ushort4*)(dstLo+oo+4) = ushort4{lo[4],lo[5],lo[6],lo[7]};
    }
}

// ============ prep: attention W [H,F,D] -> WflatT [h*64+d][f] fp16 ============
__global__ __launch_bounds__(256) void repackT_W_k(const float* __restrict__ W, unsigned short* __restrict__ WT){
    int bx = blockIdx.x;
    int h = bx >> 3, f0 = (bx & 7)*64;
    __shared__ float sT[64][65];
    int tid = threadIdx.x;
    #pragma unroll
    for (int it = 0; it < 4; ++it){
        int idx = it*256 + tid;
        int r = idx >> 4, c4 = idx & 15;
        float4 v = *(const float4*)(W + ((size_t)h*512 + f0 + r)*64 + c4*4);
        sT[r][c4*4+0]=v.x; sT[r][c4*4+1]=v.y; sT[r][c4*4+2]=v.z; sT[r][c4*4+3]=v.w;
    }
    __syncthreads();
    #pragma unroll
    for (int it = 0; it < 2; ++it){
        int idx = it*256 + tid;
        int dd = idx >> 3, c8 = idx & 7;
        ushort4 p0{f2h(sT[c8*8+0][dd]),f2h(sT[c8*8+1][dd]),f2h(sT[c8*8+2][dd]),f2h(sT[c8*8+3][dd])};
        ushort4 p1{f2h(sT[c8*8+4][dd]),f2h(sT[c8*8+5][dd]),f2h(sT[c8*8+6][dd]),f2h(sT[c8*8+7][dd])};
        unsigned short* o = WT + ((size_t)h*64 + dd)*512 + f0 + c8*8;
        *(ushort4*)o = p0; *(ushort4*)(o+4) = p1;
    }
}

// ============ prep: adj_gc [b][g][c] int -> adjT fp16 [b][c][g] ============
__global__ __launch_bounds__(256) void adjT_h_k(const int* __restrict__ adj, unsigned short* __restrict__ dst){
    int b = blockIdx.z;
    int c0 = blockIdx.x*64, g0 = blockIdx.y*64;
    __shared__ int sI[64][65];
    int tid = threadIdx.x;
    #pragma unroll
    for (int it = 0; it < 4; ++it){
        int idx = it*256 + tid;
        int r = idx >> 4, c4 = idx & 15;
        int4 v = *(const int4*)(adj + ((size_t)b*NG + g0 + r)*NC + c0 + c4*4);
        sI[r][c4*4+0]=v.x; sI[r][c4*4+1]=v.y; sI[r][c4*4+2]=v.z; sI[r][c4*4+3]=v.w;
    }
    __syncthreads();
    #pragma unroll
    for (int it = 0; it < 2; ++it){
        int idx = it*256 + tid;
        int dd = idx >> 3, c8 = idx & 7;
        ushort4 p0, p1;
        #pragma unroll
        for (int j = 0; j < 4; ++j) (&p0.x)[j] = sI[c8*8+j][dd] > 0 ? (unsigned short)0x3C00 : (unsigned short)0;
        #pragma unroll
        for (int j = 0; j < 4; ++j) (&p1.x)[j] = sI[c8*8+4+j][dd] > 0 ? (unsigned short)0x3C00 : (unsigned short)0;
        unsigned short* o = dst + ((size_t)b*NC + c0 + dd)*NG + g0 + c8*8;
        *(ushort4*)o = p0; *(ushort4*)(o+4) = p1;
    }
}

// ============ prep: adj_gq [b][g][q] int -> adjT int [b][q][g] ============
__global__ __launch_bounds__(256) void adjT_int_k(const int* __restrict__ adj, int* __restrict__ dst){
    int b = blockIdx.z;
    int q0 = blockIdx.x*64, g0 = blockIdx.y*64;
    __shared__ int sI[64][65];
    int tid = threadIdx.x;
    #pragma unroll
    for (int it = 0; it < 4; ++it){
        int idx = it*256 + tid;
        int r = idx >> 4, c4 = idx & 15;
        int4 v = *(const int4*)(adj + ((size_t)b*NG + g0 + r)*NQ + q0 + c4*4);
        sI[r][c4*4+0]=v.x; sI[r][c4*4+1]=v.y; sI[r][c4*4+2]=v.z; sI[r][c4*4+3]=v.w;
    }
    __syncthreads();
    #pragma unroll
    for (int it = 0; it < 4; ++it){
        int idx = it*256 + tid;
        int dd = idx >> 4, c4 = idx & 15;
        int4 v{sI[c4*4+0][dd], sI[c4*4+1][dd], sI[c4*4+2][dd], sI[c4*4+3][dd]};
        *(int4*)(dst + ((size_t)b*NQ + q0 + dd)*NG + g0 + c4*4) = v;
    }
}

// ============ prep: fp32 act [b][rows][512] -> transposed hi/lo fp16 [b][512][rows] ============
__global__ __launch_bounds__(256) void actT_hl_k(const float* __restrict__ src,
    unsigned short* __restrict__ dstHi, unsigned short* __restrict__ dstLo, int Nrows){
    int b = blockIdx.z;
    int f0 = blockIdx.x*64, g0 = blockIdx.y*64;
    __shared__ float sF[64][65];
    int tid = threadIdx.x;
    #pragma unroll
    for (int it = 0; it < 4; ++it){
        int idx = it*256 + tid;
        int r = idx >> 4, c4 = idx & 15;
        float4 v = *(const float4*)(src + ((size_t)b*Nrows + g0 + r)*512 + f0 + c4*4);
        sF[r][c4*4+0]=v.x; sF[r][c4*4+1]=v.y; sF[r][c4*4+2]=v.z; sF[r][c4*4+3]=v.w;
    }
    __syncthreads();
    #pragma unroll
    for (int it = 0; it < 2; ++it){
        int idx = it*256 + tid;
        int dd = idx >> 3, c8 = idx & 7;
        unsigned short hi[8], lo[8];
        #pragma unroll
        for (int j = 0; j < 8; ++j){
            float x = sF[c8*8+j][dd];
            hi[j] = f2h(x);
            lo[j] = f2h(x - h2f(hi[j]));
        }
        size_t oo = ((size_t)b*512 + f0 + dd)*Nrows + g0 + c8*8;
        *(ushort4*)(dstHi+oo)   = ushort4{hi[0],hi[1],hi[2],hi[3]};
        *(ushort4*)(dstHi+oo+4) = ushort4{hi[4],hi[5],hi[6],hi[7]};
        *(ushort4*)(dstLo+oo)   = ushort4{lo[0],lo[1],lo[2],lo[3]};
        *(ushort4*)(dstLo+oo+4) = ushort4{lo[4],lo[5],lo[6],lo[7]};
    }
}

// ============ wa[h,f] = sum_d W[h,f,d]*a[h,d] ============
__global__ __launch_bounds__(256) void wa_k(const float* __restrict__ W, const float* __restrict__ a1,
                                            const float* __restrict__ a2,
                                            float* __restrict__ wa1, float* __restrict__ wa2){
    int idx = blockIdx.x*256 + threadIdx.x;
    int h = idx >> 9;
    const float* Wp = W + (size_t)idx*64;
    float s1 = 0.f, s2 = 0.f;
    #pragma unroll
    for (int d = 0; d < 64; ++d){ float w = Wp[d]; s1 += w*a1[(h<<6)+d]; s2 += w*a2[(h<<6)+d]; }
    wa1[idx] = s1; wa2[idx] = s2;
}

// ============ scores from fp16 X ============
__global__ __launch_bounds__(256) void scores_h_k(const unsigned short* __restrict__ X, const float* __restrict__ wa,
                                                  float* __restrict__ sc){
    int lane = threadIdx.x & 63;
    int row  = blockIdx.x*4 + (threadIdx.x >> 6);
    const unsigned short* Xr = X + (size_t)row*NFEAT;
    float p[NHEADS];
    #pragma unroll
    for (int h = 0; h < NHEADS; ++h) p[h] = 0.f;
    #pragma unroll
    for (int c = 0; c < 8; ++c){
        float x = h2f(Xr[(c<<6) + lane]);
        #pragma unroll
        for (int h = 0; h < NHEADS; ++h) p[h] += x * wa[(h<<9) + (c<<6) + lane];
    }
    #pragma unroll
    for (int h = 0; h < NHEADS; ++h){
        float v = p[h];
        #pragma unroll
        for (int off = 32; off > 0; off >>= 1) v += __shfl_xor(v, off);
        if (lane == 0) sc[(size_t)row*NHEADS + h] = v;
    }
}

// ============ colmax partial / final ============
__global__ __launch_bounds__(256) void colmax_part_k(const int* __restrict__ adj, long bstride, int ns,
    const float* __restrict__ qs, float* __restrict__ pmax, int N, int M){
    int b = blockIdx.z, ch = blockIdx.y;
    int ml = threadIdx.x & 63; int m = blockIdx.x*64 + ml;
    int g = threadIdx.x >> 6;
    int chunk = N / CHUNKS, subl = chunk >> 2;
    int n0 = ch*chunk + g*subl, n1 = n0 + subl;
    const int* adjb = adj + (size_t)b*bstride;
    float mx[8];
    #pragma unroll
    for (int h = 0; h < 8; ++h) mx[h] = -INFINITY;
    for (int n = n0; n < n1; ++n){
        int a = adjb[(size_t)n*ns + m];
        const float* qr = qs + ((size_t)b*N + n)*8;
        #pragma unroll
        for (int h = 0; h < 8; ++h){ float qv = qr[h]; if (a > 0) mx[h] = fmaxf(mx[h], qv); }
    }
    __shared__ float smx[4][64][8];
    #pragma unroll
    for (int h = 0; h < 8; ++h) smx[g][ml][h] = mx[h];
    __syncthreads();
    if (g == 0){
        #pragma unroll
        for (int h = 0; h < 8; ++h){
            float v = fmaxf(fmaxf(smx[0][ml][h], smx[1][ml][h]), fmaxf(smx[2][ml][h], smx[3][ml][h]));
            pmax[(((size_t)b*CHUNKS + ch)*M + m)*8 + h] = v;
        }
    }
}

__global__ __launch_bounds__(256) void colmax_fin_k(const float* __restrict__ pmax, const float* __restrict__ ks,
    float* __restrict__ cmax, int M){
    int idx = blockIdx.x*256 + threadIdx.x;
    int m8 = M*8;
    int b = idx / m8;
    size_t base = (size_t)b*CHUNKS*m8 + (idx - (size_t)b*m8);
    float mx = -INFINITY;
    #pragma unroll
    for (int ch = 0; ch < CHUNKS; ++ch) mx = fmaxf(mx, pmax[base + (size_t)ch*m8]);
    cmax[idx] = (mx == -INFINITY) ? NEGV : lrelu(mx + ks[idx]);
}

__global__ __launch_bounds__(256) void colsum_part_k(const int* __restrict__ adj, long bstride, int ns,
    const float* __restrict__ qs, const float* __restrict__ ks, const float* __restrict__ cmax,
    float* __restrict__ psum, int N, int M){
    int b = blockIdx.z, ch = blockIdx.y;
    int ml = threadIdx.x & 63; int m = blockIdx.x*64 + ml;
    int g = threadIdx.x >> 6;
    int chunk = N / CHUNKS, subl = chunk >> 2;
    int n0 = ch*chunk + g*subl, n1 = n0 + subl;
    const int* adjb = adj + (size_t)b*bstride;
    float ksv[8], cmv[8], s[8];
    size_t mo = ((size_t)b*M + m)*8;
    #pragma unroll
    for (int h = 0; h < 8; ++h){ ksv[h] = ks[mo+h]; cmv[h] = cmax[mo+h]; s[h] = 0.f; }
    for (int n = n0; n < n1; ++n){
        int a = adjb[(size_t)n*ns + m];
        const float* qr = qs + ((size_t)b*N + n)*8;
        #pragma unroll
        for (int h = 0; h < 8; ++h){
            float e = (a > 0) ? lrelu(qr[h] + ksv[h]) : NEGV;
            s[h] += expf(e - cmv[h]);
        }
    }
    __shared__ float ssm[4][64][8];
    #pragma unroll
    for (int h = 0; h < 8; ++h) ssm[g][ml][h] = s[h];
    __syncthreads();
    if (g == 0){
        #pragma unroll
        for (int h = 0; h < 8; ++h){
            float v = ssm[0][ml][h] + ssm[1][ml][h] + ssm[2][ml][h] + ssm[3][ml][h];
            psum[(((size_t)b*CHUNKS + ch)*M + m)*8 + h] = v;
        }
    }
}

// ============ merged colsum finalize + stat repack: write ksh/cmh/ish [b][8][M] ============
__global__ __launch_bounds__(256) void colsum_fin2_k(const float* __restrict__ psum,
    const float* __restrict__ ks, const float* __restrict__ cmax,
    float* __restrict__ ksh, float* __restrict__ cmh, float* __restrict__ ish, int M){
    int idx = blockIdx.x*256 + threadIdx.x;
    int m8 = M*8;
    int b = idx / m8, rem = idx - b*m8;
    int m = rem >> 3, h = rem & 7;
    size_t base = (size_t)b*CHUNKS*m8 + rem;
    float S = 0.f;
    #pragma unroll
    for (int ch = 0; ch < CHUNKS; ++ch) S += psum[base + (size_t)ch*m8];
    size_t o = ((size_t)b*8 + h)*M + m;
    ksh[o] = ks[idx]; cmh[o] = cmax[idx]; ish[o] = 1.f/S;
}

// ============ fusion stage A: per-pass GEMM partials (fp32) ============
// grid.z = b*npass + p.  pass0: (aHi,bHi,Whi)  pass1: (aLo,bLo,Whi)  pass2: (aHi,bHi,Wlo)
// pacN/pacF layout: [((p*NB + b)*rows + r)*512 + c]
__global__ __launch_bounds__(256) void fusion3_part_k(
    const unsigned short* __restrict__ aHi, const unsigned short* __restrict__ aLo,
    const unsigned short* __restrict__ bHi, const unsigned short* __restrict__ bLo,
    const unsigned short* __restrict__ Whi, const unsigned short* __restrict__ Wlo,
    float* __restrict__ pacN, float* __restrict__ pacF, int rowsPB, int npass){
    int p = blockIdx.z / NB, b = blockIdx.z % NB;
    int r0 = blockIdx.y*128, c0 = blockIdx.x*64;
    int tid = threadIdx.x;
    __shared__ unsigned short aS[128*LSTR];
    __shared__ unsigned short bS[128*LSTR];
    __shared__ unsigned short wS[4*64*LSTR];
    size_t actOff = (size_t)b*rowsPB*512;
    const unsigned short* Ap = (p == 1) ? aLo : aHi;
    const unsigned short* Bp = (p == 1) ? bLo : bHi;
    const unsigned short* Wp = (p == 2) ? Wlo : Whi;
    const unsigned short* ApG = Ap ? Ap + actOff : nullptr;
    const unsigned short* BpG = Bp ? Bp + actOff : nullptr;
    int w = tid >> 6, lane = tid & 63;
    int lrow = lane & 15, quad = lane >> 4;
    v4f accN[2][4], accF[2][4];
    #pragma unroll
    for (int r = 0; r < 2; ++r)
        #pragma unroll
        for (int cf = 0; cf < 4; ++cf){ accN[r][cf] = (v4f)0.f; accF[r][cf] = (v4f)0.f; }
    for (int kt = 0; kt < 512; kt += 32){
        __syncthreads();
        uint4 za; za.x = za.y = za.z = za.w = 0u;
        #pragma unroll
        for (int it = 0; it < 2; ++it){
            int idx = it*256 + tid;
            int row = idx >> 2, c4 = idx & 3;
            *(uint4*)&aS[row*LSTR + c4*8] = ApG ? *(const uint4*)(ApG + (size_t)(r0+row)*512 + kt + c4*8) : za;
            *(uint4*)&bS[row*LSTR + c4*8] = BpG ? *(const uint4*)(BpG + (size_t)(r0+row)*512 + kt + c4*8) : za;
        }
        #pragma unroll
        for (int it = 0; it < 4; ++it){
            int idx = it*256 + tid;
            int mat = idx >> 8, row = (idx >> 2) & 63, c4 = idx & 3;
            *(uint4*)&wS[(mat*64+row)*LSTR + c4*8] =
                *(const uint4*)(Wp + ((size_t)mat*512 + c0 + row)*512 + kt + c4*8);
        }
        __syncthreads();
        v8h af[2], bf[2];
        #pragma unroll
        for (int r = 0; r < 2; ++r){
            af[r] = *(const v8h*)&aS[(w*32 + r*16 + lrow)*LSTR + quad*8];
            bf[r] = *(const v8h*)&bS[(w*32 + r*16 + lrow)*LSTR + quad*8];
        }
        v8h wf[4][4];
        #pragma unroll
        for (int mat = 0; mat < 4; ++mat)
            #pragma unroll
            for (int cf = 0; cf < 4; ++cf)
                wf[mat][cf] = *(const v8h*)&wS[(mat*64 + cf*16 + lrow)*LSTR + quad*8];
        #pragma unroll
        for (int r = 0; r < 2; ++r)
            #pragma unroll
            for (int cf = 0; cf < 4; ++cf){
                accN[r][cf] = MFMA16(af[r], wf[0][cf], accN[r][cf]);
                accN[r][cf] = MFMA16(bf[r], wf[1][cf], accN[r][cf]);
                accF[r][cf] = MFMA16(af[r], wf[2][cf], accF[r][cf]);
                accF[r][cf] = MFMA16(bf[r], wf[3][cf], accF[r][cf]);
            }
    }
    size_t pOff = ((size_t)p*NB + b)*rowsPB;
    #pragma unroll
    for (int r = 0; r < 2; ++r)
        #pragma unroll
        for (int cf = 0; cf < 4; ++cf){
            int colg = c0 + cf*16 + lrow;
            int rbase = r0 + w*32 + r*16 + quad*4;
            #pragma unroll
            for (int reg = 0; reg < 4; ++reg){
                size_t oo = (pOff + rbase + reg)*512 + colg;
                pacN[oo] = accN[r][cf][reg];
                pacF[oo] = accF[r][cf][reg];
            }
        }
}

// ============ fusion stage B: sum partials, gate, emit hi/lo (+T, +fp32) ============
// 64x64 tiles; grid (8, rows/64, NB)
__global__ __launch_bounds__(256) void fusion_epi_k(
    const float* __restrict__ pacN, const float* __restrict__ pacF, int npass,
    const unsigned short* __restrict__ aHi, const unsigned short* __restrict__ aLo,
    unsigned short* __restrict__ dst, unsigned short* __restrict__ dstLo,
    unsigned short* __restrict__ dstT, unsigned short* __restrict__ dstTLo,
    float* __restrict__ dstF, int rows){
    int b = blockIdx.z;
    int c0 = blockIdx.x*64, r0 = blockIdx.y*64;
    int tid = threadIdx.x;
    int lr = tid >> 2, q = tid & 3;
    int gr = r0 + lr;
    size_t rowOff = ((size_t)b*rows + gr)*512 + c0 + q*16;
    float oN[16], oF[16];
    #pragma unroll
    for (int j = 0; j < 16; ++j){ oN[j] = 0.f; oF[j] = 0.f; }
    for (int p = 0; p < npass; ++p){
        size_t pOff = (((size_t)p*NB + b)*rows + gr)*512 + c0 + q*16;
        #pragma unroll
        for (int j4 = 0; j4 < 4; ++j4){
            float4 vN = *(const float4*)(pacN + pOff + j4*4);
            float4 vF = *(const float4*)(pacF + pOff + j4*4);
            oN[j4*4+0] += vN.x; oN[j4*4+1] += vN.y; oN[j4*4+2] += vN.z; oN[j4*4+3] += vN.w;
            oF[j4*4+0] += vF.x; oF[j4*4+1] += vF.y; oF[j4*4+2] += vF.z; oF[j4*4+3] += vF.w;
        }
    }
    float o[16];
    unsigned short hv[16], lv[16];
    #pragma unroll
    for (int j = 0; j < 16; ++j){
        float f = 1.f/(1.f + expf(-oF[j]));
        float ao = h2f(aHi[rowOff + j]);
        if (aLo) ao += h2f(aLo[rowOff + j]);
        o[j] = f*oN[j] + (1.f - f)*ao;
        hv[j] = f2h(o[j]);
        lv[j] = f2h(o[j] - h2f(hv[j]));
    }
    #pragma unroll
    for (int j4 = 0; j4 < 4; ++j4)
        *(ushort4*)(dst + rowOff + j4*4) = ushort4{hv[j4*4+0],hv[j4*4+1],hv[j4*4+2],hv[j4*4+3]};
    if (dstLo){
        #pragma unroll
        for (int j4 = 0; j4 < 4; ++j4)
            *(ushort4*)(dstLo + rowOff + j4*4) = ushort4{lv[j4*4+0],lv[j4*4+1],lv[j4*4+2],lv[j4*4+3]};
    }
    if (dstF){
        #pragma unroll
        for (int j4 = 0; j4 < 4; ++j4)
            *(float4*)(dstF + rowOff + j4*4) = float4{o[j4*4+0],o[j4*4+1],o[j4*4+2],o[j4*4+3]};
    }
    if (dstT){
        __shared__ unsigned short sT[64*72];
        #pragma unroll
        for (int j = 0; j < 16; ++j) sT[lr*72 + q*16 + j] = hv[j];
        __syncthreads();
        {
            int tc = tid >> 2, tq = tid & 3;     // tc = local col
            unsigned short v[16];
            #pragma unroll
            for (int j = 0; j < 16; ++j) v[j] = sT[(tq*16 + j)*72 + tc];
            size_t to = ((size_t)b*512 + c0 + tc)*rows + r0 + tq*16;
            #pragma unroll
            for (int j4 = 0; j4 < 4; ++j4)
                *(ushort4*)(dstT + to + j4*4) = ushort4{v[j4*4+0],v[j4*4+1],v[j4*4+2],v[j4*4+3]};
        }
        if (dstTLo){
            __syncthreads();
            #pragma unroll
            for (int j = 0; j < 16; ++j) sT[lr*72 + q*16 + j] = lv[j];
            __syncthreads();
            int tc = tid >> 2, tq = tid & 3;
            unsigned short v[16];
            #pragma unroll
            for (int j = 0; j < 16; ++j) v[j] = sT[(tq*16 + j)*72 + tc];
            size_t to = ((size_t)b*512 + c0 + tc)*rows + r0 + tq*16;
            #pragma unroll
            for (int j4 = 0; j4 < 4; ++j4)
                *(ushort4*)(dstTLo + to + j4*4) = ushort4{v[j4*4+0],v[j4*4+1],v[j4*4+2],v[j4*4+3]};
        }
    }
}

// ============ generic MFMA GEMM: C[b] = A[b]@BT^T (+ A[b]@BT2^T) ============
__global__ __launch_bounds__(256) void gemmT_mfma_k(
    const unsigned short* __restrict__ A, size_t aStride,
    const unsigned short* __restrict__ BT, const unsigned short* __restrict__ BT2, size_t bStride,
    int K, int rowsPB,
    unsigned short* __restrict__ outRM, unsigned short* __restrict__ outLo,
    unsigned short* __restrict__ outT){
    int b = blockIdx.z;
    int r0 = blockIdx.y*128, c0 = blockIdx.x*64;
    int tid = threadIdx.x;
    __shared__ unsigned short aS[128*LSTR];
    __shared__ unsigned short bS[64*LSTR];
    const unsigned short* aG = A + (size_t)b*aStride;
    int w = tid >> 6, lane = tid & 63;
    int lrow = lane & 15, quad = lane >> 4;
    v4f acc[2][4];
    #pragma unroll
    for (int r = 0; r < 2; ++r)
        #pragma unroll
        for (int cf = 0; cf < 4; ++cf) acc[r][cf] = (v4f)0.f;
    for (int p = 0; p < 2; ++p){
        if (p == 1 && BT2 == nullptr) break;
        const unsigned short* bG = (p ? BT2 : BT) + (size_t)b*bStride;
        for (int kt = 0; kt < K; kt += 32){
            __syncthreads();
            #pragma unroll
            for (int it = 0; it < 2; ++it){
                int idx = it*256 + tid;
                int row = idx >> 2, c4 = idx & 3;
                *(uint4*)&aS[row*LSTR + c4*8] = *(const uint4*)(aG + (size_t)(r0+row)*K + kt + c4*8);
            }
            {
                int row = tid >> 2, c4 = tid & 3;
                *(uint4*)&bS[row*LSTR + c4*8] = *(const uint4*)(bG + (size_t)(c0+row)*K + kt + c4*8);
            }
            __syncthreads();
            v8h af[2], bf[4];
            #pragma unroll
            for (int r = 0; r < 2; ++r) af[r] = *(const v8h*)&aS[(w*32 + r*16 + lrow)*LSTR + quad*8];
            #pragma unroll
            for (int cf = 0; cf < 4; ++cf) bf[cf] = *(const v8h*)&bS[(cf*16 + lrow)*LSTR + quad*8];
            #pragma unroll
            for (int r = 0; r < 2; ++r)
                #pragma unroll
                for (int cf = 0; cf < 4; ++cf)
                    acc[r][cf] = MFMA16(af[r], bf[cf], acc[r][cf]);
        }
    }
    #pragma unroll
    for (int r = 0; r < 2; ++r)
        #pragma unroll
        for (int cf = 0; cf < 4; ++cf){
            int colg = c0 + cf*16 + lrow;
            int rbase = r0 + w*32 + r*16 + quad*4;
            if (outRM){
                #pragma unroll
                for (int reg = 0; reg < 4; ++reg){
                    float v = acc[r][cf][reg];
                    unsigned short hv = f2h(v);
                    size_t oo = ((size_t)b*rowsPB + rbase + reg)*512 + colg;
                    outRM[oo] = hv;
                    if (outLo) outLo[oo] = f2h(v - h2f(hv));
                }
            }
            if (outT){
                ushort4 pk{f2h(acc[r][cf][0]), f2h(acc[r][cf][1]), f2h(acc[r][cf][2]), f2h(acc[r][cf][3])};
                *(ushort4*)&outT[((size_t)b*512 + colg)*rowsPB + rbase] = pk;
            }
        }
}

// ============ attention output MFMA ============
__global__ __launch_bounds__(256) void attn_mfma_k(const int* __restrict__ adj, long bstride, int ns,
    const float* __restrict__ qs, const float* __restrict__ ksh, const float* __restrict__ cmh,
    const float* __restrict__ ish, const unsigned short* __restrict__ WkT,
    unsigned short* __restrict__ outp, int N, int M){
    int bh = blockIdx.y; int b = bh >> 3, h = bh & 7;
    int n0 = blockIdx.x*64;
    int tid = threadIdx.x;
    __shared__ unsigned short pS[64*LSTR];
    __shared__ unsigned short wS[64*LSTR];
    __shared__ float qsS[64];
    if (tid < 64) qsS[tid] = qs[((size_t)b*N + n0 + tid)*8 + h];
    const int* adjb = adj + (size_t)b*bstride;
    const float* ksb = ksh + ((size_t)b*8 + h)*M;
    const float* cmb = cmh + ((size_t)b*8 + h)*M;
    const float* isb = ish + ((size_t)b*8 + h)*M;
    const unsigned short* wkb = WkT + ((size_t)b*512 + h*64)*M;
    int w = tid >> 6, lane = tid & 63;
    int lrow = lane & 15, quad = lane >> 4;
    int pn = tid >> 2, pm = (tid & 3)*8;
    v4f acc[4];
    #pragma unroll
    for (int cf = 0; cf < 4; ++cf) acc[cf] = (v4f)0.f;
    for (int mt = 0; mt < M; mt += 32){
        __syncthreads();
        *(uint4*)&wS[(tid>>2)*LSTR + (tid&3)*8] = *(const uint4*)(wkb + (size_t)(tid>>2)*M + mt + (tid&3)*8);
        const int* arow = adjb + (size_t)(n0+pn)*ns + mt + pm;
        int4 a0 = *(const int4*)arow;
        int4 a1 = *(const int4*)(arow + 4);
        float4 k0 = *(const float4*)(ksb + mt + pm), k1 = *(const float4*)(ksb + mt + pm + 4);
        float4 c0v = *(const float4*)(cmb + mt + pm), c1v = *(const float4*)(cmb + mt + pm + 4);
        float4 i0 = *(const float4*)(isb + mt + pm), i1 = *(const float4*)(isb + mt + pm + 4);
        float qv = qsS[pn];
        float p[8];
        const int* aa0 = &a0.x; const int* aa1 = &a1.x;
        const float* kk0 = &k0.x; const float* kk1 = &k1.x;
        const float* cc0 = &c0v.x; const float* cc1 = &c1v.x;
        const float* ii0 = &i0.x; const float* ii1 = &i1.x;
        #pragma unroll
        for (int j = 0; j < 4; ++j){
            float e = (aa0[j] > 0) ? lrelu(qv + kk0[j]) : NEGV;
            p[j] = expf(e - cc0[j]) * ii0[j];
        }
        #pragma unroll
        for (int j = 0; j < 4; ++j){
            float e = (aa1[j] > 0) ? lrelu(qv + kk1[j]) : NEGV;
            p[4+j] = expf(e - cc1[j]) * ii1[j];
        }
        ushort4 pk0{f2h(p[0]), f2h(p[1]), f2h(p[2]), f2h(p[3])};
        ushort4 pk1{f2h(p[4]), f2h(p[5]), f2h(p[6]), f2h(p[7])};
        *(ushort4*)&pS[pn*LSTR + pm] = pk0;
        *(ushort4*)&pS[pn*LSTR + pm + 4] = pk1;
        __syncthreads();
        v8h af = *(const v8h*)&pS[(w*16 + lrow)*LSTR + quad*8];
        #pragma unroll
        for (int cf = 0; cf < 4; ++cf){
            v8h bf = *(const v8h*)&wS[(cf*16 + lrow)*LSTR + quad*8];
            acc[cf] = MFMA16(af, bf, acc[cf]);
        }
    }
    #pragma unroll
    for (int cf = 0; cf < 4; ++cf){
        int colg = h*64 + cf*16 + lrow;
        int rbase = n0 + w*16 + quad*4;
        #pragma unroll
        for (int reg = 0; reg < 4; ++reg){
            float v = acc[cf][reg];
            v = (v > 0.f) ? v : expm1f(v);
            outp[((size_t)b*N + rbase + reg)*512 + colg] = f2h(v);
        }
    }
}

extern "C" void kernel_launch(void* const* d_in, const int* in_sizes, int n_in,
                              void* d_out, int out_size, void* d_ws, size_t ws_size,
                              hipStream_t stream){
    const float* in_gloss = (const float*)d_in[0];
    const float* in_clip  = (const float*)d_in[1];
    const float* in_q     = (const float*)d_in[2];
    const int*   adj_gc   = (const int*)d_in[3];
    const int*   adj_gq   = (const int*)d_in[4];
    const float* c2gW  = (const float*)d_in[5];
    const float* c2ga1 = (const float*)d_in[6];
    const float* c2ga2 = (const float*)d_in[7];
    const float* g2qW  = (const float*)d_in[8];
    const float* g2qa1 = (const float*)d_in[9];
    const float* g2qa2 = (const float*)d_in[10];
    const float* q2gW  = (const float*)d_in[11];
    const float* q2ga1 = (const float*)d_in[12];
    const float* q2ga2 = (const float*)d_in[13];
    const float* fusW  = (const float*)d_in[14];
    const float* fusU  = (const float*)d_in[15];
    const float* fusWf = (const float*)d_in[16];
    const float* fusUf = (const float*)d_in[17];
    float* out = (float*)d_out;
    float* out_gloss = out;
    float* out_clip  = out + (size_t)NB*NG*NFEAT;
    float* out_q     = out + (size_t)NB*NG*NFEAT*2;

    char* wsB = (char*)d_ws;
    size_t off = 0;
    auto alloc = [&](size_t bytes){ void* p = wsB + off; off += (bytes + 255) & ~(size_t)255; return p; };
    float* wa1   = (float*)alloc(4096*4);
    float* wa2   = (float*)alloc(4096*4);
    float* qsb   = (float*)alloc((size_t)NB*NG*8*4);
    float* ksb   = (float*)alloc((size_t)NB*NG*8*4);
    float* cmaxb = (float*)alloc((size_t)NB*NG*8*4);
    float* ksh   = (float*)alloc((size_t)NB*NG*8*4);
    float* cmh   = (float*)alloc((size_t)NB*NG*8*4);
    float* ish   = (float*)alloc((size_t)NB*NG*8*4);
    float* pmaxb = (float*)alloc((size_t)NB*CHUNKS*NG*8*4);
    float* psumb = (float*)alloc((size_t)NB*CHUNKS*NG*8*4);
    float* pacN  = (float*)alloc((size_t)3*NB*NG*NFEAT*4);
    float* pacF  = (float*)alloc((size_t)3*NB*NG*NFEAT*4);
    unsigned short* WflatT  = (unsigned short*)alloc((size_t)NFEAT*NFEAT*2);
    unsigned short* wtAll   = (unsigned short*)alloc((size_t)32*FF*2);
    unsigned short* wtAllLo = (unsigned short*)alloc((size_t)32*FF*2);
    unsigned short* adjTgc  = (unsigned short*)alloc((size_t)NB*NC*NG*2);
    unsigned short* g_bf0   = (unsigned short*)alloc((size_t)NB*NG*NFEAT*2);
    unsigned short* gLo0    = (unsigned short*)alloc((size_t)NB*NG*NFEAT*2);
    unsigned short* g_bf1   = (unsigned short*)alloc((size_t)NB*NG*NFEAT*2);
    unsigned short* gLo1    = (unsigned short*)alloc((size_t)NB*NG*NFEAT*2);
    unsigned short* gT      = (unsigned short*)alloc((size_t)NB*NFEAT*NG*2);
    unsigned short* gTlo    = (unsigned short*)alloc((size_t)NB*NFEAT*NG*2);
    unsigned short* gA_bf   = (unsigned short*)alloc((size_t)NB*NG*NFEAT*2);
    unsigned short* gALo    = (unsigned short*)alloc((size_t)NB*NG*NFEAT*2);
    unsigned short* c_bf0   = (unsigned short*)alloc((size_t)NB*NC*NFEAT*2);
    unsigned short* cLo0    = (unsigned short*)alloc((size_t)NB*NC*NFEAT*2);
    unsigned short* c_bf1   = (unsigned short*)alloc((size_t)NB*NC*NFEAT*2);
    unsigned short* cLo1    = (unsigned short*)alloc((size_t)NB*NC*NFEAT*2);
    unsigned short* q_bf0   = (unsigned short*)alloc((size_t)NB*NQ*NFEAT*2);
    unsigned short* q_bf1   = (unsigned short*)alloc((size_t)NB*NQ*NFEAT*2);
    unsigned short* agg_bf  = (unsigned short*)alloc((size_t)NB*NG*NFEAT*2);
    unsigned short* aggLo   = (unsigned short*)alloc((size_t)NB*NG*NFEAT*2);
    unsigned short* WkT     = (unsigned short*)alloc((size_t)NB*NFEAT*NG*2);
    int* adjTgq = (int*)alloc((size_t)NB*NQ*NG*4);
    (void)ws_size; (void)in_sizes; (void)n_in; (void)out_size;

    const size_t HFD = (size_t)NHEADS*NFEAT*HDIM;
    const size_t HD  = (size_t)NHEADS*HDIM;

    // ---- prep ----
    wtT_k<<<2048, 256, 0, stream>>>(fusW, fusU, fusWf, fusUf, wtAll, wtAllLo);
    adjT_h_k<<<dim3(NC/64, NG/64, NB), 256, 0, stream>>>(adj_gc, adjTgc);
    adjT_int_k<<<dim3(NQ/64, NG/64, NB), 256, 0, stream>>>(adj_gq, adjTgq);
    cvt_hl_k<<<(NB*NG*NFEAT)/2048, 256, 0, stream>>>(in_gloss, g_bf0, gLo0);
    cvt_hl_k<<<(NB*NC*NFEAT)/2048, 256, 0, stream>>>(in_clip,  c_bf0, cLo0);
    cvt_h_k<<<(NB*NQ*NFEAT)/2048, 256, 0, stream>>>(in_q,     q_bf0);
    actT_hl_k<<<dim3(8, NG/64, NB), 256, 0, stream>>>(in_gloss, gT, gTlo, NG);

    auto run_attn = [&](const unsigned short* qX, int N, const unsigned short* kvX, int M,
                        const int* adjp, long bstride, int ns,
                        const float* W, const float* a1, const float* a2, unsigned short* dst){
        repackT_W_k<<<64, 256, 0, stream>>>(W, WflatT);
        wa_k<<<16, 256, 0, stream>>>(W, a1, a2, wa1, wa2);
        scores_h_k<<<(NB*N)/4, 256, 0, stream>>>(qX, wa1, qsb);
        scores_h_k<<<(NB*M)/4, 256, 0, stream>>>(kvX, wa2, ksb);
        gemmT_mfma_k<<<dim3(8, M/128, NB), 256, 0, stream>>>(kvX, (size_t)M*512, WflatT, nullptr, 0,
                                                             512, M, nullptr, nullptr, WkT);
        colmax_part_k<<<dim3(M/64, CHUNKS, NB), 256, 0, stream>>>(adjp, bstride, ns, qsb, pmaxb, N, M);
        colmax_fin_k<<<(NB*M*8)/256, 256, 0, stream>>>(pmaxb, ksb, cmaxb, M);
        colsum_part_k<<<dim3(M/64, CHUNKS, NB), 256, 0, stream>>>(adjp, bstride, ns, qsb, ksb, cmaxb, psumb, N, M);
        colsum_fin2_k<<<(NB*M*8)/256, 256, 0, stream>>>(psumb, ksb, cmaxb, ksh, cmh, ish, M);
        attn_mfma_k<<<dim3(N/64, NB*8), 256, 0, stream>>>(adjp, bstride, ns, qsb, ksh, cmh, ish,
                                                          WkT, dst, N, M);
    };
    auto run_fusion = [&](const unsigned short* a, const unsigned short* aLo,
                          const unsigned short* bb, const unsigned short* bLo, int rows,
                          int l, int i, int npass,
                          unsigned short* dst, unsigned short* dstLo,
                          unsigned short* dstT, unsigned short* dstTLo, float* dstF){
        const unsigned short* Whi = wtAll   + (size_t)((l*4 + i)*4)*FF;
        const unsigned short* Wlo = wtAllLo + (size_t)((l*4 + i)*4)*FF;
        fusion3_part_k<<<dim3(8, rows/128, NB*npass), 256, 0, stream>>>(
            a, aLo, bb, bLo, Whi, Wlo, pacN, pacF, rows, npass);
        fusion_epi_k<<<dim3(8, rows/64, NB), 256, 0, stream>>>(
            pacN, pacF, npass, a, aLo, dst, dstLo, dstT, dstTLo, dstF, rows);
    };

    for (int l = 0; l < 2; ++l){
        const unsigned short* g_cur = (l == 0) ? g_bf0 : g_bf1;
        const unsigned short* gLoC  = (l == 0) ? gLo0  : gLo1;
        const unsigned short* c_cur = (l == 0) ? c_bf0 : c_bf1;
        const unsigned short* cLoC  = (l == 0) ? cLo0  : cLo1;
        const unsigned short* q_cur = (l == 0) ? q_bf0 : q_bf1;
        unsigned short* g_nxt = (l == 0) ? g_bf1 : g_bf0;
        unsigned short* gLoN  = (l == 0) ? gLo1  : nullptr;
        unsigned short* c_nxt = (l == 0) ? c_bf1 : c_bf0;
        unsigned short* cLoN  = (l == 0) ? cLo1  : nullptr;
        unsigned short* q_nxt = (l == 0) ? q_bf1 : q_bf0;
        float* gF = (l == 1) ? out_gloss : nullptr;
        float* cF = (l == 1) ? out_clip  : nullptr;
        float* qF = (l == 1) ? out_q     : nullptr;

        // gloss_same = adj_gc^T @ gloss  (hi/lo B, hi/lo out)
        gemmT_mfma_k<<<dim3(8, NC/128, NB), 256, 0, stream>>>(adjTgc, (size_t)NC*NG, gT, gTlo,
                                                              (size_t)512*NG, NG, NC,
                                                              agg_bf, aggLo, nullptr);
        // clip_1 (3-pass hi/lo)
        run_fusion(c_cur, cLoC, agg_bf, aggLo, NC, l, 0, 3,
                   c_nxt, cLoN, nullptr, nullptr, cF);
        // clip_agg = attn(q=gloss, kv=clip, adj_gc)
        run_attn(g_cur, NG, c_cur, NC, adj_gc, (long)NG*NC, NC,
                 c2gW + l*HFD, c2ga1 + l*HD, c2ga2 + l*HD, agg_bf);
        // gloss_1 (3-pass: a-lo + weight-lo; b-lo absent)
        run_fusion(g_cur, gLoC, agg_bf, nullptr, NG, l, 1, 3,
                   gA_bf, gALo, nullptr, nullptr, nullptr);
        // gloss_agg = attn(q=question, kv=gloss, adjT_gq)
        run_attn(q_cur, NQ, g_cur, NG, adjTgq, (long)NQ*NG, NG,
                 g2qW + l*HFD, g2qa1 + l*HD, g2qa2 + l*HD, agg_bf);
        // question_1 (single pass)
        run_fusion(q_cur, nullptr, agg_bf, nullptr, NQ, l, 2, 1,
                   q_nxt, nullptr, nullptr, nullptr, qF);
        // question_agg = attn(q=gloss, kv=question, adj_gq)
        run_attn(g_cur, NG, q_cur, NQ, adj_gq, (long)NG*NQ, NQ,
                 q2gW + l*HFD, q2ga1 + l*HD, q2ga2 + l*HD, agg_bf);
        // gloss_2 (3-pass; emit hi/lo + transposed hi/lo for next layer's gloss_same)
        run_fusion(gA_bf, gALo, agg_bf, nullptr, NG, l, 3, 3,
                   g_nxt, gLoN, (l == 0) ? gT : nullptr, (l == 0) ? gTlo : nullptr, gF);
    }
}

// Round 8
// 1259.514 us; speedup vs baseline: 4.1848x; 1.1213x over previous
//
#include <hip/hip_runtime.h>
#include <math.h>

#define NFEAT 512
#define NHEADS 8
#define HDIM 64
#define NB 4
#define NG 1024
#define NC 1024
#define NQ 256
#define NEGV -9e15f
#define CHUNKS 16
#define FF ((size_t)NFEAT*NFEAT)
#define LSTR 36   // LDS row stride (ushorts): 32 payload + 4 pad

typedef _Float16 v8h __attribute__((ext_vector_type(8)));
typedef float v4f __attribute__((ext_vector_type(4)));
#define MFMA16(a,b,c) __builtin_amdgcn_mfma_f32_16x16x32_f16((a),(b),(c),0,0,0)

__device__ __forceinline__ float lrelu(float x){ return fmaxf(x, 0.2f*x); }
__device__ __forceinline__ unsigned short f2h(float x){ union{_Float16 h; unsigned short u;} v; v.h = (_Float16)x; return v.u; }
__device__ __forceinline__ float h2f(unsigned short u){ union{_Float16 h; unsigned short u;} v; v.u = u; return (float)v.h; }

// ============ prep: fp32 -> fp16 flat ============
__global__ __launch_bounds__(256) void cvt_h_k(const float* __restrict__ src, unsigned short* __restrict__ dst){
    int idx = blockIdx.x*256 + threadIdx.x;
    const float4* s = (const float4*)(src + (size_t)idx*8);
    float4 a = s[0], b = s[1];
    ushort4 p0{f2h(a.x),f2h(a.y),f2h(a.z),f2h(a.w)};
    ushort4 p1{f2h(b.x),f2h(b.y),f2h(b.z),f2h(b.w)};
    *(ushort4*)(dst + (size_t)idx*8) = p0;
    *(ushort4*)(dst + (size_t)idx*8 + 4) = p1;
}

// ============ prep: fp32 -> fp16 hi/lo flat ============
__global__ __launch_bounds__(256) void cvt_hl_k(const float* __restrict__ src,
    unsigned short* __restrict__ dstHi, unsigned short* __restrict__ dstLo){
    int idx = blockIdx.x*256 + threadIdx.x;
    const float4* s = (const float4*)(src + (size_t)idx*8);
    float4 a = s[0], b = s[1];
    float x[8] = {a.x,a.y,a.z,a.w,b.x,b.y,b.z,b.w};
    unsigned short hi[8], lo[8];
    #pragma unroll
    for (int j = 0; j < 8; ++j){ hi[j] = f2h(x[j]); lo[j] = f2h(x[j] - h2f(hi[j])); }
    *(ushort4*)(dstHi + (size_t)idx*8)     = ushort4{hi[0],hi[1],hi[2],hi[3]};
    *(ushort4*)(dstHi + (size_t)idx*8 + 4) = ushort4{hi[4],hi[5],hi[6],hi[7]};
    *(ushort4*)(dstLo + (size_t)idx*8)     = ushort4{lo[0],lo[1],lo[2],lo[3]};
    *(ushort4*)(dstLo + (size_t)idx*8 + 4) = ushort4{lo[4],lo[5],lo[6],lo[7]};
}

// ============ prep: fusion weights -> transposed fp16 hi/lo, all 32 matrices ============
__global__ __launch_bounds__(256) void wtT_k(const float* __restrict__ w0, const float* __restrict__ w1,
    const float* __restrict__ w2, const float* __restrict__ w3,
    unsigned short* __restrict__ dstHi, unsigned short* __restrict__ dstLo){
    int bx = blockIdx.x;
    int mat = bx >> 6, t = bx & 63;
    int a = mat & 3, li = mat >> 2;
    const float* src = (a==0?w0:a==1?w1:a==2?w2:w3) + (size_t)li*FF;
    int fo0 = (t>>3)*64, fi0 = (t&7)*64;
    __shared__ float sT[64][65];
    int tid = threadIdx.x;
    #pragma unroll
    for (int it = 0; it < 4; ++it){
        int idx = it*256 + tid;
        int r = idx >> 4, c4 = idx & 15;
        float4 v = *(const float4*)(src + (size_t)(fi0+r)*512 + fo0 + c4*4);
        sT[r][c4*4+0]=v.x; sT[r][c4*4+1]=v.y; sT[r][c4*4+2]=v.z; sT[r][c4*4+3]=v.w;
    }
    __syncthreads();
    #pragma unroll
    for (int it = 0; it < 2; ++it){
        int idx = it*256 + tid;
        int dd = idx >> 3, c8 = idx & 7;
        unsigned short hi[8], lo[8];
        #pragma unroll
        for (int j = 0; j < 8; ++j){
            float x = sT[c8*8+j][dd];
            hi[j] = f2h(x);
            lo[j] = f2h(x - h2f(hi[j]));
        }
        size_t oo = (size_t)mat*FF + (size_t)(fo0+dd)*512 + fi0 + c8*8;
        *(ushort4*)(dstHi+oo)   = ushort4{hi[0],hi[1],hi[2],hi[3]};
        *(ushort4*)(dstHi+oo+4) = ushort4{hi[4],hi[5],hi[6],hi[7]};
        *(ushort4*)(dstLo+oo)   = ushort4{lo[0],lo[1],lo[2],lo[3]};
        *(ushort4*)(dstLo+oo+4) = ushort4{lo[4],lo[5],lo[6],lo[7]};
    }
}

// ============ prep: attention W repack (blocks 0..63) + wa vectors (blocks 64..79) ============
__global__ __launch_bounds__(256) void prep_attnW_k(const float* __restrict__ W,
    const float* __restrict__ a1, const float* __restrict__ a2,
    unsigned short* __restrict__ WT, float* __restrict__ wa1, float* __restrict__ wa2){
    int bx = blockIdx.x;
    int tid = threadIdx.x;
    if (bx >= 64){
        int idx = (bx - 64)*256 + tid;
        int h = idx >> 9;
        const float* Wp = W + (size_t)idx*64;
        float s1 = 0.f, s2 = 0.f;
        #pragma unroll
        for (int d = 0; d < 64; ++d){ float w = Wp[d]; s1 += w*a1[(h<<6)+d]; s2 += w*a2[(h<<6)+d]; }
        wa1[idx] = s1; wa2[idx] = s2;
        return;
    }
    int h = bx >> 3, f0 = (bx & 7)*64;
    __shared__ float sT[64][65];
    #pragma unroll
    for (int it = 0; it < 4; ++it){
        int idx = it*256 + tid;
        int r = idx >> 4, c4 = idx & 15;
        float4 v = *(const float4*)(W + ((size_t)h*512 + f0 + r)*64 + c4*4);
        sT[r][c4*4+0]=v.x; sT[r][c4*4+1]=v.y; sT[r][c4*4+2]=v.z; sT[r][c4*4+3]=v.w;
    }
    __syncthreads();
    #pragma unroll
    for (int it = 0; it < 2; ++it){
        int idx = it*256 + tid;
        int dd = idx >> 3, c8 = idx & 7;
        ushort4 p0{f2h(sT[c8*8+0][dd]),f2h(sT[c8*8+1][dd]),f2h(sT[c8*8+2][dd]),f2h(sT[c8*8+3][dd])};
        ushort4 p1{f2h(sT[c8*8+4][dd]),f2h(sT[c8*8+5][dd]),f2h(sT[c8*8+6][dd]),f2h(sT[c8*8+7][dd])};
        unsigned short* o = WT + ((size_t)h*64 + dd)*512 + f0 + c8*8;
        *(ushort4*)o = p0; *(ushort4*)(o+4) = p1;
    }
}

// ============ prep: adj_gc [b][g][c] int -> adjT fp16 [b][c][g] ============
__global__ __launch_bounds__(256) void adjT_h_k(const int* __restrict__ adj, unsigned short* __restrict__ dst){
    int b = blockIdx.z;
    int c0 = blockIdx.x*64, g0 = blockIdx.y*64;
    __shared__ int sI[64][65];
    int tid = threadIdx.x;
    #pragma unroll
    for (int it = 0; it < 4; ++it){
        int idx = it*256 + tid;
        int r = idx >> 4, c4 = idx & 15;
        int4 v = *(const int4*)(adj + ((size_t)b*NG + g0 + r)*NC + c0 + c4*4);
        sI[r][c4*4+0]=v.x; sI[r][c4*4+1]=v.y; sI[r][c4*4+2]=v.z; sI[r][c4*4+3]=v.w;
    }
    __syncthreads();
    #pragma unroll
    for (int it = 0; it < 2; ++it){
        int idx = it*256 + tid;
        int dd = idx >> 3, c8 = idx & 7;
        ushort4 p0, p1;
        #pragma unroll
        for (int j = 0; j < 4; ++j) (&p0.x)[j] = sI[c8*8+j][dd] > 0 ? (unsigned short)0x3C00 : (unsigned short)0;
        #pragma unroll
        for (int j = 0; j < 4; ++j) (&p1.x)[j] = sI[c8*8+4+j][dd] > 0 ? (unsigned short)0x3C00 : (unsigned short)0;
        unsigned short* o = dst + ((size_t)b*NC + c0 + dd)*NG + g0 + c8*8;
        *(ushort4*)o = p0; *(ushort4*)(o+4) = p1;
    }
}

// ============ prep: adj_gq [b][g][q] int -> adjT int [b][q][g] ============
__global__ __launch_bounds__(256) void adjT_int_k(const int* __restrict__ adj, int* __restrict__ dst){
    int b = blockIdx.z;
    int q0 = blockIdx.x*64, g0 = blockIdx.y*64;
    __shared__ int sI[64][65];
    int tid = threadIdx.x;
    #pragma unroll
    for (int it = 0; it < 4; ++it){
        int idx = it*256 + tid;
        int r = idx >> 4, c4 = idx & 15;
        int4 v = *(const int4*)(adj + ((size_t)b*NG + g0 + r)*NQ + q0 + c4*4);
        sI[r][c4*4+0]=v.x; sI[r][c4*4+1]=v.y; sI[r][c4*4+2]=v.z; sI[r][c4*4+3]=v.w;
    }
    __syncthreads();
    #pragma unroll
    for (int it = 0; it < 4; ++it){
        int idx = it*256 + tid;
        int dd = idx >> 4, c4 = idx & 15;
        int4 v{sI[c4*4+0][dd], sI[c4*4+1][dd], sI[c4*4+2][dd], sI[c4*4+3][dd]};
        *(int4*)(dst + ((size_t)b*NQ + q0 + dd)*NG + g0 + c4*4) = v;
    }
}

// ============ prep: fp32 act [b][rows][512] -> transposed hi/lo fp16 [b][512][rows] ============
__global__ __launch_bounds__(256) void actT_hl_k(const float* __restrict__ src,
    unsigned short* __restrict__ dstHi, unsigned short* __restrict__ dstLo, int Nrows){
    int b = blockIdx.z;
    int f0 = blockIdx.x*64, g0 = blockIdx.y*64;
    __shared__ float sF[64][65];
    int tid = threadIdx.x;
    #pragma unroll
    for (int it = 0; it < 4; ++it){
        int idx = it*256 + tid;
        int r = idx >> 4, c4 = idx & 15;
        float4 v = *(const float4*)(src + ((size_t)b*Nrows + g0 + r)*512 + f0 + c4*4);
        sF[r][c4*4+0]=v.x; sF[r][c4*4+1]=v.y; sF[r][c4*4+2]=v.z; sF[r][c4*4+3]=v.w;
    }
    __syncthreads();
    #pragma unroll
    for (int it = 0; it < 2; ++it){
        int idx = it*256 + tid;
        int dd = idx >> 3, c8 = idx & 7;
        unsigned short hi[8], lo[8];
        #pragma unroll
        for (int j = 0; j < 8; ++j){
            float x = sF[c8*8+j][dd];
            hi[j] = f2h(x);
            lo[j] = f2h(x - h2f(hi[j]));
        }
        size_t oo = ((size_t)b*512 + f0 + dd)*Nrows + g0 + c8*8;
        *(ushort4*)(dstHi+oo)   = ushort4{hi[0],hi[1],hi[2],hi[3]};
        *(ushort4*)(dstHi+oo+4) = ushort4{hi[4],hi[5],hi[6],hi[7]};
        *(ushort4*)(dstLo+oo)   = ushort4{lo[0],lo[1],lo[2],lo[3]};
        *(ushort4*)(dstLo+oo+4) = ushort4{lo[4],lo[5],lo[6],lo[7]};
    }
}

// ============ scores for q and kv in one launch ============
__global__ __launch_bounds__(256) void scores2_k(
    const unsigned short* __restrict__ qX, const float* __restrict__ wa1, float* __restrict__ qs, int nQblocks,
    const unsigned short* __restrict__ kX, const float* __restrict__ wa2, float* __restrict__ ks){
    int lane = threadIdx.x & 63;
    const unsigned short* X; const float* wa; float* sc; int row;
    if ((int)blockIdx.x < nQblocks){ X = qX; wa = wa1; sc = qs; row = blockIdx.x*4 + (threadIdx.x >> 6); }
    else { X = kX; wa = wa2; sc = ks; row = (blockIdx.x - nQblocks)*4 + (threadIdx.x >> 6); }
    const unsigned short* Xr = X + (size_t)row*NFEAT;
    float p[NHEADS];
    #pragma unroll
    for (int h = 0; h < NHEADS; ++h) p[h] = 0.f;
    #pragma unroll
    for (int c = 0; c < 8; ++c){
        float x = h2f(Xr[(c<<6) + lane]);
        #pragma unroll
        for (int h = 0; h < NHEADS; ++h) p[h] += x * wa[(h<<9) + (c<<6) + lane];
    }
    #pragma unroll
    for (int h = 0; h < NHEADS; ++h){
        float v = p[h];
        #pragma unroll
        for (int off = 32; off > 0; off >>= 1) v += __shfl_xor(v, off);
        if (lane == 0) sc[(size_t)row*NHEADS + h] = v;
    }
}

// ============ colmax partial / final ============
__global__ __launch_bounds__(256) void colmax_part_k(const int* __restrict__ adj, long bstride, int ns,
    const float* __restrict__ qs, float* __restrict__ pmax, int N, int M){
    int b = blockIdx.z, ch = blockIdx.y;
    int ml = threadIdx.x & 63; int m = blockIdx.x*64 + ml;
    int g = threadIdx.x >> 6;
    int chunk = N / CHUNKS, subl = chunk >> 2;
    int n0 = ch*chunk + g*subl, n1 = n0 + subl;
    const int* adjb = adj + (size_t)b*bstride;
    float mx[8];
    #pragma unroll
    for (int h = 0; h < 8; ++h) mx[h] = -INFINITY;
    for (int n = n0; n < n1; ++n){
        int a = adjb[(size_t)n*ns + m];
        const float* qr = qs + ((size_t)b*N + n)*8;
        #pragma unroll
        for (int h = 0; h < 8; ++h){ float qv = qr[h]; if (a > 0) mx[h] = fmaxf(mx[h], qv); }
    }
    __shared__ float smx[4][64][8];
    #pragma unroll
    for (int h = 0; h < 8; ++h) smx[g][ml][h] = mx[h];
    __syncthreads();
    if (g == 0){
        #pragma unroll
        for (int h = 0; h < 8; ++h){
            float v = fmaxf(fmaxf(smx[0][ml][h], smx[1][ml][h]), fmaxf(smx[2][ml][h], smx[3][ml][h]));
            pmax[(((size_t)b*CHUNKS + ch)*M + m)*8 + h] = v;
        }
    }
}

__global__ __launch_bounds__(256) void colmax_fin_k(const float* __restrict__ pmax, const float* __restrict__ ks,
    float* __restrict__ cmax, int M){
    int idx = blockIdx.x*256 + threadIdx.x;
    int m8 = M*8;
    int b = idx / m8;
    size_t base = (size_t)b*CHUNKS*m8 + (idx - (size_t)b*m8);
    float mx = -INFINITY;
    #pragma unroll
    for (int ch = 0; ch < CHUNKS; ++ch) mx = fmaxf(mx, pmax[base + (size_t)ch*m8]);
    cmax[idx] = (mx == -INFINITY) ? NEGV : lrelu(mx + ks[idx]);
}

__global__ __launch_bounds__(256) void colsum_part_k(const int* __restrict__ adj, long bstride, int ns,
    const float* __restrict__ qs, const float* __restrict__ ks, const float* __restrict__ cmax,
    float* __restrict__ psum, int N, int M){
    int b = blockIdx.z, ch = blockIdx.y;
    int ml = threadIdx.x & 63; int m = blockIdx.x*64 + ml;
    int g = threadIdx.x >> 6;
    int chunk = N / CHUNKS, subl = chunk >> 2;
    int n0 = ch*chunk + g*subl, n1 = n0 + subl;
    const int* adjb = adj + (size_t)b*bstride;
    float ksv[8], cmv[8], s[8];
    size_t mo = ((size_t)b*M + m)*8;
    #pragma unroll
    for (int h = 0; h < 8; ++h){ ksv[h] = ks[mo+h]; cmv[h] = cmax[mo+h]; s[h] = 0.f; }
    for (int n = n0; n < n1; ++n){
        int a = adjb[(size_t)n*ns + m];
        const float* qr = qs + ((size_t)b*N + n)*8;
        #pragma unroll
        for (int h = 0; h < 8; ++h){
            float e = (a > 0) ? lrelu(qr[h] + ksv[h]) : NEGV;
            s[h] += expf(e - cmv[h]);
        }
    }
    __shared__ float ssm[4][64][8];
    #pragma unroll
    for (int h = 0; h < 8; ++h) ssm[g][ml][h] = s[h];
    __syncthreads();
    if (g == 0){
        #pragma unroll
        for (int h = 0; h < 8; ++h){
            float v = ssm[0][ml][h] + ssm[1][ml][h] + ssm[2][ml][h] + ssm[3][ml][h];
            psum[(((size_t)b*CHUNKS + ch)*M + m)*8 + h] = v;
        }
    }
}

// ============ merged colsum finalize + stat repack: write ksh/cmh/ish [b][8][M] ============
__global__ __launch_bounds__(256) void colsum_fin2_k(const float* __restrict__ psum,
    const float* __restrict__ ks, const float* __restrict__ cmax,
    float* __restrict__ ksh, float* __restrict__ cmh, float* __restrict__ ish, int M){
    int idx = blockIdx.x*256 + threadIdx.x;
    int m8 = M*8;
    int b = idx / m8, rem = idx - b*m8;
    int m = rem >> 3, h = rem & 7;
    size_t base = (size_t)b*CHUNKS*m8 + rem;
    float S = 0.f;
    #pragma unroll
    for (int ch = 0; ch < CHUNKS; ++ch) S += psum[base + (size_t)ch*m8];
    size_t o = ((size_t)b*8 + h)*M + m;
    ksh[o] = ks[idx]; cmh[o] = cmax[idx]; ish[o] = 1.f/S;
}

// ============ fused fusion MFMA: all hi/lo passes in one in-register K-loop ============
// 64x64 tile; grid (8, rows/64, NB). npass: 1 = hi only; 3 = + (aLo,bLo)*Whi + (aHi,bHi)*Wlo
__global__ __launch_bounds__(256) void fusion_all_k(
    const unsigned short* __restrict__ aHi, const unsigned short* __restrict__ aLo,
    const unsigned short* __restrict__ bHi, const unsigned short* __restrict__ bLo,
    const unsigned short* __restrict__ Whi, const unsigned short* __restrict__ Wlo,
    unsigned short* __restrict__ dst, unsigned short* __restrict__ dstLo,
    unsigned short* __restrict__ dstT, unsigned short* __restrict__ dstTLo,
    float* __restrict__ dstF, int rows, int npass){
    int b = blockIdx.z;
    int r0 = blockIdx.y*64, c0 = blockIdx.x*64;
    int tid = threadIdx.x;
    __shared__ unsigned short aHs[64*LSTR], aLs[64*LSTR], bHs[64*LSTR], bLs[64*LSTR];
    __shared__ unsigned short wHs[4*64*LSTR], wLs[4*64*LSTR];
    size_t actOff = (size_t)b*rows*512;
    const unsigned short* aHG = aHi + actOff;
    const unsigned short* bHG = bHi + actOff;
    const unsigned short* aLG = aLo ? aLo + actOff : nullptr;
    const unsigned short* bLG = bLo ? bLo + actOff : nullptr;
    bool multi = (npass == 3);
    bool hasALo = multi && (aLG != nullptr);
    bool hasBLo = multi && (bLG != nullptr);
    int w = tid >> 6, lane = tid & 63;
    int lrow = lane & 15, quad = lane >> 4;
    v4f accN[4], accF[4];
    #pragma unroll
    for (int cf = 0; cf < 4; ++cf){ accN[cf] = (v4f)0.f; accF[cf] = (v4f)0.f; }
    for (int kt = 0; kt < 512; kt += 32){
        __syncthreads();
        {
            int row = tid >> 2, c4 = tid & 3;
            size_t go = (size_t)(r0+row)*512 + kt + c4*8;
            int lo = row*LSTR + c4*8;
            uint4 za; za.x = za.y = za.z = za.w = 0u;
            *(uint4*)&aHs[lo] = *(const uint4*)(aHG + go);
            *(uint4*)&bHs[lo] = *(const uint4*)(bHG + go);
            if (multi){
                *(uint4*)&aLs[lo] = hasALo ? *(const uint4*)(aLG + go) : za;
                *(uint4*)&bLs[lo] = hasBLo ? *(const uint4*)(bLG + go) : za;
            }
        }
        #pragma unroll
        for (int it = 0; it < 4; ++it){
            int idx = it*256 + tid;
            int mat = idx >> 8, row = (idx >> 2) & 63, c4 = idx & 3;
            size_t go = ((size_t)mat*512 + c0 + row)*512 + kt + c4*8;
            int lo = (mat*64+row)*LSTR + c4*8;
            *(uint4*)&wHs[lo] = *(const uint4*)(Whi + go);
            if (multi) *(uint4*)&wLs[lo] = *(const uint4*)(Wlo + go);
        }
        __syncthreads();
        int arow = (w*16 + lrow)*LSTR + quad*8;
        v8h ah = *(const v8h*)&aHs[arow];
        v8h bh = *(const v8h*)&bHs[arow];
        v8h al, bl;
        if (multi){ al = *(const v8h*)&aLs[arow]; bl = *(const v8h*)&bLs[arow]; }
        #pragma unroll
        for (int cf = 0; cf < 4; ++cf){
            int wrow = (cf*16 + lrow)*LSTR + quad*8;
            v8h w0 = *(const v8h*)&wHs[wrow];
            v8h w1 = *(const v8h*)&wHs[64*LSTR + wrow];
            v8h w2 = *(const v8h*)&wHs[128*LSTR + wrow];
            v8h w3 = *(const v8h*)&wHs[192*LSTR + wrow];
            accN[cf] = MFMA16(ah, w0, accN[cf]);
            accN[cf] = MFMA16(bh, w1, accN[cf]);
            accF[cf] = MFMA16(ah, w2, accF[cf]);
            accF[cf] = MFMA16(bh, w3, accF[cf]);
            if (multi){
                if (hasALo){ accN[cf] = MFMA16(al, w0, accN[cf]); accF[cf] = MFMA16(al, w2, accF[cf]); }
                if (hasBLo){ accN[cf] = MFMA16(bl, w1, accN[cf]); accF[cf] = MFMA16(bl, w3, accF[cf]); }
                v8h l0 = *(const v8h*)&wLs[wrow];
                v8h l1 = *(const v8h*)&wLs[64*LSTR + wrow];
                v8h l2 = *(const v8h*)&wLs[128*LSTR + wrow];
                v8h l3 = *(const v8h*)&wLs[192*LSTR + wrow];
                accN[cf] = MFMA16(ah, l0, accN[cf]);
                accN[cf] = MFMA16(bh, l1, accN[cf]);
                accF[cf] = MFMA16(ah, l2, accF[cf]);
                accF[cf] = MFMA16(bh, l3, accF[cf]);
            }
        }
    }
    #pragma unroll
    for (int cf = 0; cf < 4; ++cf){
        int colg = c0 + cf*16 + lrow;
        int rbase = r0 + w*16 + quad*4;
        float o4[4];
        #pragma unroll
        for (int reg = 0; reg < 4; ++reg){
            float f = 1.f/(1.f + expf(-accF[cf][reg]));
            size_t ai = (size_t)(rbase+reg)*512 + colg;
            float ao = h2f(aHG[ai]);
            if (aLG) ao += h2f(aLG[ai]);
            o4[reg] = f*accN[cf][reg] + (1.f - f)*ao;
            size_t oo = ((size_t)b*rows + rbase + reg)*512 + colg;
            unsigned short hv = f2h(o4[reg]);
            dst[oo] = hv;
            if (dstLo) dstLo[oo] = f2h(o4[reg] - h2f(hv));
            if (dstF) dstF[oo] = o4[reg];
        }
        if (dstT){
            unsigned short h0 = f2h(o4[0]), h1 = f2h(o4[1]), h2 = f2h(o4[2]), h3 = f2h(o4[3]);
            size_t to = ((size_t)b*512 + colg)*rows + rbase;
            *(ushort4*)&dstT[to] = ushort4{h0,h1,h2,h3};
            if (dstTLo)
                *(ushort4*)&dstTLo[to] = ushort4{f2h(o4[0]-h2f(h0)), f2h(o4[1]-h2f(h1)),
                                                 f2h(o4[2]-h2f(h2)), f2h(o4[3]-h2f(h3))};
        }
    }
}

// ============ generic MFMA GEMM (64-row tiles): C[b] = A[b]@BT^T (+ A[b]@BT2^T) ============
__global__ __launch_bounds__(256) void gemmT_mfma_k(
    const unsigned short* __restrict__ A, size_t aStride,
    const unsigned short* __restrict__ BT, const unsigned short* __restrict__ BT2, size_t bStride,
    int K, int rowsPB,
    unsigned short* __restrict__ outRM, unsigned short* __restrict__ outLo,
    unsigned short* __restrict__ outT){
    int b = blockIdx.z;
    int r0 = blockIdx.y*64, c0 = blockIdx.x*64;
    int tid = threadIdx.x;
    __shared__ unsigned short aS[64*LSTR];
    __shared__ unsigned short bS[64*LSTR];
    const unsigned short* aG = A + (size_t)b*aStride;
    int w = tid >> 6, lane = tid & 63;
    int lrow = lane & 15, quad = lane >> 4;
    v4f acc[4];
    #pragma unroll
    for (int cf = 0; cf < 4; ++cf) acc[cf] = (v4f)0.f;
    for (int p = 0; p < 2; ++p){
        if (p == 1 && BT2 == nullptr) break;
        const unsigned short* bG = (p ? BT2 : BT) + (size_t)b*bStride;
        for (int kt = 0; kt < K; kt += 32){
            __syncthreads();
            {
                int row = tid >> 2, c4 = tid & 3;
                *(uint4*)&aS[row*LSTR + c4*8] = *(const uint4*)(aG + (size_t)(r0+row)*K + kt + c4*8);
                *(uint4*)&bS[row*LSTR + c4*8] = *(const uint4*)(bG + (size_t)(c0+row)*K + kt + c4*8);
            }
            __syncthreads();
            v8h af = *(const v8h*)&aS[(w*16 + lrow)*LSTR + quad*8];
            #pragma unroll
            for (int cf = 0; cf < 4; ++cf){
                v8h bf = *(const v8h*)&bS[(cf*16 + lrow)*LSTR + quad*8];
                acc[cf] = MFMA16(af, bf, acc[cf]);
            }
        }
    }
    #pragma unroll
    for (int cf = 0; cf < 4; ++cf){
        int colg = c0 + cf*16 + lrow;
        int rbase = r0 + w*16 + quad*4;
        if (outRM){
            #pragma unroll
            for (int reg = 0; reg < 4; ++reg){
                float v = acc[cf][reg];
                unsigned short hv = f2h(v);
                size_t oo = ((size_t)b*rowsPB + rbase + reg)*512 + colg;
                outRM[oo] = hv;
                if (outLo) outLo[oo] = f2h(v - h2f(hv));
            }
        }
        if (outT){
            ushort4 pk{f2h(acc[cf][0]), f2h(acc[cf][1]), f2h(acc[cf][2]), f2h(acc[cf][3])};
            *(ushort4*)&outT[((size_t)b*512 + colg)*rowsPB + rbase] = pk;
        }
    }
}

// ============ attention output MFMA ============
__global__ __launch_bounds__(256) void attn_mfma_k(const int* __restrict__ adj, long bstride, int ns,
    const float* __restrict__ qs, const float* __restrict__ ksh, const float* __restrict__ cmh,
    const float* __restrict__ ish, const unsigned short* __restrict__ WkT,
    unsigned short* __restrict__ outp, int N, int M){
    int bh = blockIdx.y; int b = bh >> 3, h = bh & 7;
    int n0 = blockIdx.x*64;
    int tid = threadIdx.x;
    __shared__ unsigned short pS[64*LSTR];
    __shared__ unsigned short wS[64*LSTR];
    __shared__ float qsS[64];
    if (tid < 64) qsS[tid] = qs[((size_t)b*N + n0 + tid)*8 + h];
    const int* adjb = adj + (size_t)b*bstride;
    const float* ksb = ksh + ((size_t)b*8 + h)*M;
    const float* cmb = cmh + ((size_t)b*8 + h)*M;
    const float* isb = ish + ((size_t)b*8 + h)*M;
    const unsigned short* wkb = WkT + ((size_t)b*512 + h*64)*M;
    int w = tid >> 6, lane = tid & 63;
    int lrow = lane & 15, quad = lane >> 4;
    int pn = tid >> 2, pm = (tid & 3)*8;
    v4f acc[4];
    #pragma unroll
    for (int cf = 0; cf < 4; ++cf) acc[cf] = (v4f)0.f;
    for (int mt = 0; mt < M; mt += 32){
        __syncthreads();
        *(uint4*)&wS[(tid>>2)*LSTR + (tid&3)*8] = *(const uint4*)(wkb + (size_t)(tid>>2)*M + mt + (tid&3)*8);
        const int* arow = adjb + (size_t)(n0+pn)*ns + mt + pm;
        int4 a0 = *(const int4*)arow;
        int4 a1 = *(const int4*)(arow + 4);
        float4 k0 = *(const float4*)(ksb + mt + pm), k1 = *(const float4*)(ksb + mt + pm + 4);
        float4 c0v = *(const float4*)(cmb + mt + pm), c1v = *(const float4*)(cmb + mt + pm + 4);
        float4 i0 = *(const float4*)(isb + mt + pm), i1 = *(const float4*)(isb + mt + pm + 4);
        float qv = qsS[pn];
        float p[8];
        const int* aa0 = &a0.x; const int* aa1 = &a1.x;
        const float* kk0 = &k0.x; const float* kk1 = &k1.x;
        const float* cc0 = &c0v.x; const float* cc1 = &c1v.x;
        const float* ii0 = &i0.x; const float* ii1 = &i1.x;
        #pragma unroll
        for (int j = 0; j < 4; ++j){
            float e = (aa0[j] > 0) ? lrelu(qv + kk0[j]) : NEGV;
            p[j] = expf(e - cc0[j]) * ii0[j];
        }
        #pragma unroll
        for (int j = 0; j < 4; ++j){
            float e = (aa1[j] > 0) ? lrelu(qv + kk1[j]) : NEGV;
            p[4+j] = expf(e - cc1[j]) * ii1[j];
        }
        ushort4 pk0{f2h(p[0]), f2h(p[1]), f2h(p[2]), f2h(p[3])};
        ushort4 pk1{f2h(p[4]), f2h(p[5]), f2h(p[6]), f2h(p[7])};
        *(ushort4*)&pS[pn*LSTR + pm] = pk0;
        *(ushort4*)&pS[pn*LSTR + pm + 4] = pk1;
        __syncthreads();
        v8h af = *(const v8h*)&pS[(w*16 + lrow)*LSTR + quad*8];
        #pragma unroll
        for (int cf = 0; cf < 4; ++cf){
            v8h bf = *(const v8h*)&wS[(cf*16 + lrow)*LSTR + quad*8];
            acc[cf] = MFMA16(af, bf, acc[cf]);
        }
    }
    #pragma unroll
    for (int cf = 0; cf < 4; ++cf){
        int colg = h*64 + cf*16 + lrow;
        int rbase = n0 + w*16 + quad*4;
        #pragma unroll
        for (int reg = 0; reg < 4; ++reg){
            float v = acc[cf][reg];
            v = (v > 0.f) ? v : expm1f(v);
            outp[((size_t)b*N + rbase + reg)*512 + colg] = f2h(v);
        }
    }
}

extern "C" void kernel_launch(void* const* d_in, const int* in_sizes, int n_in,
                              void* d_out, int out_size, void* d_ws, size_t ws_size,
                              hipStream_t stream){
    const float* in_gloss = (const float*)d_in[0];
    const float* in_clip  = (const float*)d_in[1];
    const float* in_q     = (const float*)d_in[2];
    const int*   adj_gc   = (const int*)d_in[3];
    const int*   adj_gq   = (const int*)d_in[4];
    const float* c2gW  = (const float*)d_in[5];
    const float* c2ga1 = (const float*)d_in[6];
    const float* c2ga2 = (const float*)d_in[7];
    const float* g2qW  = (const float*)d_in[8];
    const float* g2qa1 = (const float*)d_in[9];
    const float* g2qa2 = (const float*)d_in[10];
    const float* q2gW  = (const float*)d_in[11];
    const float* q2ga1 = (const float*)d_in[12];
    const float* q2ga2 = (const float*)d_in[13];
    const float* fusW  = (const float*)d_in[14];
    const float* fusU  = (const float*)d_in[15];
    const float* fusWf = (const float*)d_in[16];
    const float* fusUf = (const float*)d_in[17];
    float* out = (float*)d_out;
    float* out_gloss = out;
    float* out_clip  = out + (size_t)NB*NG*NFEAT;
    float* out_q     = out + (size_t)NB*NG*NFEAT*2;

    char* wsB = (char*)d_ws;
    size_t off = 0;
    auto alloc = [&](size_t bytes){ void* p = wsB + off; off += (bytes + 255) & ~(size_t)255; return p; };
    float* wa1   = (float*)alloc(4096*4);
    float* wa2   = (float*)alloc(4096*4);
    float* qsb   = (float*)alloc((size_t)NB*NG*8*4);
    float* ksb   = (float*)alloc((size_t)NB*NG*8*4);
    float* cmaxb = (float*)alloc((size_t)NB*NG*8*4);
    float* ksh   = (float*)alloc((size_t)NB*NG*8*4);
    float* cmh   = (float*)alloc((size_t)NB*NG*8*4);
    float* ish   = (float*)alloc((size_t)NB*NG*8*4);
    float* pmaxb = (float*)alloc((size_t)NB*CHUNKS*NG*8*4);
    float* psumb = (float*)alloc((size_t)NB*CHUNKS*NG*8*4);
    unsigned short* WflatT  = (unsigned short*)alloc((size_t)NFEAT*NFEAT*2);
    unsigned short* wtAll   = (unsigned short*)alloc((size_t)32*FF*2);
    unsigned short* wtAllLo = (unsigned short*)alloc((size_t)32*FF*2);
    unsigned short* adjTgc  = (unsigned short*)alloc((size_t)NB*NC*NG*2);
    unsigned short* g_bf0   = (unsigned short*)alloc((size_t)NB*NG*NFEAT*2);
    unsigned short* gLo0    = (unsigned short*)alloc((size_t)NB*NG*NFEAT*2);
    unsigned short* g_bf1   = (unsigned short*)alloc((size_t)NB*NG*NFEAT*2);
    unsigned short* gLo1    = (unsigned short*)alloc((size_t)NB*NG*NFEAT*2);
    unsigned short* gT      = (unsigned short*)alloc((size_t)NB*NFEAT*NG*2);
    unsigned short* gTlo    = (unsigned short*)alloc((size_t)NB*NFEAT*NG*2);
    unsigned short* gA_bf   = (unsigned short*)alloc((size_t)NB*NG*NFEAT*2);
    unsigned short* gALo    = (unsigned short*)alloc((size_t)NB*NG*NFEAT*2);
    unsigned short* c_bf0   = (unsigned short*)alloc((size_t)NB*NC*NFEAT*2);
    unsigned short* cLo0    = (unsigned short*)alloc((size_t)NB*NC*NFEAT*2);
    unsigned short* c_bf1   = (unsigned short*)alloc((size_t)NB*NC*NFEAT*2);
    unsigned short* cLo1    = (unsigned short*)alloc((size_t)NB*NC*NFEAT*2);
    unsigned short* q_bf0   = (unsigned short*)alloc((size_t)NB*NQ*NFEAT*2);
    unsigned short* q_bf1   = (unsigned short*)alloc((size_t)NB*NQ*NFEAT*2);
    unsigned short* agg_bf  = (unsigned short*)alloc((size_t)NB*NG*NFEAT*2);
    unsigned short* aggLo   = (unsigned short*)alloc((size_t)NB*NG*NFEAT*2);
    unsigned short* WkT     = (unsigned short*)alloc((size_t)NB*NFEAT*NG*2);
    int* adjTgq = (int*)alloc((size_t)NB*NQ*NG*4);
    (void)ws_size; (void)in_sizes; (void)n_in; (void)out_size;

    const size_t HFD = (size_t)NHEADS*NFEAT*HDIM;
    const size_t HD  = (size_t)NHEADS*HDIM;

    // ---- prep ----
    wtT_k<<<2048, 256, 0, stream>>>(fusW, fusU, fusWf, fusUf, wtAll, wtAllLo);
    adjT_h_k<<<dim3(NC/64, NG/64, NB), 256, 0, stream>>>(adj_gc, adjTgc);
    adjT_int_k<<<dim3(NQ/64, NG/64, NB), 256, 0, stream>>>(adj_gq, adjTgq);
    cvt_hl_k<<<(NB*NG*NFEAT)/2048, 256, 0, stream>>>(in_gloss, g_bf0, gLo0);
    cvt_hl_k<<<(NB*NC*NFEAT)/2048, 256, 0, stream>>>(in_clip,  c_bf0, cLo0);
    cvt_h_k<<<(NB*NQ*NFEAT)/2048, 256, 0, stream>>>(in_q,     q_bf0);
    actT_hl_k<<<dim3(8, NG/64, NB), 256, 0, stream>>>(in_gloss, gT, gTlo, NG);

    auto run_attn = [&](const unsigned short* qX, int N, const unsigned short* kvX, int M,
                        const int* adjp, long bstride, int ns,
                        const float* W, const float* a1, const float* a2, unsigned short* dst){
        prep_attnW_k<<<80, 256, 0, stream>>>(W, a1, a2, WflatT, wa1, wa2);
        scores2_k<<<(NB*(N+M))/4, 256, 0, stream>>>(qX, wa1, qsb, (NB*N)/4, kvX, wa2, ksb);
        gemmT_mfma_k<<<dim3(8, M/64, NB), 256, 0, stream>>>(kvX, (size_t)M*512, WflatT, nullptr, 0,
                                                            512, M, nullptr, nullptr, WkT);
        colmax_part_k<<<dim3(M/64, CHUNKS, NB), 256, 0, stream>>>(adjp, bstride, ns, qsb, pmaxb, N, M);
        colmax_fin_k<<<(NB*M*8)/256, 256, 0, stream>>>(pmaxb, ksb, cmaxb, M);
        colsum_part_k<<<dim3(M/64, CHUNKS, NB), 256, 0, stream>>>(adjp, bstride, ns, qsb, ksb, cmaxb, psumb, N, M);
        colsum_fin2_k<<<(NB*M*8)/256, 256, 0, stream>>>(psumb, ksb, cmaxb, ksh, cmh, ish, M);
        attn_mfma_k<<<dim3(N/64, NB*8), 256, 0, stream>>>(adjp, bstride, ns, qsb, ksh, cmh, ish,
                                                          WkT, dst, N, M);
    };
    auto run_fusion = [&](const unsigned short* a, const unsigned short* aLo,
                          const unsigned short* bb, const unsigned short* bLo, int rows,
                          int l, int i, int npass,
                          unsigned short* dst, unsigned short* dstLo,
                          unsigned short* dstT, unsigned short* dstTLo, float* dstF){
        const unsigned short* Whi = wtAll   + (size_t)((l*4 + i)*4)*FF;
        const unsigned short* Wlo = wtAllLo + (size_t)((l*4 + i)*4)*FF;
        fusion_all_k<<<dim3(8, rows/64, NB), 256, 0, stream>>>(
            a, aLo, bb, bLo, Whi, Wlo, dst, dstLo, dstT, dstTLo, dstF, rows, npass);
    };

    for (int l = 0; l < 2; ++l){
        const unsigned short* g_cur = (l == 0) ? g_bf0 : g_bf1;
        const unsigned short* gLoC  = (l == 0) ? gLo0  : gLo1;
        const unsigned short* c_cur = (l == 0) ? c_bf0 : c_bf1;
        const unsigned short* cLoC  = (l == 0) ? cLo0  : cLo1;
        const unsigned short* q_cur = (l == 0) ? q_bf0 : q_bf1;
        unsigned short* g_nxt = (l == 0) ? g_bf1 : g_bf0;
        unsigned short* gLoN  = (l == 0) ? gLo1  : nullptr;
        unsigned short* c_nxt = (l == 0) ? c_bf1 : c_bf0;
        unsigned short* cLoN  = (l == 0) ? cLo1  : nullptr;
        unsigned short* q_nxt = (l == 0) ? q_bf1 : q_bf0;
        float* gF = (l == 1) ? out_gloss : nullptr;
        float* cF = (l == 1) ? out_clip  : nullptr;
        float* qF = (l == 1) ? out_q     : nullptr;

        // gloss_same = adj_gc^T @ gloss  (hi/lo B, hi/lo out)
        gemmT_mfma_k<<<dim3(8, NC/64, NB), 256, 0, stream>>>(adjTgc, (size_t)NC*NG, gT, gTlo,
                                                             (size_t)512*NG, NG, NC,
                                                             agg_bf, aggLo, nullptr);
        // clip_1 (3-pass hi/lo)
        run_fusion(c_cur, cLoC, agg_bf, aggLo, NC, l, 0, 3,
                   c_nxt, cLoN, nullptr, nullptr, cF);
        // clip_agg = attn(q=gloss, kv=clip, adj_gc)
        run_attn(g_cur, NG, c_cur, NC, adj_gc, (long)NG*NC, NC,
                 c2gW + l*HFD, c2ga1 + l*HD, c2ga2 + l*HD, agg_bf);
        // gloss_1 (3-pass: a-lo + weight-lo; b-lo absent)
        run_fusion(g_cur, gLoC, agg_bf, nullptr, NG, l, 1, 3,
                   gA_bf, gALo, nullptr, nullptr, nullptr);
        // gloss_agg = attn(q=question, kv=gloss, adjT_gq)
        run_attn(q_cur, NQ, g_cur, NG, adjTgq, (long)NQ*NG, NG,
                 g2qW + l*HFD, g2qa1 + l*HD, g2qa2 + l*HD, agg_bf);
        // question_1 (single pass)
        run_fusion(q_cur, nullptr, agg_bf, nullptr, NQ, l, 2, 1,
                   q_nxt, nullptr, nullptr, nullptr, qF);
        // question_agg = attn(q=gloss, kv=question, adj_gq)
        run_attn(g_cur, NG, q_cur, NQ, adj_gq, (long)NG*NQ, NQ,
                 q2gW + l*HFD, q2ga1 + l*HD, q2ga2 + l*HD, agg_bf);
        // gloss_2 (3-pass; emit hi/lo + transposed hi/lo for next layer's gloss_same)
        run_fusion(gA_bf, gALo, agg_bf, nullptr, NG, l, 3, 3,
                   g_nxt, gLoN, (l == 0) ? gT : nullptr, (l == 0) ? gTlo : nullptr, gF);
    }
}

// Round 9
// 1200.570 us; speedup vs baseline: 4.3902x; 1.0491x over previous
//
#include <hip/hip_runtime.h>
#include <math.h>

#define NFEAT 512
#define NHEADS 8
#define HDIM 64
#define NB 4
#define NG 1024
#define NC 1024
#define NQ 256
#define NEGV -9e15f
#define CHUNKS 16
#define FF ((size_t)NFEAT*NFEAT)
#define LSTR 36   // LDS row stride (ushorts): 32 payload + 4 pad

typedef _Float16 v8h __attribute__((ext_vector_type(8)));
typedef float v4f __attribute__((ext_vector_type(4)));
#define MFMA16(a,b,c) __builtin_amdgcn_mfma_f32_16x16x32_f16((a),(b),(c),0,0,0)

__device__ __forceinline__ float lrelu(float x){ return fmaxf(x, 0.2f*x); }
__device__ __forceinline__ unsigned short f2h(float x){ union{_Float16 h; unsigned short u;} v; v.h = (_Float16)x; return v.u; }
__device__ __forceinline__ float h2f(unsigned short u){ union{_Float16 h; unsigned short u;} v; v.u = u; return (float)v.h; }

// ============ prep: fp32 -> fp16 flat ============
__global__ __launch_bounds__(256) void cvt_h_k(const float* __restrict__ src, unsigned short* __restrict__ dst){
    int idx = blockIdx.x*256 + threadIdx.x;
    const float4* s = (const float4*)(src + (size_t)idx*8);
    float4 a = s[0], b = s[1];
    ushort4 p0{f2h(a.x),f2h(a.y),f2h(a.z),f2h(a.w)};
    ushort4 p1{f2h(b.x),f2h(b.y),f2h(b.z),f2h(b.w)};
    *(ushort4*)(dst + (size_t)idx*8) = p0;
    *(ushort4*)(dst + (size_t)idx*8 + 4) = p1;
}

// ============ prep: fp32 -> fp16 hi/lo flat ============
__global__ __launch_bounds__(256) void cvt_hl_k(const float* __restrict__ src,
    unsigned short* __restrict__ dstHi, unsigned short* __restrict__ dstLo){
    int idx = blockIdx.x*256 + threadIdx.x;
    const float4* s = (const float4*)(src + (size_t)idx*8);
    float4 a = s[0], b = s[1];
    float x[8] = {a.x,a.y,a.z,a.w,b.x,b.y,b.z,b.w};
    unsigned short hi[8], lo[8];
    #pragma unroll
    for (int j = 0; j < 8; ++j){ hi[j] = f2h(x[j]); lo[j] = f2h(x[j] - h2f(hi[j])); }
    *(ushort4*)(dstHi + (size_t)idx*8)     = ushort4{hi[0],hi[1],hi[2],hi[3]};
    *(ushort4*)(dstHi + (size_t)idx*8 + 4) = ushort4{hi[4],hi[5],hi[6],hi[7]};
    *(ushort4*)(dstLo + (size_t)idx*8)     = ushort4{lo[0],lo[1],lo[2],lo[3]};
    *(ushort4*)(dstLo + (size_t)idx*8 + 4) = ushort4{lo[4],lo[5],lo[6],lo[7]};
}

// ============ prep: fusion weights -> transposed fp16 hi/lo, all 32 matrices ============
__global__ __launch_bounds__(256) void wtT_k(const float* __restrict__ w0, const float* __restrict__ w1,
    const float* __restrict__ w2, const float* __restrict__ w3,
    unsigned short* __restrict__ dstHi, unsigned short* __restrict__ dstLo){
    int bx = blockIdx.x;
    int mat = bx >> 6, t = bx & 63;
    int a = mat & 3, li = mat >> 2;
    const float* src = (a==0?w0:a==1?w1:a==2?w2:w3) + (size_t)li*FF;
    int fo0 = (t>>3)*64, fi0 = (t&7)*64;
    __shared__ float sT[64][65];
    int tid = threadIdx.x;
    #pragma unroll
    for (int it = 0; it < 4; ++it){
        int idx = it*256 + tid;
        int r = idx >> 4, c4 = idx & 15;
        float4 v = *(const float4*)(src + (size_t)(fi0+r)*512 + fo0 + c4*4);
        sT[r][c4*4+0]=v.x; sT[r][c4*4+1]=v.y; sT[r][c4*4+2]=v.z; sT[r][c4*4+3]=v.w;
    }
    __syncthreads();
    #pragma unroll
    for (int it = 0; it < 2; ++it){
        int idx = it*256 + tid;
        int dd = idx >> 3, c8 = idx & 7;
        unsigned short hi[8], lo[8];
        #pragma unroll
        for (int j = 0; j < 8; ++j){
            float x = sT[c8*8+j][dd];
            hi[j] = f2h(x);
            lo[j] = f2h(x - h2f(hi[j]));
        }
        size_t oo = (size_t)mat*FF + (size_t)(fo0+dd)*512 + fi0 + c8*8;
        *(ushort4*)(dstHi+oo)   = ushort4{hi[0],hi[1],hi[2],hi[3]};
        *(ushort4*)(dstHi+oo+4) = ushort4{hi[4],hi[5],hi[6],hi[7]};
        *(ushort4*)(dstLo+oo)   = ushort4{lo[0],lo[1],lo[2],lo[3]};
        *(ushort4*)(dstLo+oo+4) = ushort4{lo[4],lo[5],lo[6],lo[7]};
    }
}

// ============ prep: attention W repack (blocks 0..63) + wa vectors (blocks 64..79) ============
__global__ __launch_bounds__(256) void prep_attnW_k(const float* __restrict__ W,
    const float* __restrict__ a1, const float* __restrict__ a2,
    unsigned short* __restrict__ WT, float* __restrict__ wa1, float* __restrict__ wa2){
    int bx = blockIdx.x;
    int tid = threadIdx.x;
    if (bx >= 64){
        int idx = (bx - 64)*256 + tid;
        int h = idx >> 9;
        const float* Wp = W + (size_t)idx*64;
        float s1 = 0.f, s2 = 0.f;
        #pragma unroll
        for (int d = 0; d < 64; ++d){ float w = Wp[d]; s1 += w*a1[(h<<6)+d]; s2 += w*a2[(h<<6)+d]; }
        wa1[idx] = s1; wa2[idx] = s2;
        return;
    }
    int h = bx >> 3, f0 = (bx & 7)*64;
    __shared__ float sT[64][65];
    #pragma unroll
    for (int it = 0; it < 4; ++it){
        int idx = it*256 + tid;
        int r = idx >> 4, c4 = idx & 15;
        float4 v = *(const float4*)(W + ((size_t)h*512 + f0 + r)*64 + c4*4);
        sT[r][c4*4+0]=v.x; sT[r][c4*4+1]=v.y; sT[r][c4*4+2]=v.z; sT[r][c4*4+3]=v.w;
    }
    __syncthreads();
    #pragma unroll
    for (int it = 0; it < 2; ++it){
        int idx = it*256 + tid;
        int dd = idx >> 3, c8 = idx & 7;
        ushort4 p0{f2h(sT[c8*8+0][dd]),f2h(sT[c8*8+1][dd]),f2h(sT[c8*8+2][dd]),f2h(sT[c8*8+3][dd])};
        ushort4 p1{f2h(sT[c8*8+4][dd]),f2h(sT[c8*8+5][dd]),f2h(sT[c8*8+6][dd]),f2h(sT[c8*8+7][dd])};
        unsigned short* o = WT + ((size_t)h*64 + dd)*512 + f0 + c8*8;
        *(ushort4*)o = p0; *(ushort4*)(o+4) = p1;
    }
}

// ============ prep: adj_gc [b][g][c] int -> adjT fp16 [b][c][g] ============
__global__ __launch_bounds__(256) void adjT_h_k(const int* __restrict__ adj, unsigned short* __restrict__ dst){
    int b = blockIdx.z;
    int c0 = blockIdx.x*64, g0 = blockIdx.y*64;
    __shared__ int sI[64][65];
    int tid = threadIdx.x;
    #pragma unroll
    for (int it = 0; it < 4; ++it){
        int idx = it*256 + tid;
        int r = idx >> 4, c4 = idx & 15;
        int4 v = *(const int4*)(adj + ((size_t)b*NG + g0 + r)*NC + c0 + c4*4);
        sI[r][c4*4+0]=v.x; sI[r][c4*4+1]=v.y; sI[r][c4*4+2]=v.z; sI[r][c4*4+3]=v.w;
    }
    __syncthreads();
    #pragma unroll
    for (int it = 0; it < 2; ++it){
        int idx = it*256 + tid;
        int dd = idx >> 3, c8 = idx & 7;
        ushort4 p0, p1;
        #pragma unroll
        for (int j = 0; j < 4; ++j) (&p0.x)[j] = sI[c8*8+j][dd] > 0 ? (unsigned short)0x3C00 : (unsigned short)0;
        #pragma unroll
        for (int j = 0; j < 4; ++j) (&p1.x)[j] = sI[c8*8+4+j][dd] > 0 ? (unsigned short)0x3C00 : (unsigned short)0;
        unsigned short* o = dst + ((size_t)b*NC + c0 + dd)*NG + g0 + c8*8;
        *(ushort4*)o = p0; *(ushort4*)(o+4) = p1;
    }
}

// ============ prep: adj_gq [b][g][q] int -> adjT int [b][q][g] ============
__global__ __launch_bounds__(256) void adjT_int_k(const int* __restrict__ adj, int* __restrict__ dst){
    int b = blockIdx.z;
    int q0 = blockIdx.x*64, g0 = blockIdx.y*64;
    __shared__ int sI[64][65];
    int tid = threadIdx.x;
    #pragma unroll
    for (int it = 0; it < 4; ++it){
        int idx = it*256 + tid;
        int r = idx >> 4, c4 = idx & 15;
        int4 v = *(const int4*)(adj + ((size_t)b*NG + g0 + r)*NQ + q0 + c4*4);
        sI[r][c4*4+0]=v.x; sI[r][c4*4+1]=v.y; sI[r][c4*4+2]=v.z; sI[r][c4*4+3]=v.w;
    }
    __syncthreads();
    #pragma unroll
    for (int it = 0; it < 4; ++it){
        int idx = it*256 + tid;
        int dd = idx >> 4, c4 = idx & 15;
        int4 v{sI[c4*4+0][dd], sI[c4*4+1][dd], sI[c4*4+2][dd], sI[c4*4+3][dd]};
        *(int4*)(dst + ((size_t)b*NQ + q0 + dd)*NG + g0 + c4*4) = v;
    }
}

// ============ prep: fp32 act [b][rows][512] -> transposed hi/lo fp16 [b][512][rows] ============
__global__ __launch_bounds__(256) void actT_hl_k(const float* __restrict__ src,
    unsigned short* __restrict__ dstHi, unsigned short* __restrict__ dstLo, int Nrows){
    int b = blockIdx.z;
    int f0 = blockIdx.x*64, g0 = blockIdx.y*64;
    __shared__ float sF[64][65];
    int tid = threadIdx.x;
    #pragma unroll
    for (int it = 0; it < 4; ++it){
        int idx = it*256 + tid;
        int r = idx >> 4, c4 = idx & 15;
        float4 v = *(const float4*)(src + ((size_t)b*Nrows + g0 + r)*512 + f0 + c4*4);
        sF[r][c4*4+0]=v.x; sF[r][c4*4+1]=v.y; sF[r][c4*4+2]=v.z; sF[r][c4*4+3]=v.w;
    }
    __syncthreads();
    #pragma unroll
    for (int it = 0; it < 2; ++it){
        int idx = it*256 + tid;
        int dd = idx >> 3, c8 = idx & 7;
        unsigned short hi[8], lo[8];
        #pragma unroll
        for (int j = 0; j < 8; ++j){
            float x = sF[c8*8+j][dd];
            hi[j] = f2h(x);
            lo[j] = f2h(x - h2f(hi[j]));
        }
        size_t oo = ((size_t)b*512 + f0 + dd)*Nrows + g0 + c8*8;
        *(ushort4*)(dstHi+oo)   = ushort4{hi[0],hi[1],hi[2],hi[3]};
        *(ushort4*)(dstHi+oo+4) = ushort4{hi[4],hi[5],hi[6],hi[7]};
        *(ushort4*)(dstLo+oo)   = ushort4{lo[0],lo[1],lo[2],lo[3]};
        *(ushort4*)(dstLo+oo+4) = ushort4{lo[4],lo[5],lo[6],lo[7]};
    }
}

// ============ scores for q and kv in one launch ============
__global__ __launch_bounds__(256) void scores2_k(
    const unsigned short* __restrict__ qX, const float* __restrict__ wa1, float* __restrict__ qs, int nQblocks,
    const unsigned short* __restrict__ kX, const float* __restrict__ wa2, float* __restrict__ ks){
    int lane = threadIdx.x & 63;
    const unsigned short* X; const float* wa; float* sc; int row;
    if ((int)blockIdx.x < nQblocks){ X = qX; wa = wa1; sc = qs; row = blockIdx.x*4 + (threadIdx.x >> 6); }
    else { X = kX; wa = wa2; sc = ks; row = (blockIdx.x - nQblocks)*4 + (threadIdx.x >> 6); }
    const unsigned short* Xr = X + (size_t)row*NFEAT;
    float p[NHEADS];
    #pragma unroll
    for (int h = 0; h < NHEADS; ++h) p[h] = 0.f;
    #pragma unroll
    for (int c = 0; c < 8; ++c){
        float x = h2f(Xr[(c<<6) + lane]);
        #pragma unroll
        for (int h = 0; h < NHEADS; ++h) p[h] += x * wa[(h<<9) + (c<<6) + lane];
    }
    #pragma unroll
    for (int h = 0; h < NHEADS; ++h){
        float v = p[h];
        #pragma unroll
        for (int off = 32; off > 0; off >>= 1) v += __shfl_xor(v, off);
        if (lane == 0) sc[(size_t)row*NHEADS + h] = v;
    }
}

// ============ colmax partial / final ============
__global__ __launch_bounds__(256) void colmax_part_k(const int* __restrict__ adj, long bstride, int ns,
    const float* __restrict__ qs, float* __restrict__ pmax, int N, int M){
    int b = blockIdx.z, ch = blockIdx.y;
    int ml = threadIdx.x & 63; int m = blockIdx.x*64 + ml;
    int g = threadIdx.x >> 6;
    int chunk = N / CHUNKS, subl = chunk >> 2;
    int n0 = ch*chunk + g*subl, n1 = n0 + subl;
    const int* adjb = adj + (size_t)b*bstride;
    float mx[8];
    #pragma unroll
    for (int h = 0; h < 8; ++h) mx[h] = -INFINITY;
    for (int n = n0; n < n1; ++n){
        int a = adjb[(size_t)n*ns + m];
        const float* qr = qs + ((size_t)b*N + n)*8;
        #pragma unroll
        for (int h = 0; h < 8; ++h){ float qv = qr[h]; if (a > 0) mx[h] = fmaxf(mx[h], qv); }
    }
    __shared__ float smx[4][64][8];
    #pragma unroll
    for (int h = 0; h < 8; ++h) smx[g][ml][h] = mx[h];
    __syncthreads();
    if (g == 0){
        #pragma unroll
        for (int h = 0; h < 8; ++h){
            float v = fmaxf(fmaxf(smx[0][ml][h], smx[1][ml][h]), fmaxf(smx[2][ml][h], smx[3][ml][h]));
            pmax[(((size_t)b*CHUNKS + ch)*M + m)*8 + h] = v;
        }
    }
}

__global__ __launch_bounds__(256) void colmax_fin_k(const float* __restrict__ pmax, const float* __restrict__ ks,
    float* __restrict__ cmax, int M){
    int idx = blockIdx.x*256 + threadIdx.x;
    int m8 = M*8;
    int b = idx / m8;
    size_t base = (size_t)b*CHUNKS*m8 + (idx - (size_t)b*m8);
    float mx = -INFINITY;
    #pragma unroll
    for (int ch = 0; ch < CHUNKS; ++ch) mx = fmaxf(mx, pmax[base + (size_t)ch*m8]);
    cmax[idx] = (mx == -INFINITY) ? NEGV : lrelu(mx + ks[idx]);
}

__global__ __launch_bounds__(256) void colsum_part_k(const int* __restrict__ adj, long bstride, int ns,
    const float* __restrict__ qs, const float* __restrict__ ks, const float* __restrict__ cmax,
    float* __restrict__ psum, int N, int M){
    int b = blockIdx.z, ch = blockIdx.y;
    int ml = threadIdx.x & 63; int m = blockIdx.x*64 + ml;
    int g = threadIdx.x >> 6;
    int chunk = N / CHUNKS, subl = chunk >> 2;
    int n0 = ch*chunk + g*subl, n1 = n0 + subl;
    const int* adjb = adj + (size_t)b*bstride;
    float ksv[8], cmv[8], s[8];
    size_t mo = ((size_t)b*M + m)*8;
    #pragma unroll
    for (int h = 0; h < 8; ++h){ ksv[h] = ks[mo+h]; cmv[h] = cmax[mo+h]; s[h] = 0.f; }
    for (int n = n0; n < n1; ++n){
        int a = adjb[(size_t)n*ns + m];
        const float* qr = qs + ((size_t)b*N + n)*8;
        #pragma unroll
        for (int h = 0; h < 8; ++h){
            float e = (a > 0) ? lrelu(qr[h] + ksv[h]) : NEGV;
            s[h] += expf(e - cmv[h]);
        }
    }
    __shared__ float ssm[4][64][8];
    #pragma unroll
    for (int h = 0; h < 8; ++h) ssm[g][ml][h] = s[h];
    __syncthreads();
    if (g == 0){
        #pragma unroll
        for (int h = 0; h < 8; ++h){
            float v = ssm[0][ml][h] + ssm[1][ml][h] + ssm[2][ml][h] + ssm[3][ml][h];
            psum[(((size_t)b*CHUNKS + ch)*M + m)*8 + h] = v;
        }
    }
}

// ============ merged colsum finalize + stat repack: write ksh/cmh/ish [b][8][M] ============
__global__ __launch_bounds__(256) void colsum_fin2_k(const float* __restrict__ psum,
    const float* __restrict__ ks, const float* __restrict__ cmax,
    float* __restrict__ ksh, float* __restrict__ cmh, float* __restrict__ ish, int M){
    int idx = blockIdx.x*256 + threadIdx.x;
    int m8 = M*8;
    int b = idx / m8, rem = idx - b*m8;
    int m = rem >> 3, h = rem & 7;
    size_t base = (size_t)b*CHUNKS*m8 + rem;
    float S = 0.f;
    #pragma unroll
    for (int ch = 0; ch < CHUNKS; ++ch) S += psum[base + (size_t)ch*m8];
    size_t o = ((size_t)b*8 + h)*M + m;
    ksh[o] = ks[idx]; cmh[o] = cmax[idx]; ish[o] = 1.f/S;
}

// ============ fused fusion MFMA: in-register hi/lo passes, 2x2 wave tiling ============
// 64x64 tile; grid (8, rows/64, NB). npass: 1 = hi only; 3 = + (aLo,bLo)*Whi + (aHi,bHi)*Wlo
__global__ __launch_bounds__(256) void fusion_all_k(
    const unsigned short* __restrict__ aHi, const unsigned short* __restrict__ aLo,
    const unsigned short* __restrict__ bHi, const unsigned short* __restrict__ bLo,
    const unsigned short* __restrict__ Whi, const unsigned short* __restrict__ Wlo,
    unsigned short* __restrict__ dst, unsigned short* __restrict__ dstLo,
    unsigned short* __restrict__ dstT, unsigned short* __restrict__ dstTLo,
    float* __restrict__ dstF, int rows, int npass){
    int b = blockIdx.z;
    int r0 = blockIdx.y*64, c0 = blockIdx.x*64;
    int tid = threadIdx.x;
    __shared__ unsigned short aHs[64*LSTR], aLs[64*LSTR], bHs[64*LSTR], bLs[64*LSTR];
    __shared__ unsigned short wHs[4*64*LSTR], wLs[4*64*LSTR];
    size_t actOff = (size_t)b*rows*512;
    const unsigned short* aHG = aHi + actOff;
    const unsigned short* bHG = bHi + actOff;
    const unsigned short* aLG = aLo ? aLo + actOff : nullptr;
    const unsigned short* bLG = bLo ? bLo + actOff : nullptr;
    bool multi = (npass == 3);
    bool hasALo = multi && (aLG != nullptr);
    bool hasBLo = multi && (bLG != nullptr);
    int w = tid >> 6, lane = tid & 63;
    int wr = w >> 1, wc = w & 1;                  // 2x2 wave grid: 32-row x 32-col quadrant per wave
    int lrow = lane & 15, quad = lane >> 4;
    v4f accN[2][2], accF[2][2];
    #pragma unroll
    for (int r = 0; r < 2; ++r)
        #pragma unroll
        for (int cf = 0; cf < 2; ++cf){ accN[r][cf] = (v4f)0.f; accF[r][cf] = (v4f)0.f; }
    for (int kt = 0; kt < 512; kt += 32){
        __syncthreads();
        {
            int row = tid >> 2, c4 = tid & 3;
            size_t go = (size_t)(r0+row)*512 + kt + c4*8;
            int lo = row*LSTR + c4*8;
            uint4 za; za.x = za.y = za.z = za.w = 0u;
            *(uint4*)&aHs[lo] = *(const uint4*)(aHG + go);
            *(uint4*)&bHs[lo] = *(const uint4*)(bHG + go);
            if (multi){
                *(uint4*)&aLs[lo] = hasALo ? *(const uint4*)(aLG + go) : za;
                *(uint4*)&bLs[lo] = hasBLo ? *(const uint4*)(bLG + go) : za;
            }
        }
        #pragma unroll
        for (int it = 0; it < 4; ++it){
            int idx = it*256 + tid;
            int mat = idx >> 8, row = (idx >> 2) & 63, c4 = idx & 3;
            size_t go = ((size_t)mat*512 + c0 + row)*512 + kt + c4*8;
            int lo = (mat*64+row)*LSTR + c4*8;
            *(uint4*)&wHs[lo] = *(const uint4*)(Whi + go);
            if (multi) *(uint4*)&wLs[lo] = *(const uint4*)(Wlo + go);
        }
        __syncthreads();
        v8h ah[2], bh[2], al[2], bl[2];
        #pragma unroll
        for (int r = 0; r < 2; ++r){
            int arow = (wr*32 + r*16 + lrow)*LSTR + quad*8;
            ah[r] = *(const v8h*)&aHs[arow];
            bh[r] = *(const v8h*)&bHs[arow];
            if (multi){ al[r] = *(const v8h*)&aLs[arow]; bl[r] = *(const v8h*)&bLs[arow]; }
        }
        #pragma unroll
        for (int cf = 0; cf < 2; ++cf){
            int wrow = (wc*32 + cf*16 + lrow)*LSTR + quad*8;
            v8h w0 = *(const v8h*)&wHs[wrow];
            v8h w1 = *(const v8h*)&wHs[64*LSTR + wrow];
            v8h w2 = *(const v8h*)&wHs[128*LSTR + wrow];
            v8h w3 = *(const v8h*)&wHs[192*LSTR + wrow];
            v8h l0, l1, l2, l3;
            if (multi){
                l0 = *(const v8h*)&wLs[wrow];
                l1 = *(const v8h*)&wLs[64*LSTR + wrow];
                l2 = *(const v8h*)&wLs[128*LSTR + wrow];
                l3 = *(const v8h*)&wLs[192*LSTR + wrow];
            }
            #pragma unroll
            for (int r = 0; r < 2; ++r){
                accN[r][cf] = MFMA16(ah[r], w0, accN[r][cf]);
                accN[r][cf] = MFMA16(bh[r], w1, accN[r][cf]);
                accF[r][cf] = MFMA16(ah[r], w2, accF[r][cf]);
                accF[r][cf] = MFMA16(bh[r], w3, accF[r][cf]);
                if (multi){
                    if (hasALo){ accN[r][cf] = MFMA16(al[r], w0, accN[r][cf]); accF[r][cf] = MFMA16(al[r], w2, accF[r][cf]); }
                    if (hasBLo){ accN[r][cf] = MFMA16(bl[r], w1, accN[r][cf]); accF[r][cf] = MFMA16(bl[r], w3, accF[r][cf]); }
                    accN[r][cf] = MFMA16(ah[r], l0, accN[r][cf]);
                    accN[r][cf] = MFMA16(bh[r], l1, accN[r][cf]);
                    accF[r][cf] = MFMA16(ah[r], l2, accF[r][cf]);
                    accF[r][cf] = MFMA16(bh[r], l3, accF[r][cf]);
                }
            }
        }
    }
    #pragma unroll
    for (int r = 0; r < 2; ++r)
        #pragma unroll
        for (int cf = 0; cf < 2; ++cf){
            int colg = c0 + wc*32 + cf*16 + lrow;
            int rbase = r0 + wr*32 + r*16 + quad*4;
            float o4[4];
            #pragma unroll
            for (int reg = 0; reg < 4; ++reg){
                float f = 1.f/(1.f + expf(-accF[r][cf][reg]));
                size_t ai = (size_t)(rbase+reg)*512 + colg;
                float ao = h2f(aHG[ai]);
                if (aLG) ao += h2f(aLG[ai]);
                o4[reg] = f*accN[r][cf][reg] + (1.f - f)*ao;
                size_t oo = ((size_t)b*rows + rbase + reg)*512 + colg;
                unsigned short hv = f2h(o4[reg]);
                dst[oo] = hv;
                if (dstLo) dstLo[oo] = f2h(o4[reg] - h2f(hv));
                if (dstF) dstF[oo] = o4[reg];
            }
            if (dstT){
                unsigned short h0 = f2h(o4[0]), h1 = f2h(o4[1]), h2 = f2h(o4[2]), h3 = f2h(o4[3]);
                size_t to = ((size_t)b*512 + colg)*rows + rbase;
                *(ushort4*)&dstT[to] = ushort4{h0,h1,h2,h3};
                if (dstTLo)
                    *(ushort4*)&dstTLo[to] = ushort4{f2h(o4[0]-h2f(h0)), f2h(o4[1]-h2f(h1)),
                                                     f2h(o4[2]-h2f(h2)), f2h(o4[3]-h2f(h3))};
            }
        }
}

// ============ generic MFMA GEMM (64-row tiles): C[b] = A[b]@BT^T (+ A[b]@BT2^T) ============
__global__ __launch_bounds__(256) void gemmT_mfma_k(
    const unsigned short* __restrict__ A, size_t aStride,
    const unsigned short* __restrict__ BT, const unsigned short* __restrict__ BT2, size_t bStride,
    int K, int rowsPB,
    unsigned short* __restrict__ outRM, unsigned short* __restrict__ outLo,
    unsigned short* __restrict__ outT){
    int b = blockIdx.z;
    int r0 = blockIdx.y*64, c0 = blockIdx.x*64;
    int tid = threadIdx.x;
    __shared__ unsigned short aS[64*LSTR];
    __shared__ unsigned short bS[64*LSTR];
    const unsigned short* aG = A + (size_t)b*aStride;
    int w = tid >> 6, lane = tid & 63;
    int lrow = lane & 15, quad = lane >> 4;
    v4f acc[4];
    #pragma unroll
    for (int cf = 0; cf < 4; ++cf) acc[cf] = (v4f)0.f;
    for (int p = 0; p < 2; ++p){
        if (p == 1 && BT2 == nullptr) break;
        const unsigned short* bG = (p ? BT2 : BT) + (size_t)b*bStride;
        for (int kt = 0; kt < K; kt += 32){
            __syncthreads();
            {
                int row = tid >> 2, c4 = tid & 3;
                *(uint4*)&aS[row*LSTR + c4*8] = *(const uint4*)(aG + (size_t)(r0+row)*K + kt + c4*8);
                *(uint4*)&bS[row*LSTR + c4*8] = *(const uint4*)(bG + (size_t)(c0+row)*K + kt + c4*8);
            }
            __syncthreads();
            v8h af = *(const v8h*)&aS[(w*16 + lrow)*LSTR + quad*8];
            #pragma unroll
            for (int cf = 0; cf < 4; ++cf){
                v8h bf = *(const v8h*)&bS[(cf*16 + lrow)*LSTR + quad*8];
                acc[cf] = MFMA16(af, bf, acc[cf]);
            }
        }
    }
    #pragma unroll
    for (int cf = 0; cf < 4; ++cf){
        int colg = c0 + cf*16 + lrow;
        int rbase = r0 + w*16 + quad*4;
        if (outRM){
            #pragma unroll
            for (int reg = 0; reg < 4; ++reg){
                float v = acc[cf][reg];
                unsigned short hv = f2h(v);
                size_t oo = ((size_t)b*rowsPB + rbase + reg)*512 + colg;
                outRM[oo] = hv;
                if (outLo) outLo[oo] = f2h(v - h2f(hv));
            }
        }
        if (outT){
            ushort4 pk{f2h(acc[cf][0]), f2h(acc[cf][1]), f2h(acc[cf][2]), f2h(acc[cf][3])};
            *(ushort4*)&outT[((size_t)b*512 + colg)*rowsPB + rbase] = pk;
        }
    }
}

// ============ attention output MFMA ============
__global__ __launch_bounds__(256) void attn_mfma_k(const int* __restrict__ adj, long bstride, int ns,
    const float* __restrict__ qs, const float* __restrict__ ksh, const float* __restrict__ cmh,
    const float* __restrict__ ish, const unsigned short* __restrict__ WkT,
    unsigned short* __restrict__ outp, int N, int M){
    int bh = blockIdx.y; int b = bh >> 3, h = bh & 7;
    int n0 = blockIdx.x*64;
    int tid = threadIdx.x;
    __shared__ unsigned short pS[64*LSTR];
    __shared__ unsigned short wS[64*LSTR];
    __shared__ float qsS[64];
    if (tid < 64) qsS[tid] = qs[((size_t)b*N + n0 + tid)*8 + h];
    const int* adjb = adj + (size_t)b*bstride;
    const float* ksb = ksh + ((size_t)b*8 + h)*M;
    const float* cmb = cmh + ((size_t)b*8 + h)*M;
    const float* isb = ish + ((size_t)b*8 + h)*M;
    const unsigned short* wkb = WkT + ((size_t)b*512 + h*64)*M;
    int w = tid >> 6, lane = tid & 63;
    int lrow = lane & 15, quad = lane >> 4;
    int pn = tid >> 2, pm = (tid & 3)*8;
    v4f acc[4];
    #pragma unroll
    for (int cf = 0; cf < 4; ++cf) acc[cf] = (v4f)0.f;
    for (int mt = 0; mt < M; mt += 32){
        __syncthreads();
        *(uint4*)&wS[(tid>>2)*LSTR + (tid&3)*8] = *(const uint4*)(wkb + (size_t)(tid>>2)*M + mt + (tid&3)*8);
        const int* arow = adjb + (size_t)(n0+pn)*ns + mt + pm;
        int4 a0 = *(const int4*)arow;
        int4 a1 = *(const int4*)(arow + 4);
        float4 k0 = *(const float4*)(ksb + mt + pm), k1 = *(const float4*)(ksb + mt + pm + 4);
        float4 c0v = *(const float4*)(cmb + mt + pm), c1v = *(const float4*)(cmb + mt + pm + 4);
        float4 i0 = *(const float4*)(isb + mt + pm), i1 = *(const float4*)(isb + mt + pm + 4);
        float qv = qsS[pn];
        float p[8];
        const int* aa0 = &a0.x; const int* aa1 = &a1.x;
        const float* kk0 = &k0.x; const float* kk1 = &k1.x;
        const float* cc0 = &c0v.x; const float* cc1 = &c1v.x;
        const float* ii0 = &i0.x; const float* ii1 = &i1.x;
        #pragma unroll
        for (int j = 0; j < 4; ++j){
            float e = (aa0[j] > 0) ? lrelu(qv + kk0[j]) : NEGV;
            p[j] = expf(e - cc0[j]) * ii0[j];
        }
        #pragma unroll
        for (int j = 0; j < 4; ++j){
            float e = (aa1[j] > 0) ? lrelu(qv + kk1[j]) : NEGV;
            p[4+j] = expf(e - cc1[j]) * ii1[j];
        }
        ushort4 pk0{f2h(p[0]), f2h(p[1]), f2h(p[2]), f2h(p[3])};
        ushort4 pk1{f2h(p[4]), f2h(p[5]), f2h(p[6]), f2h(p[7])};
        *(ushort4*)&pS[pn*LSTR + pm] = pk0;
        *(ushort4*)&pS[pn*LSTR + pm + 4] = pk1;
        __syncthreads();
        v8h af = *(const v8h*)&pS[(w*16 + lrow)*LSTR + quad*8];
        #pragma unroll
        for (int cf = 0; cf < 4; ++cf){
            v8h bf = *(const v8h*)&wS[(cf*16 + lrow)*LSTR + quad*8];
            acc[cf] = MFMA16(af, bf, acc[cf]);
        }
    }
    #pragma unroll
    for (int cf = 0; cf < 4; ++cf){
        int colg = h*64 + cf*16 + lrow;
        int rbase = n0 + w*16 + quad*4;
        #pragma unroll
        for (int reg = 0; reg < 4; ++reg){
            float v = acc[cf][reg];
            v = (v > 0.f) ? v : expm1f(v);
            outp[((size_t)b*N + rbase + reg)*512 + colg] = f2h(v);
        }
    }
}

extern "C" void kernel_launch(void* const* d_in, const int* in_sizes, int n_in,
                              void* d_out, int out_size, void* d_ws, size_t ws_size,
                              hipStream_t stream){
    const float* in_gloss = (const float*)d_in[0];
    const float* in_clip  = (const float*)d_in[1];
    const float* in_q     = (const float*)d_in[2];
    const int*   adj_gc   = (const int*)d_in[3];
    const int*   adj_gq   = (const int*)d_in[4];
    const float* c2gW  = (const float*)d_in[5];
    const float* c2ga1 = (const float*)d_in[6];
    const float* c2ga2 = (const float*)d_in[7];
    const float* g2qW  = (const float*)d_in[8];
    const float* g2qa1 = (const float*)d_in[9];
    const float* g2qa2 = (const float*)d_in[10];
    const float* q2gW  = (const float*)d_in[11];
    const float* q2ga1 = (const float*)d_in[12];
    const float* q2ga2 = (const float*)d_in[13];
    const float* fusW  = (const float*)d_in[14];
    const float* fusU  = (const float*)d_in[15];
    const float* fusWf = (const float*)d_in[16];
    const float* fusUf = (const float*)d_in[17];
    float* out = (float*)d_out;
    float* out_gloss = out;
    float* out_clip  = out + (size_t)NB*NG*NFEAT;
    float* out_q     = out + (size_t)NB*NG*NFEAT*2;

    char* wsB = (char*)d_ws;
    size_t off = 0;
    auto alloc = [&](size_t bytes){ void* p = wsB + off; off += (bytes + 255) & ~(size_t)255; return p; };
    float* wa1   = (float*)alloc(4096*4);
    float* wa2   = (float*)alloc(4096*4);
    float* qsb   = (float*)alloc((size_t)NB*NG*8*4);
    float* ksb   = (float*)alloc((size_t)NB*NG*8*4);
    float* cmaxb = (float*)alloc((size_t)NB*NG*8*4);
    float* ksh   = (float*)alloc((size_t)NB*NG*8*4);
    float* cmh   = (float*)alloc((size_t)NB*NG*8*4);
    float* ish   = (float*)alloc((size_t)NB*NG*8*4);
    float* pmaxb = (float*)alloc((size_t)NB*CHUNKS*NG*8*4);
    float* psumb = (float*)alloc((size_t)NB*CHUNKS*NG*8*4);
    unsigned short* WflatT  = (unsigned short*)alloc((size_t)NFEAT*NFEAT*2);
    unsigned short* wtAll   = (unsigned short*)alloc((size_t)32*FF*2);
    unsigned short* wtAllLo = (unsigned short*)alloc((size_t)32*FF*2);
    unsigned short* adjTgc  = (unsigned short*)alloc((size_t)NB*NC*NG*2);
    unsigned short* g_bf0   = (unsigned short*)alloc((size_t)NB*NG*NFEAT*2);
    unsigned short* gLo0    = (unsigned short*)alloc((size_t)NB*NG*NFEAT*2);
    unsigned short* g_bf1   = (unsigned short*)alloc((size_t)NB*NG*NFEAT*2);
    unsigned short* gLo1    = (unsigned short*)alloc((size_t)NB*NG*NFEAT*2);
    unsigned short* gT      = (unsigned short*)alloc((size_t)NB*NFEAT*NG*2);
    unsigned short* gTlo    = (unsigned short*)alloc((size_t)NB*NFEAT*NG*2);
    unsigned short* gA_bf   = (unsigned short*)alloc((size_t)NB*NG*NFEAT*2);
    unsigned short* gALo    = (unsigned short*)alloc((size_t)NB*NG*NFEAT*2);
    unsigned short* c_bf0   = (unsigned short*)alloc((size_t)NB*NC*NFEAT*2);
    unsigned short* cLo0    = (unsigned short*)alloc((size_t)NB*NC*NFEAT*2);
    unsigned short* c_bf1   = (unsigned short*)alloc((size_t)NB*NC*NFEAT*2);
    unsigned short* cLo1    = (unsigned short*)alloc((size_t)NB*NC*NFEAT*2);
    unsigned short* q_bf0   = (unsigned short*)alloc((size_t)NB*NQ*NFEAT*2);
    unsigned short* q_bf1   = (unsigned short*)alloc((size_t)NB*NQ*NFEAT*2);
    unsigned short* agg_bf  = (unsigned short*)alloc((size_t)NB*NG*NFEAT*2);
    unsigned short* aggLo   = (unsigned short*)alloc((size_t)NB*NG*NFEAT*2);
    unsigned short* WkT     = (unsigned short*)alloc((size_t)NB*NFEAT*NG*2);
    int* adjTgq = (int*)alloc((size_t)NB*NQ*NG*4);
    (void)ws_size; (void)in_sizes; (void)n_in; (void)out_size;

    const size_t HFD = (size_t)NHEADS*NFEAT*HDIM;
    const size_t HD  = (size_t)NHEADS*HDIM;

    // ---- prep ----
    wtT_k<<<2048, 256, 0, stream>>>(fusW, fusU, fusWf, fusUf, wtAll, wtAllLo);
    adjT_h_k<<<dim3(NC/64, NG/64, NB), 256, 0, stream>>>(adj_gc, adjTgc);
    adjT_int_k<<<dim3(NQ/64, NG/64, NB), 256, 0, stream>>>(adj_gq, adjTgq);
    cvt_hl_k<<<(NB*NG*NFEAT)/2048, 256, 0, stream>>>(in_gloss, g_bf0, gLo0);
    cvt_hl_k<<<(NB*NC*NFEAT)/2048, 256, 0, stream>>>(in_clip,  c_bf0, cLo0);
    cvt_h_k<<<(NB*NQ*NFEAT)/2048, 256, 0, stream>>>(in_q,     q_bf0);
    actT_hl_k<<<dim3(8, NG/64, NB), 256, 0, stream>>>(in_gloss, gT, gTlo, NG);

    auto run_attn = [&](const unsigned short* qX, int N, const unsigned short* kvX, int M,
                        const int* adjp, long bstride, int ns,
                        const float* W, const float* a1, const float* a2, unsigned short* dst){
        prep_attnW_k<<<80, 256, 0, stream>>>(W, a1, a2, WflatT, wa1, wa2);
        scores2_k<<<(NB*(N+M))/4, 256, 0, stream>>>(qX, wa1, qsb, (NB*N)/4, kvX, wa2, ksb);
        gemmT_mfma_k<<<dim3(8, M/64, NB), 256, 0, stream>>>(kvX, (size_t)M*512, WflatT, nullptr, 0,
                                                            512, M, nullptr, nullptr, WkT);
        colmax_part_k<<<dim3(M/64, CHUNKS, NB), 256, 0, stream>>>(adjp, bstride, ns, qsb, pmaxb, N, M);
        colmax_fin_k<<<(NB*M*8)/256, 256, 0, stream>>>(pmaxb, ksb, cmaxb, M);
        colsum_part_k<<<dim3(M/64, CHUNKS, NB), 256, 0, stream>>>(adjp, bstride, ns, qsb, ksb, cmaxb, psumb, N, M);
        colsum_fin2_k<<<(NB*M*8)/256, 256, 0, stream>>>(psumb, ksb, cmaxb, ksh, cmh, ish, M);
        attn_mfma_k<<<dim3(N/64, NB*8), 256, 0, stream>>>(adjp, bstride, ns, qsb, ksh, cmh, ish,
                                                          WkT, dst, N, M);
    };
    auto run_fusion = [&](const unsigned short* a, const unsigned short* aLo,
                          const unsigned short* bb, const unsigned short* bLo, int rows,
                          int l, int i, int npass,
                          unsigned short* dst, unsigned short* dstLo,
                          unsigned short* dstT, unsigned short* dstTLo, float* dstF){
        const unsigned short* Whi = wtAll   + (size_t)((l*4 + i)*4)*FF;
        const unsigned short* Wlo = wtAllLo + (size_t)((l*4 + i)*4)*FF;
        fusion_all_k<<<dim3(8, rows/64, NB), 256, 0, stream>>>(
            a, aLo, bb, bLo, Whi, Wlo, dst, dstLo, dstT, dstTLo, dstF, rows, npass);
    };

    for (int l = 0; l < 2; ++l){
        const unsigned short* g_cur = (l == 0) ? g_bf0 : g_bf1;
        const unsigned short* gLoC  = (l == 0) ? gLo0  : gLo1;
        const unsigned short* c_cur = (l == 0) ? c_bf0 : c_bf1;
        const unsigned short* cLoC  = (l == 0) ? cLo0  : cLo1;
        const unsigned short* q_cur = (l == 0) ? q_bf0 : q_bf1;
        unsigned short* g_nxt = (l == 0) ? g_bf1 : g_bf0;
        unsigned short* gLoN  = (l == 0) ? gLo1  : nullptr;
        unsigned short* c_nxt = (l == 0) ? c_bf1 : c_bf0;
        unsigned short* cLoN  = (l == 0) ? cLo1  : nullptr;
        unsigned short* q_nxt = (l == 0) ? q_bf1 : q_bf0;
        float* gF = (l == 1) ? out_gloss : nullptr;
        float* cF = (l == 1) ? out_clip  : nullptr;
        float* qF = (l == 1) ? out_q     : nullptr;

        // gloss_same = adj_gc^T @ gloss  (hi/lo B, hi/lo out)
        gemmT_mfma_k<<<dim3(8, NC/64, NB), 256, 0, stream>>>(adjTgc, (size_t)NC*NG, gT, gTlo,
                                                             (size_t)512*NG, NG, NC,
                                                             agg_bf, aggLo, nullptr);
        // clip_1 (3-pass hi/lo)
        run_fusion(c_cur, cLoC, agg_bf, aggLo, NC, l, 0, 3,
                   c_nxt, cLoN, nullptr, nullptr, cF);
        // clip_agg = attn(q=gloss, kv=clip, adj_gc)
        run_attn(g_cur, NG, c_cur, NC, adj_gc, (long)NG*NC, NC,
                 c2gW + l*HFD, c2ga1 + l*HD, c2ga2 + l*HD, agg_bf);
        // gloss_1 (single pass; aLo still used for exact gate residual)
        run_fusion(g_cur, gLoC, agg_bf, nullptr, NG, l, 1, 1,
                   gA_bf, gALo, nullptr, nullptr, nullptr);
        // gloss_agg = attn(q=question, kv=gloss, adjT_gq)
        run_attn(q_cur, NQ, g_cur, NG, adjTgq, (long)NQ*NG, NG,
                 g2qW + l*HFD, g2qa1 + l*HD, g2qa2 + l*HD, agg_bf);
        // question_1 (single pass)
        run_fusion(q_cur, nullptr, agg_bf, nullptr, NQ, l, 2, 1,
                   q_nxt, nullptr, nullptr, nullptr, qF);
        // question_agg = attn(q=gloss, kv=question, adj_gq)
        run_attn(g_cur, NG, q_cur, NQ, adj_gq, (long)NG*NQ, NQ,
                 q2gW + l*HFD, q2ga1 + l*HD, q2ga2 + l*HD, agg_bf);
        // gloss_2 (3-pass; emit hi/lo + transposed hi/lo for next layer's gloss_same)
        run_fusion(gA_bf, gALo, agg_bf, nullptr, NG, l, 3, 3,
                   g_nxt, gLoN, (l == 0) ? gT : nullptr, (l == 0) ? gTlo : nullptr, gF);
    }
}